// Round 3
// baseline (1631.870 us; speedup 1.0000x reference)
//
#include <hip/hip_runtime.h>
#include <math.h>

// ---------------- types ----------------
typedef unsigned int   uint4v __attribute__((ext_vector_type(4)));
typedef float          f32x4  __attribute__((ext_vector_type(4)));
typedef __bf16         bf16x8 __attribute__((ext_vector_type(8)));
typedef unsigned short u16x8  __attribute__((ext_vector_type(8)));
typedef unsigned short u16x4  __attribute__((ext_vector_type(4)));

#define D_MODEL 512
#define SEQ     2048
#define BTOK    4096   // B * SEQ
#define HIDE    2048
#define NHEAD   8
#define HD      64

static __device__ __forceinline__ unsigned short f2bf(float f) {
  union { float f; unsigned u; } v; v.f = f;
  unsigned r = v.u + 0x7FFFu + ((v.u >> 16) & 1u);   // RNE
  return (unsigned short)(r >> 16);
}
static __device__ __forceinline__ bf16x8 ldb8(const unsigned short* p) {
  return __builtin_bit_cast(bf16x8, *(const uint4v*)p);
}
static __device__ __forceinline__ f32x4 mfma16(bf16x8 a, bf16x8 b, f32x4 c) {
  return __builtin_amdgcn_mfma_f32_16x16x32_bf16(a, b, c, 0, 0, 0);
}

// ---------------- weight prep: f32 [K][N] -> bf16 W^T [N][K], all matrices ----
// chunk space per layer (8192 chunks of 512 k-els):
//   [0,1536): qkv rows      [1536,2048): o rows
//   [2048,6144): w0t|w1t rows   [6144,8192): w2t rows (4 k-chunks each)
__global__ __launch_bounds__(256) void prep_k(
    const float* __restrict__ qw, const float* __restrict__ kw,
    const float* __restrict__ vw, const float* __restrict__ ow,
    const float* __restrict__ w0, const float* __restrict__ w1,
    const float* __restrict__ w2,
    unsigned short* __restrict__ Wq, unsigned short* __restrict__ Wo,
    unsigned short* __restrict__ W01, unsigned short* __restrict__ W2)
{
  int chunk = blockIdx.x * 4 + (threadIdx.x >> 6);
  int lane  = threadIdx.x & 63;
  int l = chunk >> 13;
  int r = chunk & 8191;
  const float* src; unsigned short* dst; int srcN, n, k0 = 0;
  if (r < 1536) {
    int sel = r >> 9; n = r & 511;
    src  = (sel == 0 ? qw : sel == 1 ? kw : vw) + (size_t)l * 262144;
    srcN = 512;
    dst  = Wq + (size_t)l * 786432 + (size_t)r * 512;
  } else if (r < 2048) {
    n = r - 1536;
    src  = ow + (size_t)l * 262144; srcN = 512;
    dst  = Wo + (size_t)l * 262144 + (size_t)n * 512;
  } else if (r < 6144) {
    int idx = r - 2048; int sel = idx >> 11; n = idx & 2047;
    src  = (sel ? w1 : w0) + (size_t)l * 1048576; srcN = 2048;
    dst  = W01 + (size_t)l * 2097152 + (size_t)sel * 1048576 + (size_t)n * 512;
  } else {
    int idx = r - 6144; n = idx >> 2; k0 = (idx & 3) * 512;
    src  = w2 + (size_t)l * 1048576; srcN = 512;
    dst  = W2 + (size_t)l * 1048576 + (size_t)n * 2048 + k0;
  }
  int kb = k0 + lane * 8;
  u16x8 o;
  #pragma unroll
  for (int i = 0; i < 8; ++i) o[i] = f2bf(src[(size_t)(kb + i) * srcN + n]);
  *(u16x8*)(dst + k0 * 0 + lane * 8 + (dst ? 0 : 0)) = o;  // dst already includes k0
}

// ---------------- RMSNorm: fp32 in -> bf16 out ----------------
__global__ __launch_bounds__(64) void rmsnorm_k(const float* __restrict__ x,
                                                const float* __restrict__ w,
                                                unsigned short* __restrict__ out) {
  int row  = blockIdx.x;
  int lane = threadIdx.x;
  const float* xr = x + (size_t)row * D_MODEL;
  f32x4 v0 = *(const f32x4*)(xr + lane * 8);
  f32x4 v1 = *(const f32x4*)(xr + lane * 8 + 4);
  float ss = v0.x*v0.x + v0.y*v0.y + v0.z*v0.z + v0.w*v0.w
           + v1.x*v1.x + v1.y*v1.y + v1.z*v1.z + v1.w*v1.w;
  #pragma unroll
  for (int m = 1; m < 64; m <<= 1) ss += __shfl_xor(ss, m, 64);
  float inv = 1.0f / (sqrtf(ss * (1.0f / D_MODEL)) + 1e-6f);
  f32x4 w0 = *(const f32x4*)(w + lane * 8);
  f32x4 w1 = *(const f32x4*)(w + lane * 8 + 4);
  u16x8 o;
  o[0] = f2bf(v0.x * w0.x * inv); o[1] = f2bf(v0.y * w0.y * inv);
  o[2] = f2bf(v0.z * w0.z * inv); o[3] = f2bf(v0.w * w0.w * inv);
  o[4] = f2bf(v1.x * w1.x * inv); o[5] = f2bf(v1.y * w1.y * inv);
  o[6] = f2bf(v1.z * w1.z * inv); o[7] = f2bf(v1.w * w1.w * inv);
  *(u16x8*)(out + (size_t)row * D_MODEL + lane * 8) = o;
}

// ---------------- GEMM v2: A bf16 [M][K] @ W^T bf16 [N][K] ----------------
// tile 128x64, 4 waves, wave = 32 rows x 64 cols. B direct from global (L2).
#define EPI_QKV   0
#define EPI_RESID 1
#define EPI_FFNUP 2

template<int EPI>
__global__ __launch_bounds__(256) void gemm2_k(
    const unsigned short* __restrict__ A,
    const unsigned short* __restrict__ Bt,    // [N][K]
    const unsigned short* __restrict__ Bt2,   // FFNUP: w1t
    const float* __restrict__ bias0,          // QKV: qb | RESID: bias | FFNUP: b0
    const float* __restrict__ bias1,          // QKV: kb | FFNUP: b1
    const float* __restrict__ bias2,          // QKV: vb
    void* __restrict__ out0,                  // QKV: q | RESID: h(f32) | FFNUP: h1
    void* __restrict__ out1,                  // QKV: k
    void* __restrict__ out2,                  // QKV: vt
    int M, int N, int K)
{
  __shared__ __attribute__((aligned(16))) unsigned short A_lds[128][72];
  int tid  = threadIdx.x;
  int lane = tid & 63, wave = tid >> 6;
  int g = lane >> 4, c = lane & 15;
  int m0 = blockIdx.y * 128, n0 = blockIdx.x * 64;
  int srow = tid >> 3, scol = (tid & 7) * 8;

  f32x4 acc[2][4]  = {};
  f32x4 acc2[2][4] = {};

  for (int kt = 0; kt < K; kt += 64) {
    #pragma unroll
    for (int rr = 0; rr < 4; ++rr) {
      uint4v av = *(const uint4v*)(A + (size_t)(m0 + rr * 32 + srow) * K + kt + scol);
      *(uint4v*)&A_lds[rr * 32 + srow][scol] = av;
    }
    __syncthreads();
    #pragma unroll
    for (int ks = 0; ks < 2; ++ks) {
      bf16x8 af0 = ldb8(&A_lds[wave * 32 + c][ks * 32 + g * 8]);
      bf16x8 af1 = ldb8(&A_lds[wave * 32 + 16 + c][ks * 32 + g * 8]);
      #pragma unroll
      for (int nb = 0; nb < 4; ++nb) {
        const size_t boff = (size_t)(n0 + nb * 16 + c) * K + kt + ks * 32 + g * 8;
        bf16x8 bfr = ldb8(Bt + boff);
        acc[0][nb] = mfma16(af0, bfr, acc[0][nb]);
        acc[1][nb] = mfma16(af1, bfr, acc[1][nb]);
        if (EPI == EPI_FFNUP) {
          bf16x8 bf2 = ldb8(Bt2 + boff);
          acc2[0][nb] = mfma16(af0, bf2, acc2[0][nb]);
          acc2[1][nb] = mfma16(af1, bf2, acc2[1][nb]);
        }
      }
    }
    __syncthreads();
  }

  int sel = n0 >> 9;  // QKV segment (uniform per block)
  #pragma unroll
  for (int ms = 0; ms < 2; ++ms) {
    #pragma unroll
    for (int nb = 0; nb < 4; ++nb) {
      int n    = n0 + nb * 16 + c;
      int mrow = m0 + wave * 32 + ms * 16 + g * 4;
      if (EPI == EPI_QKV) {
        int nloc = n & 511;
        float bn = (sel == 0 ? bias0 : sel == 1 ? bias1 : bias2)[nloc];
        if (sel < 2) {
          unsigned short* o = (unsigned short*)(sel == 0 ? out0 : out1);
          #pragma unroll
          for (int i = 0; i < 4; ++i)
            o[(size_t)(mrow + i) * D_MODEL + nloc] = f2bf(acc[ms][nb][i] + bn);
        } else {
          int hh = nloc >> 6, dd = nloc & 63;
          int b  = mrow >> 11, s0 = mrow & 2047;
          u16x4 pk;
          #pragma unroll
          for (int i = 0; i < 4; ++i) pk[i] = f2bf(acc[ms][nb][i] + bn);
          *(u16x4*)((unsigned short*)out2 +
                    ((size_t)(b * NHEAD + hh) * HD + dd) * SEQ + s0) = pk;
        }
      } else if (EPI == EPI_RESID) {
        float bn = bias0[n];
        float* O = (float*)out0;
        #pragma unroll
        for (int i = 0; i < 4; ++i) {
          size_t idx = (size_t)(mrow + i) * N + n;
          O[idx] += acc[ms][nb][i] + bn;
        }
      } else {  // FFNUP: out = (acc + b0) * silu(acc2 + b1)
        float b0n = bias0[n], b1n = bias1[n];
        unsigned short* o = (unsigned short*)out0;
        #pragma unroll
        for (int i = 0; i < 4; ++i) {
          float a  = acc[ms][nb][i] + b0n;
          float bb = acc2[ms][nb][i] + b1n;
          float s  = bb / (1.0f + __expf(-bb));
          o[(size_t)(mrow + i) * N + n] = f2bf(a * s);
        }
      }
    }
  }
}

// ---------------- attention v2: 4 waves/block, 16 q-rows/wave, KV tile 64 ----
// K read direct (row-major), V via pre-transposed VT [bh][d][s]. P via LDS.
__global__ __launch_bounds__(256) void attn2_k(const unsigned short* __restrict__ Q,
                                               const unsigned short* __restrict__ Kb,
                                               const unsigned short* __restrict__ VT,
                                               unsigned short* __restrict__ O)
{
  __shared__ __attribute__((aligned(16))) unsigned short P_lds[4][16][72];
  int tid  = threadIdx.x, lane = tid & 63, wave = tid >> 6;
  int g = lane >> 4, c = lane & 15;
  int q0 = blockIdx.x * 64 + wave * 16;
  int bh = blockIdx.y, b = bh >> 3, h = bh & 7;
  const unsigned short* Qp = Q  + (size_t)b * SEQ * D_MODEL + h * HD;
  const unsigned short* Kp = Kb + (size_t)b * SEQ * D_MODEL + h * HD;
  const unsigned short* Vp = VT + (size_t)bh * HD * SEQ;

  bf16x8 qf0 = ldb8(Qp + (size_t)(q0 + c) * D_MODEL + g * 8);
  bf16x8 qf1 = ldb8(Qp + (size_t)(q0 + c) * D_MODEL + 32 + g * 8);

  float m_i[4], s_i[4];
  f32x4 oacc[4] = {};
  #pragma unroll
  for (int i = 0; i < 4; ++i) { m_i[i] = -3e38f; s_i[i] = 0.0f; }

  int nfull = q0 >> 6;
  for (int kt = 0; kt <= nfull; ++kt) {
    int kbase = kt * 64;
    bool maskt = (kt == nfull);
    f32x4 sc[4];
    #pragma unroll
    for (int hh = 0; hh < 4; ++hh) {
      const unsigned short* kr = Kp + (size_t)(kbase + hh * 16 + c) * D_MODEL;
      f32x4 z = {};
      z = mfma16(qf0, ldb8(kr + g * 8), z);
      z = mfma16(qf1, ldb8(kr + 32 + g * 8), z);
      sc[hh] = z;
    }
    float mt[4], scale[4], rs[4];
    #pragma unroll
    for (int i = 0; i < 4; ++i) {
      int qrow = q0 + g * 4 + i;
      float mm = -3e38f;
      #pragma unroll
      for (int hh = 0; hh < 4; ++hh) {
        float v = sc[hh][i] * 0.125f;
        if (maskt) v = (kbase + hh * 16 + c <= qrow) ? v : -3e38f;
        sc[hh][i] = v;
        mm = fmaxf(mm, v);
      }
      mt[i] = mm;
    }
    #pragma unroll
    for (int mm2 = 1; mm2 < 16; mm2 <<= 1) {
      #pragma unroll
      for (int i = 0; i < 4; ++i) mt[i] = fmaxf(mt[i], __shfl_xor(mt[i], mm2, 64));
    }
    #pragma unroll
    for (int i = 0; i < 4; ++i) {
      float mnew = fmaxf(m_i[i], mt[i]);
      scale[i] = __expf(m_i[i] - mnew);
      m_i[i] = mnew;
      float r = 0.0f;
      #pragma unroll
      for (int hh = 0; hh < 4; ++hh) {
        float p = __expf(sc[hh][i] - mnew);
        r += p;
        P_lds[wave][g * 4 + i][hh * 16 + c] = f2bf(p);
      }
      rs[i] = r;
    }
    #pragma unroll
    for (int mm2 = 1; mm2 < 16; mm2 <<= 1) {
      #pragma unroll
      for (int i = 0; i < 4; ++i) rs[i] += __shfl_xor(rs[i], mm2, 64);
    }
    #pragma unroll
    for (int i = 0; i < 4; ++i) {
      s_i[i] = s_i[i] * scale[i] + rs[i];
      #pragma unroll
      for (int nb = 0; nb < 4; ++nb) oacc[nb][i] *= scale[i];
    }
    // P @ V  (A-frag from LDS, B-frag = VT direct)
    bf16x8 pa0 = ldb8(&P_lds[wave][c][g * 8]);
    bf16x8 pa1 = ldb8(&P_lds[wave][c][32 + g * 8]);
    #pragma unroll
    for (int nb = 0; nb < 4; ++nb) {
      const unsigned short* vr = Vp + (size_t)(nb * 16 + c) * SEQ + kbase;
      oacc[nb] = mfma16(pa0, ldb8(vr + g * 8), oacc[nb]);
      oacc[nb] = mfma16(pa1, ldb8(vr + 32 + g * 8), oacc[nb]);
    }
  }
  float inv[4];
  #pragma unroll
  for (int i = 0; i < 4; ++i) inv[i] = 1.0f / s_i[i];
  #pragma unroll
  for (int nb = 0; nb < 4; ++nb)
    #pragma unroll
    for (int i = 0; i < 4; ++i)
      O[((size_t)(b * SEQ + q0 + g * 4 + i)) * D_MODEL + h * HD + nb * 16 + c] =
          f2bf(oacc[nb][i] * inv[i]);
}

// ---------------- launch ----------------
extern "C" void kernel_launch(void* const* d_in, const int* in_sizes, int n_in,
                              void* d_out, int out_size, void* d_ws, size_t ws_size,
                              hipStream_t stream) {
  (void)in_sizes; (void)n_in; (void)out_size; (void)ws_size;
  const float* x   = (const float*)d_in[0];
  const float* qw  = (const float*)d_in[1];
  const float* qb  = (const float*)d_in[2];
  const float* kw  = (const float*)d_in[3];
  const float* kbi = (const float*)d_in[4];
  const float* vw  = (const float*)d_in[5];
  const float* vb  = (const float*)d_in[6];
  const float* ow  = (const float*)d_in[7];
  const float* ob  = (const float*)d_in[8];
  const float* w0  = (const float*)d_in[9];
  const float* b0  = (const float*)d_in[10];
  const float* w1  = (const float*)d_in[11];
  const float* b1  = (const float*)d_in[12];
  const float* w2  = (const float*)d_in[13];
  const float* b2  = (const float*)d_in[14];
  const float* anw = (const float*)d_in[15];
  const float* fnw = (const float*)d_in[16];

  char* ws = (char*)d_ws;
  float*          h   = (float*)ws;                               // 0..8MB fp32 residual
  unsigned short* xn  = (unsigned short*)(ws + (8u  << 20));      // 4MB
  unsigned short* q   = (unsigned short*)(ws + (12u << 20));      // 4MB
  unsigned short* k   = (unsigned short*)(ws + (16u << 20));      // 4MB
  unsigned short* vt  = (unsigned short*)(ws + (20u << 20));      // 4MB  [bh][d][s]
  unsigned short* ao  = (unsigned short*)(ws + (24u << 20));      // 4MB
  unsigned short* h1  = (unsigned short*)(ws + (12u << 20));      // 16MB (aliases q..ao)
  unsigned short* Wq  = (unsigned short*)(ws + (28u << 20));      // 6MB  [L][1536][512]
  unsigned short* Wo  = (unsigned short*)(ws + (34u << 20));      // 2MB  [L][512][512]
  unsigned short* W01 = (unsigned short*)(ws + (36u << 20));      // 16MB [L][2][2048][512]
  unsigned short* W2  = (unsigned short*)(ws + (52u << 20));      // 8MB  [L][512][2048]

  prep_k<<<8192, 256, 0, stream>>>(qw, kw, vw, ow, w0, w1, w2, Wq, Wo, W01, W2);
  hipMemcpyAsync(h, x, (size_t)BTOK * D_MODEL * sizeof(float),
                 hipMemcpyDeviceToDevice, stream);

  for (int l = 0; l < 4; ++l) {
    size_t bo  = (size_t)l * D_MODEL;
    size_t bho = (size_t)l * HIDE;

    rmsnorm_k<<<BTOK, 64, 0, stream>>>(h, anw + bo, xn);
    gemm2_k<EPI_QKV><<<dim3(24, 32), 256, 0, stream>>>(
        xn, Wq + (size_t)l * 786432, nullptr,
        qb + bo, kbi + bo, vb + bo, q, k, vt, BTOK, 3 * D_MODEL, D_MODEL);
    attn2_k<<<dim3(SEQ / 64, 16), 256, 0, stream>>>(q, k, vt, ao);
    gemm2_k<EPI_RESID><<<dim3(8, 32), 256, 0, stream>>>(
        ao, Wo + (size_t)l * 262144, nullptr,
        ob + bo, nullptr, nullptr, h, nullptr, nullptr, BTOK, D_MODEL, D_MODEL);

    rmsnorm_k<<<BTOK, 64, 0, stream>>>(h, fnw + bo, xn);
    gemm2_k<EPI_FFNUP><<<dim3(32, 32), 256, 0, stream>>>(
        xn, W01 + (size_t)l * 2097152, W01 + (size_t)l * 2097152 + 1048576,
        b0 + bho, b1 + bho, nullptr, h1, nullptr, nullptr, BTOK, HIDE, D_MODEL);
    gemm2_k<EPI_RESID><<<dim3(8, 32), 256, 0, stream>>>(
        h1, W2 + (size_t)l * 1048576, nullptr,
        b2 + bo, nullptr, nullptr, h, nullptr, nullptr, BTOK, D_MODEL, HIDE);
  }
  hipMemcpyAsync(d_out, h, (size_t)BTOK * D_MODEL * sizeof(float),
                 hipMemcpyDeviceToDevice, stream);
}

// Round 4
// 1207.520 us; speedup vs baseline: 1.3514x; 1.3514x over previous
//
#include <hip/hip_runtime.h>
#include <math.h>

// ---------------- types ----------------
typedef unsigned int   uint4v __attribute__((ext_vector_type(4)));
typedef float          f32x4  __attribute__((ext_vector_type(4)));
typedef __bf16         bf16x8 __attribute__((ext_vector_type(8)));
typedef unsigned short u16x8  __attribute__((ext_vector_type(8)));
typedef unsigned short u16x4  __attribute__((ext_vector_type(4)));

#define D_MODEL 512
#define SEQ     2048
#define BTOK    4096   // B * SEQ
#define HIDE    2048
#define NHEAD   8
#define HD      64

static __device__ __forceinline__ unsigned short f2bf(float f) {
  union { float f; unsigned u; } v; v.f = f;
  unsigned r = v.u + 0x7FFFu + ((v.u >> 16) & 1u);   // RNE
  return (unsigned short)(r >> 16);
}
static __device__ __forceinline__ bf16x8 ldb8(const unsigned short* p) {
  return __builtin_bit_cast(bf16x8, *(const uint4v*)p);
}
static __device__ __forceinline__ f32x4 mfma16(bf16x8 a, bf16x8 b, f32x4 c) {
  return __builtin_amdgcn_mfma_f32_16x16x32_bf16(a, b, c, 0, 0, 0);
}

#define SWZ(r, off) ((off) ^ (((r) & 7) << 4))

// ---------------- weight prep: LDS-tiled transpose f32 [K][N] -> bf16 [N][K] ----
// 1024 tiles/layer: [0,192) qkv, [192,256) o, [256,768) w0|w1, [768,1024) w2
__global__ __launch_bounds__(64) void prep_t(
    const float* __restrict__ qw, const float* __restrict__ kw,
    const float* __restrict__ vw, const float* __restrict__ ow,
    const float* __restrict__ w0, const float* __restrict__ w1,
    const float* __restrict__ w2,
    unsigned short* __restrict__ Wq, unsigned short* __restrict__ Wo,
    unsigned short* __restrict__ W01, unsigned short* __restrict__ W2)
{
  int bid = blockIdx.x;
  int l = bid >> 10;
  int r = bid & 1023;
  const float* src; unsigned short* dst;
  int tr, tc, srcN, dstK;
  if (r < 192) {
    int sel = r >> 6, tt = r & 63;
    tr = tt >> 3; tc = tt & 7;
    src = (sel == 0 ? qw : sel == 1 ? kw : vw) + (size_t)l * 262144;
    srcN = 512; dstK = 512;
    dst = Wq + (size_t)l * 786432 + (size_t)(sel * 512 + tc * 64) * 512 + tr * 64;
  } else if (r < 256) {
    int tt = r - 192; tr = tt >> 3; tc = tt & 7;
    src = ow + (size_t)l * 262144; srcN = 512; dstK = 512;
    dst = Wo + (size_t)l * 262144 + (size_t)(tc * 64) * 512 + tr * 64;
  } else if (r < 768) {
    int idx = r - 256; int sel = idx >> 8; int tt = idx & 255;
    tr = tt >> 5; tc = tt & 31;
    src = (sel ? w1 : w0) + (size_t)l * 1048576; srcN = 2048; dstK = 512;
    dst = W01 + (size_t)l * 2097152 + (size_t)sel * 1048576 + (size_t)(tc * 64) * 512 + tr * 64;
  } else {
    int tt = r - 768; tr = tt >> 3; tc = tt & 7;
    src = w2 + (size_t)l * 1048576; srcN = 512; dstK = 2048;
    dst = W2 + (size_t)l * 1048576 + (size_t)(tc * 64) * 2048 + tr * 64;
  }
  src += (size_t)(tr * 64) * srcN + tc * 64;
  __shared__ unsigned short T[64][68];
  int t = threadIdx.x;
  #pragma unroll
  for (int it = 0; it < 16; ++it) {
    int row = it * 4 + (t >> 4);
    int col = (t & 15) * 4;
    f32x4 v4 = *(const f32x4*)(src + (size_t)row * srcN + col);
    u16x4 o; o[0] = f2bf(v4.x); o[1] = f2bf(v4.y); o[2] = f2bf(v4.z); o[3] = f2bf(v4.w);
    *(u16x4*)&T[row][col] = o;
  }
  __syncthreads();
  unsigned short* orow = dst + (size_t)t * dstK;
  #pragma unroll
  for (int j0 = 0; j0 < 8; ++j0) {
    u16x8 o;
    #pragma unroll
    for (int j = 0; j < 8; ++j) o[j] = T[j0 * 8 + j][t];
    *(u16x8*)(orow + j0 * 8) = o;
  }
}

// ---------------- RMSNorm: fp32 in -> bf16 out ----------------
__global__ __launch_bounds__(64) void rmsnorm_k(const float* __restrict__ x,
                                                const float* __restrict__ w,
                                                unsigned short* __restrict__ out) {
  int row  = blockIdx.x;
  int lane = threadIdx.x;
  const float* xr = x + (size_t)row * D_MODEL;
  f32x4 v0 = *(const f32x4*)(xr + lane * 8);
  f32x4 v1 = *(const f32x4*)(xr + lane * 8 + 4);
  float ss = v0.x*v0.x + v0.y*v0.y + v0.z*v0.z + v0.w*v0.w
           + v1.x*v1.x + v1.y*v1.y + v1.z*v1.z + v1.w*v1.w;
  #pragma unroll
  for (int m = 1; m < 64; m <<= 1) ss += __shfl_xor(ss, m, 64);
  float inv = 1.0f / (sqrtf(ss * (1.0f / D_MODEL)) + 1e-6f);
  f32x4 w0 = *(const f32x4*)(w + lane * 8);
  f32x4 w1 = *(const f32x4*)(w + lane * 8 + 4);
  u16x8 o;
  o[0] = f2bf(v0.x * w0.x * inv); o[1] = f2bf(v0.y * w0.y * inv);
  o[2] = f2bf(v0.z * w0.z * inv); o[3] = f2bf(v0.w * w0.w * inv);
  o[4] = f2bf(v1.x * w1.x * inv); o[5] = f2bf(v1.y * w1.y * inv);
  o[6] = f2bf(v1.z * w1.z * inv); o[7] = f2bf(v1.w * w1.w * inv);
  *(u16x8*)(out + (size_t)row * D_MODEL + lane * 8) = o;
}

// ---------------- GEMM v2: A bf16 [M][K] @ W^T bf16 [N][K] ----------------
#define EPI_QKV   0
#define EPI_RESID 1
#define EPI_FFNUP 2

template<int EPI>
__global__ __launch_bounds__(256) void gemm2_k(
    const unsigned short* __restrict__ A,
    const unsigned short* __restrict__ Bt,    // [N][K]
    const unsigned short* __restrict__ Bt2,   // FFNUP: w1t
    const float* __restrict__ bias0,
    const float* __restrict__ bias1,
    const float* __restrict__ bias2,
    void* __restrict__ out0,
    void* __restrict__ out1,
    void* __restrict__ out2,
    int M, int N, int K)
{
  __shared__ __attribute__((aligned(16))) unsigned short A_lds[128][72];
  int tid  = threadIdx.x;
  int lane = tid & 63, wave = tid >> 6;
  int g = lane >> 4, c = lane & 15;
  int m0 = blockIdx.y * 128, n0 = blockIdx.x * 64;
  int srow = tid >> 3, scol = (tid & 7) * 8;

  f32x4 acc[2][4]  = {};
  f32x4 acc2[2][4] = {};

  for (int kt = 0; kt < K; kt += 64) {
    #pragma unroll
    for (int rr = 0; rr < 4; ++rr) {
      uint4v av = *(const uint4v*)(A + (size_t)(m0 + rr * 32 + srow) * K + kt + scol);
      *(uint4v*)&A_lds[rr * 32 + srow][scol] = av;
    }
    __syncthreads();
    #pragma unroll
    for (int ks = 0; ks < 2; ++ks) {
      bf16x8 af0 = ldb8(&A_lds[wave * 32 + c][ks * 32 + g * 8]);
      bf16x8 af1 = ldb8(&A_lds[wave * 32 + 16 + c][ks * 32 + g * 8]);
      #pragma unroll
      for (int nb = 0; nb < 4; ++nb) {
        const size_t boff = (size_t)(n0 + nb * 16 + c) * K + kt + ks * 32 + g * 8;
        bf16x8 bfr = ldb8(Bt + boff);
        acc[0][nb] = mfma16(af0, bfr, acc[0][nb]);
        acc[1][nb] = mfma16(af1, bfr, acc[1][nb]);
        if (EPI == EPI_FFNUP) {
          bf16x8 bf2 = ldb8(Bt2 + boff);
          acc2[0][nb] = mfma16(af0, bf2, acc2[0][nb]);
          acc2[1][nb] = mfma16(af1, bf2, acc2[1][nb]);
        }
      }
    }
    __syncthreads();
  }

  int sel = n0 >> 9;  // QKV segment (block-uniform)
  #pragma unroll
  for (int ms = 0; ms < 2; ++ms) {
    #pragma unroll
    for (int nb = 0; nb < 4; ++nb) {
      int n    = n0 + nb * 16 + c;
      int mrow = m0 + wave * 32 + ms * 16 + g * 4;
      if (EPI == EPI_QKV) {
        int nloc = n & 511;
        float bn = (sel == 0 ? bias0 : sel == 1 ? bias1 : bias2)[nloc];
        unsigned short* o = (unsigned short*)(sel == 0 ? out0 : sel == 1 ? out1 : out2);
        float scq = (sel == 0) ? 0.125f : 1.0f;   // fold 1/sqrt(hd) into q
        #pragma unroll
        for (int i = 0; i < 4; ++i)
          o[(size_t)(mrow + i) * D_MODEL + nloc] = f2bf((acc[ms][nb][i] + bn) * scq);
      } else if (EPI == EPI_RESID) {
        float bn = bias0[n];
        float* O = (float*)out0;
        #pragma unroll
        for (int i = 0; i < 4; ++i) {
          size_t idx = (size_t)(mrow + i) * N + n;
          O[idx] += acc[ms][nb][i] + bn;
        }
      } else {  // FFNUP: out = (acc + b0) * silu(acc2 + b1)
        float b0n = bias0[n], b1n = bias1[n];
        unsigned short* o = (unsigned short*)out0;
        #pragma unroll
        for (int i = 0; i < 4; ++i) {
          float a  = acc[ms][nb][i] + b0n;
          float bb = acc2[ms][nb][i] + b1n;
          float s  = bb / (1.0f + __expf(-bb));
          o[(size_t)(mrow + i) * N + n] = f2bf(a * s);
        }
      }
    }
  }
}

// ---------------- V transpose: v [B*S][512] -> vt [bh][d][s] ----------------
__global__ __launch_bounds__(64) void vtrans_k(const unsigned short* __restrict__ V,
                                               unsigned short* __restrict__ VT) {
  __shared__ unsigned short T[64][76];
  int t = threadIdx.x;
  int s0 = blockIdx.x * 64;
  int bh = blockIdx.y, b = bh >> 3, h = bh & 7;
  const unsigned short* src = V + (size_t)(b * SEQ + s0) * D_MODEL + h * HD;
  #pragma unroll
  for (int j0 = 0; j0 < 8; ++j0) {
    u16x8 vv = *(const u16x8*)(src + (size_t)t * D_MODEL + j0 * 8);
    *(u16x8*)&T[t][j0 * 8] = vv;
  }
  __syncthreads();
  unsigned short* dst = VT + ((size_t)bh * HD + t) * SEQ + s0;
  #pragma unroll
  for (int j0 = 0; j0 < 8; ++j0) {
    u16x8 o;
    #pragma unroll
    for (int j = 0; j < 8; ++j) o[j] = T[j0 * 8 + j][t];
    *(u16x8*)(dst + j0 * 8) = o;
  }
}

// ---------------- attention v3 ----------------
// 4 waves/block, 16 q-rows/wave (qtile 64), kv tile 64, K/VT LDS-staged
// (XOR-swizzled, double-buffered), no-max online softmax (exp-sum only).
struct Stg { uint4v k0, k1, v0, v1; };

static __device__ __forceinline__ Stg stage_load(const unsigned short* Kp,
                                                 const unsigned short* Vp,
                                                 int kbase, int srow, int sslot) {
  Stg s;
  const unsigned short* kr = Kp + (size_t)(kbase + srow) * D_MODEL + sslot * 8;
  s.k0 = *(const uint4v*)kr;
  s.k1 = *(const uint4v*)(kr + 32);
  const unsigned short* vr = Vp + (size_t)srow * SEQ + kbase + sslot * 8;
  s.v0 = *(const uint4v*)vr;
  s.v1 = *(const uint4v*)(vr + 32);
  return s;
}
static __device__ __forceinline__ void stage_write(unsigned short* Klb, unsigned short* Vlb,
                                                   const Stg& s, int srow, int sslot) {
  char* kb = (char*)Klb;
  *(uint4v*)(kb + SWZ(srow, srow * 128 + sslot * 16))       = s.k0;
  *(uint4v*)(kb + SWZ(srow, srow * 128 + (sslot + 4) * 16)) = s.k1;
  char* vb = (char*)Vlb;
  *(uint4v*)(vb + SWZ(srow, srow * 128 + sslot * 16))       = s.v0;
  *(uint4v*)(vb + SWZ(srow, srow * 128 + (sslot + 4) * 16)) = s.v1;
}

static __device__ __forceinline__ void attn_tile(
    const unsigned short* Klb, const unsigned short* Vlb, unsigned short* Plw,
    bf16x8 qf0, bf16x8 qf1, f32x4* oacc, f32x4& rs,
    int g, int c, bool masked, int kbase, int rowbase)
{
  f32x4 sc[4];
  #pragma unroll
  for (int hh = 0; hh < 4; ++hh) {
    int r = hh * 16 + c;
    const char* base = (const char*)Klb;
    bf16x8 k0 = ldb8((const unsigned short*)(base + SWZ(r, r * 128 + g * 16)));
    bf16x8 k1 = ldb8((const unsigned short*)(base + SWZ(r, r * 128 + 64 + g * 16)));
    f32x4 z = {};
    z = mfma16(qf0, k0, z);
    z = mfma16(qf1, k1, z);
    sc[hh] = z;
  }
  #pragma unroll
  for (int i = 0; i < 4; ++i) {
    int row = rowbase + g * 4 + i;
    #pragma unroll
    for (int hh = 0; hh < 4; ++hh) {
      float p;
      if (masked) p = (kbase + hh * 16 + c <= row) ? __expf(sc[hh][i]) : 0.0f;
      else        p = __expf(sc[hh][i]);
      rs[i] += p;
      Plw[(g * 4 + i) * 72 + hh * 16 + c] = f2bf(p);
    }
  }
  bf16x8 pa0 = ldb8(Plw + c * 72 + g * 8);
  bf16x8 pa1 = ldb8(Plw + c * 72 + 32 + g * 8);
  #pragma unroll
  for (int db = 0; db < 4; ++db) {
    int r = db * 16 + c;
    const char* base = (const char*)Vlb;
    bf16x8 v0 = ldb8((const unsigned short*)(base + SWZ(r, r * 128 + g * 16)));
    bf16x8 v1 = ldb8((const unsigned short*)(base + SWZ(r, r * 128 + 64 + g * 16)));
    oacc[db] = mfma16(pa0, v0, oacc[db]);
    oacc[db] = mfma16(pa1, v1, oacc[db]);
  }
}

__global__ __launch_bounds__(256) void attn3_k(const unsigned short* __restrict__ Q,
                                               const unsigned short* __restrict__ K,
                                               const unsigned short* __restrict__ VT,
                                               unsigned short* __restrict__ O)
{
  __shared__ __attribute__((aligned(16))) unsigned short Kl[2][64 * 64];
  __shared__ __attribute__((aligned(16))) unsigned short Vl[2][64 * 64];
  __shared__ __attribute__((aligned(16))) unsigned short Pl[4][16][72];
  int tid = threadIdx.x, lane = tid & 63, w = tid >> 6;
  int g = lane >> 4, c = lane & 15;
  int chunk = 31 - (int)blockIdx.x;     // heavy blocks first
  int bh = blockIdx.y, b = bh >> 3, h = bh & 7;
  int q0 = chunk * 64;
  int nt = chunk + 1;
  const unsigned short* Qp = Q + (size_t)(b * SEQ) * D_MODEL + h * HD;
  const unsigned short* Kp = K + (size_t)(b * SEQ) * D_MODEL + h * HD;
  const unsigned short* Vp = VT + (size_t)bh * HD * SEQ;

  int qr = q0 + w * 16 + c;
  bf16x8 qf0 = ldb8(Qp + (size_t)qr * D_MODEL + g * 8);
  bf16x8 qf1 = ldb8(Qp + (size_t)qr * D_MODEL + 32 + g * 8);

  f32x4 oacc[4] = {};
  f32x4 rs = {};
  int srow = tid >> 2, sslot = tid & 3;

  Stg s0 = stage_load(Kp, Vp, 0, srow, sslot);
  stage_write(&Kl[0][0], &Vl[0][0], s0, srow, sslot);
  __syncthreads();

  int buf = 0;
  for (int kt = 0; kt < nt - 1; ++kt) {
    Stg sn = stage_load(Kp, Vp, (kt + 1) * 64, srow, sslot);
    attn_tile(&Kl[buf][0], &Vl[buf][0], &Pl[w][0][0],
              qf0, qf1, oacc, rs, g, c, false, 0, 0);
    stage_write(&Kl[buf ^ 1][0], &Vl[buf ^ 1][0], sn, srow, sslot);
    __syncthreads();
    buf ^= 1;
  }
  attn_tile(&Kl[buf][0], &Vl[buf][0], &Pl[w][0][0],
            qf0, qf1, oacc, rs, g, c, true, q0, q0 + w * 16);

  #pragma unroll
  for (int mm = 1; mm < 16; mm <<= 1) {
    #pragma unroll
    for (int i = 0; i < 4; ++i) rs[i] += __shfl_xor(rs[i], mm, 64);
  }
  f32x4 inv;
  #pragma unroll
  for (int i = 0; i < 4; ++i) inv[i] = 1.0f / rs[i];
  #pragma unroll
  for (int db = 0; db < 4; ++db)
    #pragma unroll
    for (int i = 0; i < 4; ++i)
      O[(size_t)(b * SEQ + q0 + w * 16 + g * 4 + i) * D_MODEL + h * HD + db * 16 + c] =
          f2bf(oacc[db][i] * inv[i]);
}

// ---------------- launch ----------------
extern "C" void kernel_launch(void* const* d_in, const int* in_sizes, int n_in,
                              void* d_out, int out_size, void* d_ws, size_t ws_size,
                              hipStream_t stream) {
  (void)in_sizes; (void)n_in; (void)out_size; (void)ws_size;
  const float* x   = (const float*)d_in[0];
  const float* qw  = (const float*)d_in[1];
  const float* qb  = (const float*)d_in[2];
  const float* kw  = (const float*)d_in[3];
  const float* kbi = (const float*)d_in[4];
  const float* vw  = (const float*)d_in[5];
  const float* vb  = (const float*)d_in[6];
  const float* ow  = (const float*)d_in[7];
  const float* ob  = (const float*)d_in[8];
  const float* w0  = (const float*)d_in[9];
  const float* b0  = (const float*)d_in[10];
  const float* w1  = (const float*)d_in[11];
  const float* b1  = (const float*)d_in[12];
  const float* w2  = (const float*)d_in[13];
  const float* b2  = (const float*)d_in[14];
  const float* anw = (const float*)d_in[15];
  const float* fnw = (const float*)d_in[16];

  char* ws = (char*)d_ws;
  float*          h   = (float*)ws;                               // 0..8MB fp32 residual
  unsigned short* xn  = (unsigned short*)(ws + (8u  << 20));      // 4MB (aliases vt)
  unsigned short* vt  = (unsigned short*)(ws + (8u  << 20));      // 4MB [bh][d][s]
  unsigned short* q   = (unsigned short*)(ws + (12u << 20));      // 4MB
  unsigned short* k   = (unsigned short*)(ws + (16u << 20));      // 4MB
  unsigned short* v   = (unsigned short*)(ws + (20u << 20));      // 4MB
  unsigned short* ao  = (unsigned short*)(ws + (24u << 20));      // 4MB
  unsigned short* h1  = (unsigned short*)(ws + (12u << 20));      // 16MB (aliases q,k,v,ao)
  unsigned short* Wq  = (unsigned short*)(ws + (28u << 20));      // 6MB
  unsigned short* Wo  = (unsigned short*)(ws + (34u << 20));      // 2MB
  unsigned short* W01 = (unsigned short*)(ws + (36u << 20));      // 16MB
  unsigned short* W2  = (unsigned short*)(ws + (52u << 20));      // 8MB

  prep_t<<<4096, 64, 0, stream>>>(qw, kw, vw, ow, w0, w1, w2, Wq, Wo, W01, W2);
  hipMemcpyAsync(h, x, (size_t)BTOK * D_MODEL * sizeof(float),
                 hipMemcpyDeviceToDevice, stream);

  for (int l = 0; l < 4; ++l) {
    size_t bo  = (size_t)l * D_MODEL;
    size_t bho = (size_t)l * HIDE;

    rmsnorm_k<<<BTOK, 64, 0, stream>>>(h, anw + bo, xn);
    gemm2_k<EPI_QKV><<<dim3(24, 32), 256, 0, stream>>>(
        xn, Wq + (size_t)l * 786432, nullptr,
        qb + bo, kbi + bo, vb + bo, q, k, v, BTOK, 3 * D_MODEL, D_MODEL);
    vtrans_k<<<dim3(32, 16), 64, 0, stream>>>(v, vt);
    attn3_k<<<dim3(32, 16), 256, 0, stream>>>(q, k, vt, ao);
    gemm2_k<EPI_RESID><<<dim3(8, 32), 256, 0, stream>>>(
        ao, Wo + (size_t)l * 262144, nullptr,
        ob + bo, nullptr, nullptr, h, nullptr, nullptr, BTOK, D_MODEL, D_MODEL);

    rmsnorm_k<<<BTOK, 64, 0, stream>>>(h, fnw + bo, xn);
    gemm2_k<EPI_FFNUP><<<dim3(32, 32), 256, 0, stream>>>(
        xn, W01 + (size_t)l * 2097152, W01 + (size_t)l * 2097152 + 1048576,
        b0 + bho, b1 + bho, nullptr, h1, nullptr, nullptr, BTOK, HIDE, D_MODEL);
    gemm2_k<EPI_RESID><<<dim3(8, 32), 256, 0, stream>>>(
        h1, W2 + (size_t)l * 1048576, nullptr,
        b2 + bo, nullptr, nullptr, h, nullptr, nullptr, BTOK, D_MODEL, HIDE);
  }
  hipMemcpyAsync(d_out, h, (size_t)BTOK * D_MODEL * sizeof(float),
                 hipMemcpyDeviceToDevice, stream);
}

// Round 5
// 717.104 us; speedup vs baseline: 2.2756x; 1.6839x over previous
//
#include <hip/hip_runtime.h>
#include <math.h>

// ---------------- types ----------------
typedef unsigned int   uint4v __attribute__((ext_vector_type(4)));
typedef float          f32x4  __attribute__((ext_vector_type(4)));
typedef __bf16         bf16x8 __attribute__((ext_vector_type(8)));
typedef unsigned short u16x8  __attribute__((ext_vector_type(8)));
typedef unsigned short u16x4  __attribute__((ext_vector_type(4)));

#define D_MODEL 512
#define SEQ     2048
#define BTOK    4096   // B * SEQ
#define HIDE    2048
#define NHEAD   8
#define HD      64

static __device__ __forceinline__ unsigned short f2bf(float f) {
  union { float f; unsigned u; } v; v.f = f;
  unsigned r = v.u + 0x7FFFu + ((v.u >> 16) & 1u);   // RNE
  return (unsigned short)(r >> 16);
}
static __device__ __forceinline__ float bf2f(unsigned short b) {
  union { unsigned u; float f; } v; v.u = ((unsigned)b) << 16;
  return v.f;
}
static __device__ __forceinline__ bf16x8 ldb8(const unsigned short* p) {
  return __builtin_bit_cast(bf16x8, *(const uint4v*)p);
}
static __device__ __forceinline__ f32x4 mfma16(bf16x8 a, bf16x8 b, f32x4 c) {
  return __builtin_amdgcn_mfma_f32_16x16x32_bf16(a, b, c, 0, 0, 0);
}

typedef unsigned int u32_g __attribute__((address_space(1)));
typedef unsigned int u32_l __attribute__((address_space(3)));
static __device__ __forceinline__ void gload16(const unsigned short* g, unsigned short* l) {
  __builtin_amdgcn_global_load_lds((const u32_g*)(const void*)g,
                                   (u32_l*)(void*)l, 16, 0, 0);
}

#define SWZ(r, off) ((off) ^ (((r) & 7) << 4))

// ---------------- weight prep: LDS-tiled transpose f32 [K][N] -> bf16 [N][K] ----
__global__ __launch_bounds__(64) void prep_t(
    const float* __restrict__ qw, const float* __restrict__ kw,
    const float* __restrict__ vw, const float* __restrict__ ow,
    const float* __restrict__ w0, const float* __restrict__ w1,
    const float* __restrict__ w2,
    unsigned short* __restrict__ Wq, unsigned short* __restrict__ Wo,
    unsigned short* __restrict__ W01, unsigned short* __restrict__ W2)
{
  int bid = blockIdx.x;
  int l = bid >> 10;
  int r = bid & 1023;
  const float* src; unsigned short* dst;
  int tr, tc, srcN, dstK;
  if (r < 192) {
    int sel = r >> 6, tt = r & 63;
    tr = tt >> 3; tc = tt & 7;
    src = (sel == 0 ? qw : sel == 1 ? kw : vw) + (size_t)l * 262144;
    srcN = 512; dstK = 512;
    dst = Wq + (size_t)l * 786432 + (size_t)(sel * 512 + tc * 64) * 512 + tr * 64;
  } else if (r < 256) {
    int tt = r - 192; tr = tt >> 3; tc = tt & 7;
    src = ow + (size_t)l * 262144; srcN = 512; dstK = 512;
    dst = Wo + (size_t)l * 262144 + (size_t)(tc * 64) * 512 + tr * 64;
  } else if (r < 768) {
    int idx = r - 256; int sel = idx >> 8; int tt = idx & 255;
    tr = tt >> 5; tc = tt & 31;
    src = (sel ? w1 : w0) + (size_t)l * 1048576; srcN = 2048; dstK = 512;
    dst = W01 + (size_t)l * 2097152 + (size_t)sel * 1048576 + (size_t)(tc * 64) * 512 + tr * 64;
  } else {
    int tt = r - 768; tr = tt >> 3; tc = tt & 7;
    src = w2 + (size_t)l * 1048576; srcN = 512; dstK = 2048;
    dst = W2 + (size_t)l * 1048576 + (size_t)(tc * 64) * 2048 + tr * 64;
  }
  src += (size_t)(tr * 64) * srcN + tc * 64;
  __shared__ unsigned short T[64][68];
  int t = threadIdx.x;
  #pragma unroll
  for (int it = 0; it < 16; ++it) {
    int row = it * 4 + (t >> 4);
    int col = (t & 15) * 4;
    f32x4 v4 = *(const f32x4*)(src + (size_t)row * srcN + col);
    u16x4 o; o[0] = f2bf(v4.x); o[1] = f2bf(v4.y); o[2] = f2bf(v4.z); o[3] = f2bf(v4.w);
    *(u16x4*)&T[row][col] = o;
  }
  __syncthreads();
  unsigned short* orow = dst + (size_t)t * dstK;
  #pragma unroll
  for (int j0 = 0; j0 < 8; ++j0) {
    u16x8 o;
    #pragma unroll
    for (int j = 0; j < 8; ++j) o[j] = T[j0 * 8 + j][t];
    *(u16x8*)(orow + j0 * 8) = o;
  }
}

// ---------------- RMSNorm: fp32 in -> bf16 out ----------------
__global__ __launch_bounds__(64) void rmsnorm_k(const float* __restrict__ x,
                                                const float* __restrict__ w,
                                                unsigned short* __restrict__ out) {
  int row  = blockIdx.x;
  int lane = threadIdx.x;
  const float* xr = x + (size_t)row * D_MODEL;
  f32x4 v0 = *(const f32x4*)(xr + lane * 8);
  f32x4 v1 = *(const f32x4*)(xr + lane * 8 + 4);
  float ss = v0.x*v0.x + v0.y*v0.y + v0.z*v0.z + v0.w*v0.w
           + v1.x*v1.x + v1.y*v1.y + v1.z*v1.z + v1.w*v1.w;
  #pragma unroll
  for (int m = 1; m < 64; m <<= 1) ss += __shfl_xor(ss, m, 64);
  float inv = 1.0f / (sqrtf(ss * (1.0f / D_MODEL)) + 1e-6f);
  f32x4 w0 = *(const f32x4*)(w + lane * 8);
  f32x4 w1 = *(const f32x4*)(w + lane * 8 + 4);
  u16x8 o;
  o[0] = f2bf(v0.x * w0.x * inv); o[1] = f2bf(v0.y * w0.y * inv);
  o[2] = f2bf(v0.z * w0.z * inv); o[3] = f2bf(v0.w * w0.w * inv);
  o[4] = f2bf(v1.x * w1.x * inv); o[5] = f2bf(v1.y * w1.y * inv);
  o[6] = f2bf(v1.z * w1.z * inv); o[7] = f2bf(v1.w * w1.w * inv);
  *(u16x8*)(out + (size_t)row * D_MODEL + lane * 8) = o;
}

// ---------------- GEMM v3: m97 structure. A bf16 [M][K] @ W^T bf16 [N][K] ----
// BM=128, BN=128/64, BK=64, 4 waves, global_load_lds staging, dbuf LDS,
// one barrier per K-tile, XCD-chunked m-major block order.
#define EPI_QKV   0
#define EPI_PLAIN 1
#define EPI_GATE  2
#define EPI_RESID 3

template<int EPI, int BN>
__global__ __launch_bounds__(256) void gemm3_k(
    const unsigned short* __restrict__ A,
    const unsigned short* __restrict__ Bt,    // [N][K]
    const float* __restrict__ bias0,
    const float* __restrict__ bias1,
    const float* __restrict__ bias2,
    void* __restrict__ out0,
    void* __restrict__ out1,
    void* __restrict__ out2,
    int M, int N, int K)
{
  constexpr int WGN   = (BN == 128) ? 2 : 1;   // waves along n
  constexpr int MF    = (BN == 128) ? 4 : 2;   // 16-row frags per wave (m)
  constexpr int NF    = 4;                     // 16-col frags per wave (n)
  constexpr int BROWS = BN / 4;                // B rows staged per wave

  __shared__ __attribute__((aligned(16))) unsigned short Al[2][128 * 64];
  __shared__ __attribute__((aligned(16))) unsigned short Bl[2][BN * 64];

  // bijective XCD chunk transform (m204), m-major order -> A-locality per XCD
  int nblk = gridDim.x;
  int orig = blockIdx.x;
  int qq = nblk >> 3, rr = nblk & 7, xcd = orig & 7, pos = orig >> 3;
  int lid = (xcd < rr ? xcd * (qq + 1) : rr * (qq + 1) + (xcd - rr) * qq) + pos;
  int numN = N / BN;
  int mt = lid / numN, nt = lid % numN;
  int m0 = mt * 128, n0 = nt * BN;

  int tid = threadIdx.x, lane = tid & 63, w = tid >> 6;
  int wm = w / WGN, wn = w % WGN;
  int g = lane >> 4, c = lane & 15;
  int srow = lane >> 3, scol = (lane & 7) * 8;

  const unsigned short* aG = A  + (size_t)(m0 + w * 32 + srow) * K + scol;
  const unsigned short* bG = Bt + (size_t)(n0 + w * BROWS + srow) * K + scol;
  unsigned short* aL = &Al[0][(w * 32 + srow) * 64 + scol];
  unsigned short* bL = &Bl[0][(w * BROWS + srow) * 64 + scol];

  f32x4 acc[MF][NF] = {};
  int KT = K >> 6;

  // prologue: stage kt=0 into buf 0
  #pragma unroll
  for (int t = 0; t < 4; ++t)
    gload16(aG + (size_t)(t * 8) * K, aL + t * 8 * 64);
  #pragma unroll
  for (int t = 0; t < BROWS / 8; ++t)
    gload16(bG + (size_t)(t * 8) * K, bL + t * 8 * 64);

  for (int kt = 0; kt < KT; ++kt) {
    int buf = kt & 1;
    __syncthreads();   // drains vmcnt -> buf ready; all waves past compute(kt-1)
    if (kt + 1 < KT) {
      int nb = buf ^ 1;
      const unsigned short* aGk = aG + (kt + 1) * 64;
      const unsigned short* bGk = bG + (kt + 1) * 64;
      #pragma unroll
      for (int t = 0; t < 4; ++t)
        gload16(aGk + (size_t)(t * 8) * K, aL + nb * (128 * 64) + t * 8 * 64);
      #pragma unroll
      for (int t = 0; t < BROWS / 8; ++t)
        gload16(bGk + (size_t)(t * 8) * K, bL + nb * (BN * 64) + t * 8 * 64);
    }
    const unsigned short* Ab = &Al[buf][0];
    const unsigned short* Bb = &Bl[buf][0];
    #pragma unroll
    for (int ks = 0; ks < 2; ++ks) {
      bf16x8 af[MF], bfr[NF];
      #pragma unroll
      for (int i = 0; i < MF; ++i)
        af[i] = ldb8(Ab + (wm * (MF * 16) + i * 16 + c) * 64 + ks * 32 + g * 8);
      #pragma unroll
      for (int j = 0; j < NF; ++j)
        bfr[j] = ldb8(Bb + (wn * (NF * 16) + j * 16 + c) * 64 + ks * 32 + g * 8);
      #pragma unroll
      for (int i = 0; i < MF; ++i)
        #pragma unroll
        for (int j = 0; j < NF; ++j)
          acc[i][j] = mfma16(af[i], bfr[j], acc[i][j]);
    }
  }

  // epilogue: lane (g,c) holds rows mrow..mrow+3 of col n
  #pragma unroll
  for (int i = 0; i < MF; ++i) {
    int mrow = m0 + wm * (MF * 16) + i * 16 + g * 4;
    #pragma unroll
    for (int j = 0; j < NF; ++j) {
      int n = n0 + wn * (NF * 16) + j * 16 + c;
      if (EPI == EPI_QKV) {
        int sel  = n >> 9;
        int nloc = n & 511;
        const float* bp = sel == 0 ? bias0 : sel == 1 ? bias1 : bias2;
        unsigned short* o = (unsigned short*)(sel == 0 ? out0 : sel == 1 ? out1 : out2);
        float sc = (sel == 0) ? 0.125f : 1.0f;   // fold 1/sqrt(hd) into q
        float bn = bp[nloc];
        #pragma unroll
        for (int ii = 0; ii < 4; ++ii)
          o[(size_t)(mrow + ii) * D_MODEL + nloc] = f2bf((acc[i][j][ii] + bn) * sc);
      } else if (EPI == EPI_PLAIN) {
        float bn = bias0[n];
        unsigned short* o = (unsigned short*)out0;
        #pragma unroll
        for (int ii = 0; ii < 4; ++ii)
          o[(size_t)(mrow + ii) * N + n] = f2bf(acc[i][j][ii] + bn);
      } else if (EPI == EPI_GATE) {
        float bn = bias0[n];
        unsigned short* o = (unsigned short*)out0;
        #pragma unroll
        for (int ii = 0; ii < 4; ++ii) {
          size_t idx = (size_t)(mrow + ii) * N + n;
          float h1 = acc[i][j][ii] + bn;
          float s  = h1 / (1.0f + __expf(-h1));
          o[idx] = f2bf(bf2f(o[idx]) * s);       // in-place: h0 * silu(h1)
        }
      } else {  // EPI_RESID
        float bn = bias0[n];
        float* O = (float*)out0;
        #pragma unroll
        for (int ii = 0; ii < 4; ++ii) {
          size_t idx = (size_t)(mrow + ii) * N + n;
          O[idx] += acc[i][j][ii] + bn;
        }
      }
    }
  }
}

// ---------------- V transpose: v [B*S][512] -> vt [bh][d][s] ----------------
__global__ __launch_bounds__(64) void vtrans_k(const unsigned short* __restrict__ V,
                                               unsigned short* __restrict__ VT) {
  __shared__ unsigned short T[64][76];
  int t = threadIdx.x;
  int s0 = blockIdx.x * 64;
  int bh = blockIdx.y, b = bh >> 3, h = bh & 7;
  const unsigned short* src = V + (size_t)(b * SEQ + s0) * D_MODEL + h * HD;
  #pragma unroll
  for (int j0 = 0; j0 < 8; ++j0) {
    u16x8 vv = *(const u16x8*)(src + (size_t)t * D_MODEL + j0 * 8);
    *(u16x8*)&T[t][j0 * 8] = vv;
  }
  __syncthreads();
  unsigned short* dst = VT + ((size_t)bh * HD + t) * SEQ + s0;
  #pragma unroll
  for (int j0 = 0; j0 < 8; ++j0) {
    u16x8 o;
    #pragma unroll
    for (int j = 0; j < 8; ++j) o[j] = T[j0 * 8 + j][t];
    *(u16x8*)(dst + j0 * 8) = o;
  }
}

// ---------------- attention v3 (unchanged from R4) ----------------
struct Stg { uint4v k0, k1, v0, v1; };

static __device__ __forceinline__ Stg stage_load(const unsigned short* Kp,
                                                 const unsigned short* Vp,
                                                 int kbase, int srow, int sslot) {
  Stg s;
  const unsigned short* kr = Kp + (size_t)(kbase + srow) * D_MODEL + sslot * 8;
  s.k0 = *(const uint4v*)kr;
  s.k1 = *(const uint4v*)(kr + 32);
  const unsigned short* vr = Vp + (size_t)srow * SEQ + kbase + sslot * 8;
  s.v0 = *(const uint4v*)vr;
  s.v1 = *(const uint4v*)(vr + 32);
  return s;
}
static __device__ __forceinline__ void stage_write(unsigned short* Klb, unsigned short* Vlb,
                                                   const Stg& s, int srow, int sslot) {
  char* kb = (char*)Klb;
  *(uint4v*)(kb + SWZ(srow, srow * 128 + sslot * 16))       = s.k0;
  *(uint4v*)(kb + SWZ(srow, srow * 128 + (sslot + 4) * 16)) = s.k1;
  char* vb = (char*)Vlb;
  *(uint4v*)(vb + SWZ(srow, srow * 128 + sslot * 16))       = s.v0;
  *(uint4v*)(vb + SWZ(srow, srow * 128 + (sslot + 4) * 16)) = s.v1;
}

static __device__ __forceinline__ void attn_tile(
    const unsigned short* Klb, const unsigned short* Vlb, unsigned short* Plw,
    bf16x8 qf0, bf16x8 qf1, f32x4* oacc, f32x4& rs,
    int g, int c, bool masked, int kbase, int rowbase)
{
  f32x4 sc[4];
  #pragma unroll
  for (int hh = 0; hh < 4; ++hh) {
    int r = hh * 16 + c;
    const char* base = (const char*)Klb;
    bf16x8 k0 = ldb8((const unsigned short*)(base + SWZ(r, r * 128 + g * 16)));
    bf16x8 k1 = ldb8((const unsigned short*)(base + SWZ(r, r * 128 + 64 + g * 16)));
    f32x4 z = {};
    z = mfma16(qf0, k0, z);
    z = mfma16(qf1, k1, z);
    sc[hh] = z;
  }
  #pragma unroll
  for (int i = 0; i < 4; ++i) {
    int row = rowbase + g * 4 + i;
    #pragma unroll
    for (int hh = 0; hh < 4; ++hh) {
      float p;
      if (masked) p = (kbase + hh * 16 + c <= row) ? __expf(sc[hh][i]) : 0.0f;
      else        p = __expf(sc[hh][i]);
      rs[i] += p;
      Plw[(g * 4 + i) * 72 + hh * 16 + c] = f2bf(p);
    }
  }
  bf16x8 pa0 = ldb8(Plw + c * 72 + g * 8);
  bf16x8 pa1 = ldb8(Plw + c * 72 + 32 + g * 8);
  #pragma unroll
  for (int db = 0; db < 4; ++db) {
    int r = db * 16 + c;
    const char* base = (const char*)Vlb;
    bf16x8 v0 = ldb8((const unsigned short*)(base + SWZ(r, r * 128 + g * 16)));
    bf16x8 v1 = ldb8((const unsigned short*)(base + SWZ(r, r * 128 + 64 + g * 16)));
    oacc[db] = mfma16(pa0, v0, oacc[db]);
    oacc[db] = mfma16(pa1, v1, oacc[db]);
  }
}

__global__ __launch_bounds__(256) void attn3_k(const unsigned short* __restrict__ Q,
                                               const unsigned short* __restrict__ K,
                                               const unsigned short* __restrict__ VT,
                                               unsigned short* __restrict__ O)
{
  __shared__ __attribute__((aligned(16))) unsigned short Kl[2][64 * 64];
  __shared__ __attribute__((aligned(16))) unsigned short Vl[2][64 * 64];
  __shared__ __attribute__((aligned(16))) unsigned short Pl[4][16][72];
  int tid = threadIdx.x, lane = tid & 63, w = tid >> 6;
  int g = lane >> 4, c = lane & 15;
  int chunk = 31 - (int)blockIdx.x;     // heavy blocks first
  int bh = blockIdx.y, b = bh >> 3, h = bh & 7;
  int q0 = chunk * 64;
  int nt = chunk + 1;
  const unsigned short* Qp = Q + (size_t)(b * SEQ) * D_MODEL + h * HD;
  const unsigned short* Kp = K + (size_t)(b * SEQ) * D_MODEL + h * HD;
  const unsigned short* Vp = VT + (size_t)bh * HD * SEQ;

  int qr = q0 + w * 16 + c;
  bf16x8 qf0 = ldb8(Qp + (size_t)qr * D_MODEL + g * 8);
  bf16x8 qf1 = ldb8(Qp + (size_t)qr * D_MODEL + 32 + g * 8);

  f32x4 oacc[4] = {};
  f32x4 rs = {};
  int srow = tid >> 2, sslot = tid & 3;

  Stg s0 = stage_load(Kp, Vp, 0, srow, sslot);
  stage_write(&Kl[0][0], &Vl[0][0], s0, srow, sslot);
  __syncthreads();

  int buf = 0;
  for (int kt = 0; kt < nt - 1; ++kt) {
    Stg sn = stage_load(Kp, Vp, (kt + 1) * 64, srow, sslot);
    attn_tile(&Kl[buf][0], &Vl[buf][0], &Pl[w][0][0],
              qf0, qf1, oacc, rs, g, c, false, 0, 0);
    stage_write(&Kl[buf ^ 1][0], &Vl[buf ^ 1][0], sn, srow, sslot);
    __syncthreads();
    buf ^= 1;
  }
  attn_tile(&Kl[buf][0], &Vl[buf][0], &Pl[w][0][0],
            qf0, qf1, oacc, rs, g, c, true, q0, q0 + w * 16);

  #pragma unroll
  for (int mm = 1; mm < 16; mm <<= 1) {
    #pragma unroll
    for (int i = 0; i < 4; ++i) rs[i] += __shfl_xor(rs[i], mm, 64);
  }
  f32x4 inv;
  #pragma unroll
  for (int i = 0; i < 4; ++i) inv[i] = 1.0f / rs[i];
  #pragma unroll
  for (int db = 0; db < 4; ++db)
    #pragma unroll
    for (int i = 0; i < 4; ++i)
      O[(size_t)(b * SEQ + q0 + w * 16 + g * 4 + i) * D_MODEL + h * HD + db * 16 + c] =
          f2bf(oacc[db][i] * inv[i]);
}

// ---------------- launch ----------------
extern "C" void kernel_launch(void* const* d_in, const int* in_sizes, int n_in,
                              void* d_out, int out_size, void* d_ws, size_t ws_size,
                              hipStream_t stream) {
  (void)in_sizes; (void)n_in; (void)out_size; (void)ws_size;
  const float* x   = (const float*)d_in[0];
  const float* qw  = (const float*)d_in[1];
  const float* qb  = (const float*)d_in[2];
  const float* kw  = (const float*)d_in[3];
  const float* kbi = (const float*)d_in[4];
  const float* vw  = (const float*)d_in[5];
  const float* vb  = (const float*)d_in[6];
  const float* ow  = (const float*)d_in[7];
  const float* ob  = (const float*)d_in[8];
  const float* w0  = (const float*)d_in[9];
  const float* b0  = (const float*)d_in[10];
  const float* w1  = (const float*)d_in[11];
  const float* b1  = (const float*)d_in[12];
  const float* w2  = (const float*)d_in[13];
  const float* b2  = (const float*)d_in[14];
  const float* anw = (const float*)d_in[15];
  const float* fnw = (const float*)d_in[16];

  char* ws = (char*)d_ws;
  float*          h    = (float*)ws;                              // 0..8MB fp32 residual
  unsigned short* xn   = (unsigned short*)(ws + (8u  << 20));     // 4MB (aliases vt)
  unsigned short* vt   = (unsigned short*)(ws + (8u  << 20));     // 4MB [bh][d][s]
  unsigned short* q    = (unsigned short*)(ws + (12u << 20));     // 4MB
  unsigned short* k    = (unsigned short*)(ws + (16u << 20));     // 4MB
  unsigned short* v    = (unsigned short*)(ws + (20u << 20));     // 4MB
  unsigned short* ao   = (unsigned short*)(ws + (24u << 20));     // 4MB
  unsigned short* hbuf = (unsigned short*)(ws + (12u << 20));     // 16MB (aliases q,k,v,ao)
  unsigned short* Wq   = (unsigned short*)(ws + (28u << 20));     // 6MB
  unsigned short* Wo   = (unsigned short*)(ws + (34u << 20));     // 2MB
  unsigned short* W01  = (unsigned short*)(ws + (36u << 20));     // 16MB
  unsigned short* W2   = (unsigned short*)(ws + (52u << 20));     // 8MB

  prep_t<<<4096, 64, 0, stream>>>(qw, kw, vw, ow, w0, w1, w2, Wq, Wo, W01, W2);
  hipMemcpyAsync(h, x, (size_t)BTOK * D_MODEL * sizeof(float),
                 hipMemcpyDeviceToDevice, stream);

  for (int l = 0; l < 4; ++l) {
    size_t bo  = (size_t)l * D_MODEL;
    size_t bho = (size_t)l * HIDE;

    rmsnorm_k<<<BTOK, 64, 0, stream>>>(h, anw + bo, xn);
    gemm3_k<EPI_QKV, 128><<<384, 256, 0, stream>>>(
        xn, Wq + (size_t)l * 786432, qb + bo, kbi + bo, vb + bo,
        q, k, v, BTOK, 3 * D_MODEL, D_MODEL);
    vtrans_k<<<dim3(32, 16), 64, 0, stream>>>(v, vt);
    attn3_k<<<dim3(32, 16), 256, 0, stream>>>(q, k, vt, ao);
    gemm3_k<EPI_RESID, 64><<<256, 256, 0, stream>>>(
        ao, Wo + (size_t)l * 262144, ob + bo, nullptr, nullptr,
        h, nullptr, nullptr, BTOK, D_MODEL, D_MODEL);

    rmsnorm_k<<<BTOK, 64, 0, stream>>>(h, fnw + bo, xn);
    gemm3_k<EPI_PLAIN, 128><<<512, 256, 0, stream>>>(
        xn, W01 + (size_t)l * 2097152, b0 + bho, nullptr, nullptr,
        hbuf, nullptr, nullptr, BTOK, HIDE, D_MODEL);
    gemm3_k<EPI_GATE, 128><<<512, 256, 0, stream>>>(
        xn, W01 + (size_t)l * 2097152 + 1048576, b1 + bho, nullptr, nullptr,
        hbuf, nullptr, nullptr, BTOK, HIDE, D_MODEL);
    gemm3_k<EPI_RESID, 64><<<256, 256, 0, stream>>>(
        hbuf, W2 + (size_t)l * 1048576, b2 + bo, nullptr, nullptr,
        h, nullptr, nullptr, BTOK, D_MODEL, HIDE);
  }
  hipMemcpyAsync(d_out, h, (size_t)BTOK * D_MODEL * sizeof(float),
                 hipMemcpyDeviceToDevice, stream);
}

// Round 6
// 711.320 us; speedup vs baseline: 2.2941x; 1.0081x over previous
//
#include <hip/hip_runtime.h>
#include <math.h>

// ---------------- types ----------------
typedef unsigned int   uint4v __attribute__((ext_vector_type(4)));
typedef float          f32x4  __attribute__((ext_vector_type(4)));
typedef __bf16         bf16x8 __attribute__((ext_vector_type(8)));
typedef unsigned short u16x8  __attribute__((ext_vector_type(8)));
typedef unsigned short u16x4  __attribute__((ext_vector_type(4)));

#define D_MODEL 512
#define SEQ     2048
#define BTOK    4096   // B * SEQ
#define HIDE    2048
#define NHEAD   8
#define HD      64

static __device__ __forceinline__ unsigned short f2bf(float f) {
  union { float f; unsigned u; } v; v.f = f;
  unsigned r = v.u + 0x7FFFu + ((v.u >> 16) & 1u);   // RNE
  return (unsigned short)(r >> 16);
}
static __device__ __forceinline__ float bf2f(unsigned short b) {
  union { unsigned u; float f; } v; v.u = ((unsigned)b) << 16;
  return v.f;
}
static __device__ __forceinline__ bf16x8 ldb8(const unsigned short* p) {
  return __builtin_bit_cast(bf16x8, *(const uint4v*)p);
}
static __device__ __forceinline__ f32x4 mfma16(bf16x8 a, bf16x8 b, f32x4 c) {
  return __builtin_amdgcn_mfma_f32_16x16x32_bf16(a, b, c, 0, 0, 0);
}

typedef unsigned int u32_g __attribute__((address_space(1)));
typedef unsigned int u32_l __attribute__((address_space(3)));
static __device__ __forceinline__ void gload16(const unsigned short* g, unsigned short* l) {
  __builtin_amdgcn_global_load_lds((const u32_g*)(const void*)g,
                                   (u32_l*)(void*)l, 16, 0, 0);
}

#define SWZ(r, off) ((off) ^ (((r) & 7) << 4))
#define QSCALE 0.180336880f   // 0.125 * log2(e)

// ---------------- weight prep: LDS-tiled transpose f32 [K][N] -> bf16 [N][K] ----
__global__ __launch_bounds__(64) void prep_t(
    const float* __restrict__ qw, const float* __restrict__ kw,
    const float* __restrict__ vw, const float* __restrict__ ow,
    const float* __restrict__ w0, const float* __restrict__ w1,
    const float* __restrict__ w2,
    unsigned short* __restrict__ Wq, unsigned short* __restrict__ Wo,
    unsigned short* __restrict__ W01, unsigned short* __restrict__ W2)
{
  int bid = blockIdx.x;
  int l = bid >> 10;
  int r = bid & 1023;
  const float* src; unsigned short* dst;
  int tr, tc, srcN, dstK;
  if (r < 192) {
    int sel = r >> 6, tt = r & 63;
    tr = tt >> 3; tc = tt & 7;
    src = (sel == 0 ? qw : sel == 1 ? kw : vw) + (size_t)l * 262144;
    srcN = 512; dstK = 512;
    dst = Wq + (size_t)l * 786432 + (size_t)(sel * 512 + tc * 64) * 512 + tr * 64;
  } else if (r < 256) {
    int tt = r - 192; tr = tt >> 3; tc = tt & 7;
    src = ow + (size_t)l * 262144; srcN = 512; dstK = 512;
    dst = Wo + (size_t)l * 262144 + (size_t)(tc * 64) * 512 + tr * 64;
  } else if (r < 768) {
    int idx = r - 256; int sel = idx >> 8; int tt = idx & 255;
    tr = tt >> 5; tc = tt & 31;
    src = (sel ? w1 : w0) + (size_t)l * 1048576; srcN = 2048; dstK = 512;
    dst = W01 + (size_t)l * 2097152 + (size_t)sel * 1048576 + (size_t)(tc * 64) * 512 + tr * 64;
  } else {
    int tt = r - 768; tr = tt >> 3; tc = tt & 7;
    src = w2 + (size_t)l * 1048576; srcN = 512; dstK = 2048;
    dst = W2 + (size_t)l * 1048576 + (size_t)(tc * 64) * 2048 + tr * 64;
  }
  src += (size_t)(tr * 64) * srcN + tc * 64;
  __shared__ unsigned short T[64][68];
  int t = threadIdx.x;
  #pragma unroll
  for (int it = 0; it < 16; ++it) {
    int row = it * 4 + (t >> 4);
    int col = (t & 15) * 4;
    f32x4 v4 = *(const f32x4*)(src + (size_t)row * srcN + col);
    u16x4 o; o[0] = f2bf(v4.x); o[1] = f2bf(v4.y); o[2] = f2bf(v4.z); o[3] = f2bf(v4.w);
    *(u16x4*)&T[row][col] = o;
  }
  __syncthreads();
  unsigned short* orow = dst + (size_t)t * dstK;
  #pragma unroll
  for (int j0 = 0; j0 < 8; ++j0) {
    u16x8 o;
    #pragma unroll
    for (int j = 0; j < 8; ++j) o[j] = T[j0 * 8 + j][t];
    *(u16x8*)(orow + j0 * 8) = o;
  }
}

// ---------------- RMSNorm: fp32 in -> bf16 out (4 rows / 256-thr block) ----
__global__ __launch_bounds__(256) void rmsnorm_k(const float* __restrict__ x,
                                                 const float* __restrict__ w,
                                                 unsigned short* __restrict__ out) {
  int row  = blockIdx.x * 4 + (threadIdx.x >> 6);
  int lane = threadIdx.x & 63;
  const float* xr = x + (size_t)row * D_MODEL;
  f32x4 v0 = *(const f32x4*)(xr + lane * 8);
  f32x4 v1 = *(const f32x4*)(xr + lane * 8 + 4);
  float ss = v0.x*v0.x + v0.y*v0.y + v0.z*v0.z + v0.w*v0.w
           + v1.x*v1.x + v1.y*v1.y + v1.z*v1.z + v1.w*v1.w;
  #pragma unroll
  for (int m = 1; m < 64; m <<= 1) ss += __shfl_xor(ss, m, 64);
  float inv = 1.0f / (sqrtf(ss * (1.0f / D_MODEL)) + 1e-6f);
  f32x4 w0 = *(const f32x4*)(w + lane * 8);
  f32x4 w1 = *(const f32x4*)(w + lane * 8 + 4);
  u16x8 o;
  o[0] = f2bf(v0.x * w0.x * inv); o[1] = f2bf(v0.y * w0.y * inv);
  o[2] = f2bf(v0.z * w0.z * inv); o[3] = f2bf(v0.w * w0.w * inv);
  o[4] = f2bf(v1.x * w1.x * inv); o[5] = f2bf(v1.y * w1.y * inv);
  o[6] = f2bf(v1.z * w1.z * inv); o[7] = f2bf(v1.w * w1.w * inv);
  *(u16x8*)(out + (size_t)row * D_MODEL + lane * 8) = o;
}

// ---------------- GEMM v3 (unchanged structure) ----------------
#define EPI_QKV   0
#define EPI_PLAIN 1
#define EPI_GATE  2
#define EPI_RESID 3

template<int EPI, int BN>
__global__ __launch_bounds__(256) void gemm3_k(
    const unsigned short* __restrict__ A,
    const unsigned short* __restrict__ Bt,    // [N][K]
    const float* __restrict__ bias0,
    const float* __restrict__ bias1,
    const float* __restrict__ bias2,
    void* __restrict__ out0,
    void* __restrict__ out1,
    void* __restrict__ out2,
    int M, int N, int K)
{
  constexpr int WGN   = (BN == 128) ? 2 : 1;
  constexpr int MF    = (BN == 128) ? 4 : 2;
  constexpr int NF    = 4;
  constexpr int BROWS = BN / 4;

  __shared__ __attribute__((aligned(16))) unsigned short Al[2][128 * 64];
  __shared__ __attribute__((aligned(16))) unsigned short Bl[2][BN * 64];

  int nblk = gridDim.x;
  int orig = blockIdx.x;
  int qq = nblk >> 3, rr = nblk & 7, xcd = orig & 7, pos = orig >> 3;
  int lid = (xcd < rr ? xcd * (qq + 1) : rr * (qq + 1) + (xcd - rr) * qq) + pos;
  int numN = N / BN;
  int mt = lid / numN, nt = lid % numN;
  int m0 = mt * 128, n0 = nt * BN;

  int tid = threadIdx.x, lane = tid & 63, w = tid >> 6;
  int wm = w / WGN, wn = w % WGN;
  int g = lane >> 4, c = lane & 15;
  int srow = lane >> 3, scol = (lane & 7) * 8;

  const unsigned short* aG = A  + (size_t)(m0 + w * 32 + srow) * K + scol;
  const unsigned short* bG = Bt + (size_t)(n0 + w * BROWS + srow) * K + scol;
  unsigned short* aL = &Al[0][(w * 32 + srow) * 64 + scol];
  unsigned short* bL = &Bl[0][(w * BROWS + srow) * 64 + scol];

  f32x4 acc[MF][NF] = {};
  int KT = K >> 6;

  #pragma unroll
  for (int t = 0; t < 4; ++t)
    gload16(aG + (size_t)(t * 8) * K, aL + t * 8 * 64);
  #pragma unroll
  for (int t = 0; t < BROWS / 8; ++t)
    gload16(bG + (size_t)(t * 8) * K, bL + t * 8 * 64);

  for (int kt = 0; kt < KT; ++kt) {
    int buf = kt & 1;
    __syncthreads();
    if (kt + 1 < KT) {
      int nb = buf ^ 1;
      const unsigned short* aGk = aG + (kt + 1) * 64;
      const unsigned short* bGk = bG + (kt + 1) * 64;
      #pragma unroll
      for (int t = 0; t < 4; ++t)
        gload16(aGk + (size_t)(t * 8) * K, aL + nb * (128 * 64) + t * 8 * 64);
      #pragma unroll
      for (int t = 0; t < BROWS / 8; ++t)
        gload16(bGk + (size_t)(t * 8) * K, bL + nb * (BN * 64) + t * 8 * 64);
    }
    const unsigned short* Ab = &Al[buf][0];
    const unsigned short* Bb = &Bl[buf][0];
    #pragma unroll
    for (int ks = 0; ks < 2; ++ks) {
      bf16x8 af[MF], bfr[NF];
      #pragma unroll
      for (int i = 0; i < MF; ++i)
        af[i] = ldb8(Ab + (wm * (MF * 16) + i * 16 + c) * 64 + ks * 32 + g * 8);
      #pragma unroll
      for (int j = 0; j < NF; ++j)
        bfr[j] = ldb8(Bb + (wn * (NF * 16) + j * 16 + c) * 64 + ks * 32 + g * 8);
      #pragma unroll
      for (int i = 0; i < MF; ++i)
        #pragma unroll
        for (int j = 0; j < NF; ++j)
          acc[i][j] = mfma16(af[i], bfr[j], acc[i][j]);
    }
  }

  #pragma unroll
  for (int i = 0; i < MF; ++i) {
    int mrow = m0 + wm * (MF * 16) + i * 16 + g * 4;
    #pragma unroll
    for (int j = 0; j < NF; ++j) {
      int n = n0 + wn * (NF * 16) + j * 16 + c;
      if (EPI == EPI_QKV) {
        int sel  = n >> 9;
        int nloc = n & 511;
        const float* bp = sel == 0 ? bias0 : sel == 1 ? bias1 : bias2;
        unsigned short* o = (unsigned short*)(sel == 0 ? out0 : sel == 1 ? out1 : out2);
        float sc = (sel == 0) ? QSCALE : 1.0f;   // fold 1/sqrt(hd)*log2e into q
        float bn = bp[nloc];
        #pragma unroll
        for (int ii = 0; ii < 4; ++ii)
          o[(size_t)(mrow + ii) * D_MODEL + nloc] = f2bf((acc[i][j][ii] + bn) * sc);
      } else if (EPI == EPI_PLAIN) {
        float bn = bias0[n];
        unsigned short* o = (unsigned short*)out0;
        #pragma unroll
        for (int ii = 0; ii < 4; ++ii)
          o[(size_t)(mrow + ii) * N + n] = f2bf(acc[i][j][ii] + bn);
      } else if (EPI == EPI_GATE) {
        float bn = bias0[n];
        unsigned short* o = (unsigned short*)out0;
        #pragma unroll
        for (int ii = 0; ii < 4; ++ii) {
          size_t idx = (size_t)(mrow + ii) * N + n;
          float h1 = acc[i][j][ii] + bn;
          float s  = h1 / (1.0f + __expf(-h1));
          o[idx] = f2bf(bf2f(o[idx]) * s);
        }
      } else {  // EPI_RESID
        float bn = bias0[n];
        float* O = (float*)out0;
        #pragma unroll
        for (int ii = 0; ii < 4; ++ii) {
          size_t idx = (size_t)(mrow + ii) * N + n;
          O[idx] += acc[i][j][ii] + bn;
        }
      }
    }
  }
}

// ---------------- V transpose: v [B*S][512] -> vt [bh][d][s] ----------------
__global__ __launch_bounds__(64) void vtrans_k(const unsigned short* __restrict__ V,
                                               unsigned short* __restrict__ VT) {
  __shared__ unsigned short T[64][76];
  int t = threadIdx.x;
  int s0 = blockIdx.x * 64;
  int bh = blockIdx.y, b = bh >> 3, h = bh & 7;
  const unsigned short* src = V + (size_t)(b * SEQ + s0) * D_MODEL + h * HD;
  #pragma unroll
  for (int j0 = 0; j0 < 8; ++j0) {
    u16x8 vv = *(const u16x8*)(src + (size_t)t * D_MODEL + j0 * 8);
    *(u16x8*)&T[t][j0 * 8] = vv;
  }
  __syncthreads();
  unsigned short* dst = VT + ((size_t)bh * HD + t) * SEQ + s0;
  #pragma unroll
  for (int j0 = 0; j0 < 8; ++j0) {
    u16x8 o;
    #pragma unroll
    for (int j = 0; j < 8; ++j) o[j] = T[j0 * 8 + j][t];
    *(u16x8*)(dst + j0 * 8) = o;
  }
}

// ---------------- attention v4: swapped QK^T, P fully in-register ----------
struct Stg { uint4v k0, k1, v0, v1; };

static __device__ __forceinline__ Stg stage_load(const unsigned short* Kp,
                                                 const unsigned short* Vp,
                                                 int kbase, int srow, int sslot) {
  Stg s;
  const unsigned short* kr = Kp + (size_t)(kbase + srow) * D_MODEL + sslot * 8;
  s.k0 = *(const uint4v*)kr;
  s.k1 = *(const uint4v*)(kr + 32);
  const unsigned short* vr = Vp + (size_t)srow * SEQ + kbase + sslot * 8;
  s.v0 = *(const uint4v*)vr;
  s.v1 = *(const uint4v*)(vr + 32);
  return s;
}
static __device__ __forceinline__ void stage_write(unsigned short* Klb, unsigned short* Vlb,
                                                   const Stg& s, int srow, int sslot) {
  char* kb = (char*)Klb;
  *(uint4v*)(kb + SWZ(srow, srow * 128 + sslot * 16))       = s.k0;
  *(uint4v*)(kb + SWZ(srow, srow * 128 + (sslot + 4) * 16)) = s.k1;
  char* vb = (char*)Vlb;
  *(uint4v*)(vb + SWZ(srow, srow * 128 + sslot * 16))       = s.v0;
  *(uint4v*)(vb + SWZ(srow, srow * 128 + (sslot + 4) * 16)) = s.v1;
}

// one 64-key tile: swapped QK^T -> P in-register -> PV
template<bool MASKED>
static __device__ __forceinline__ void attn_tile(
    const unsigned short* Klb, const unsigned short* Vlb,
    bf16x8 qf0, bf16x8 qf1, f32x4* oacc, float& ps,
    int g, int c, int kbase, int qrow)
{
  // z[hh][i] = score(q = qrow(c), k = kbase + hh*16 + g*4 + i)
  f32x4 z[4];
  #pragma unroll
  for (int hh = 0; hh < 4; ++hh) {
    int r = hh * 16 + c;
    const char* base = (const char*)Klb;
    bf16x8 k0 = ldb8((const unsigned short*)(base + SWZ(r, r * 128 + g * 16)));
    bf16x8 k1 = ldb8((const unsigned short*)(base + SWZ(r, r * 128 + 64 + g * 16)));
    f32x4 t = {};
    t = mfma16(k0, qf0, t);   // swapped: K rows as A, Q rows as B
    t = mfma16(k1, qf1, t);
    z[hh] = t;
  }
  // exp2 (log2e folded into Q), mask, row-sum, pack A-fragments
  u16x8 pa0, pa1;
  #pragma unroll
  for (int hh = 0; hh < 4; ++hh) {
    #pragma unroll
    for (int i = 0; i < 4; ++i) {
      float p = exp2f(z[hh][i]);
      if (MASKED && (kbase + hh * 16 + g * 4 + i > qrow)) p = 0.0f;
      ps += p;
      unsigned short pb = f2bf(p);
      if (hh < 2) pa0[hh * 4 + i] = pb;
      else        pa1[(hh - 2) * 4 + i] = pb;
    }
  }
  bf16x8 af0 = __builtin_bit_cast(bf16x8, pa0);
  bf16x8 af1 = __builtin_bit_cast(bf16x8, pa1);
  // PV: B-frag slots mirror af k-permutation: j<4 -> k=g*4+j, j>=4 -> k=16+g*4+j-4
  #pragma unroll
  for (int db = 0; db < 4; ++db) {
    int r = db * 16 + c;
    const char* base = (const char*)Vlb;
    u16x4 v00 = *(const u16x4*)(base + SWZ(r, r * 128 + g * 8));
    u16x4 v01 = *(const u16x4*)(base + SWZ(r, r * 128 + 32 + g * 8));
    u16x4 v10 = *(const u16x4*)(base + SWZ(r, r * 128 + 64 + g * 8));
    u16x4 v11 = *(const u16x4*)(base + SWZ(r, r * 128 + 96 + g * 8));
    u16x8 vb0, vb1;
    #pragma unroll
    for (int j = 0; j < 4; ++j) {
      vb0[j] = v00[j]; vb0[4 + j] = v01[j];
      vb1[j] = v10[j]; vb1[4 + j] = v11[j];
    }
    oacc[db] = mfma16(af0, __builtin_bit_cast(bf16x8, vb0), oacc[db]);
    oacc[db] = mfma16(af1, __builtin_bit_cast(bf16x8, vb1), oacc[db]);
  }
}

__global__ __launch_bounds__(256) void attn4_k(const unsigned short* __restrict__ Q,
                                               const unsigned short* __restrict__ K,
                                               const unsigned short* __restrict__ VT,
                                               unsigned short* __restrict__ O)
{
  __shared__ __attribute__((aligned(16))) unsigned short Kl[2][64 * 64];
  __shared__ __attribute__((aligned(16))) unsigned short Vl[2][64 * 64];
  int tid = threadIdx.x, lane = tid & 63, w = tid >> 6;
  int g = lane >> 4, c = lane & 15;
  int chunk = 31 - (int)blockIdx.x;     // heavy blocks first
  int bh = blockIdx.y, b = bh >> 3, h = bh & 7;
  int q0 = chunk * 64;
  int nt = chunk + 1;
  const unsigned short* Qp = Q + (size_t)(b * SEQ) * D_MODEL + h * HD;
  const unsigned short* Kp = K + (size_t)(b * SEQ) * D_MODEL + h * HD;
  const unsigned short* Vp = VT + (size_t)bh * HD * SEQ;

  int qrow = q0 + w * 16 + c;
  bf16x8 qf0 = ldb8(Qp + (size_t)qrow * D_MODEL + g * 8);
  bf16x8 qf1 = ldb8(Qp + (size_t)qrow * D_MODEL + 32 + g * 8);

  f32x4 oacc[4] = {};
  float ps = 0.0f;
  int srow = tid >> 2, sslot = tid & 3;

  Stg s0 = stage_load(Kp, Vp, 0, srow, sslot);
  stage_write(&Kl[0][0], &Vl[0][0], s0, srow, sslot);
  __syncthreads();

  int buf = 0;
  for (int kt = 0; kt < nt - 1; ++kt) {
    Stg sn = stage_load(Kp, Vp, (kt + 1) * 64, srow, sslot);
    attn_tile<false>(&Kl[buf][0], &Vl[buf][0], qf0, qf1, oacc, ps, g, c, 0, 0);
    stage_write(&Kl[buf ^ 1][0], &Vl[buf ^ 1][0], sn, srow, sslot);
    __syncthreads();
    buf ^= 1;
  }
  attn_tile<true>(&Kl[buf][0], &Vl[buf][0], qf0, qf1, oacc, ps, g, c,
                  q0, qrow);

  // full row-sum for q = c: reduce over the 4 g-lanes
  ps += __shfl_xor(ps, 16, 64);
  ps += __shfl_xor(ps, 32, 64);
  f32x4 inv;
  #pragma unroll
  for (int i = 0; i < 4; ++i) inv[i] = 1.0f / __shfl(ps, g * 4 + i, 64);

  #pragma unroll
  for (int db = 0; db < 4; ++db)
    #pragma unroll
    for (int i = 0; i < 4; ++i)
      O[(size_t)(b * SEQ + q0 + w * 16 + g * 4 + i) * D_MODEL + h * HD + db * 16 + c] =
          f2bf(oacc[db][i] * inv[i]);
}

// ---------------- launch ----------------
extern "C" void kernel_launch(void* const* d_in, const int* in_sizes, int n_in,
                              void* d_out, int out_size, void* d_ws, size_t ws_size,
                              hipStream_t stream) {
  (void)in_sizes; (void)n_in; (void)out_size; (void)ws_size;
  const float* x   = (const float*)d_in[0];
  const float* qw  = (const float*)d_in[1];
  const float* qb  = (const float*)d_in[2];
  const float* kw  = (const float*)d_in[3];
  const float* kbi = (const float*)d_in[4];
  const float* vw  = (const float*)d_in[5];
  const float* vb  = (const float*)d_in[6];
  const float* ow  = (const float*)d_in[7];
  const float* ob  = (const float*)d_in[8];
  const float* w0  = (const float*)d_in[9];
  const float* b0  = (const float*)d_in[10];
  const float* w1  = (const float*)d_in[11];
  const float* b1  = (const float*)d_in[12];
  const float* w2  = (const float*)d_in[13];
  const float* b2  = (const float*)d_in[14];
  const float* anw = (const float*)d_in[15];
  const float* fnw = (const float*)d_in[16];

  char* ws = (char*)d_ws;
  float*          h    = (float*)ws;                              // 0..8MB fp32 residual
  unsigned short* xn   = (unsigned short*)(ws + (8u  << 20));     // 4MB (aliases vt)
  unsigned short* vt   = (unsigned short*)(ws + (8u  << 20));     // 4MB [bh][d][s]
  unsigned short* q    = (unsigned short*)(ws + (12u << 20));     // 4MB
  unsigned short* k    = (unsigned short*)(ws + (16u << 20));     // 4MB
  unsigned short* v    = (unsigned short*)(ws + (20u << 20));     // 4MB
  unsigned short* ao   = (unsigned short*)(ws + (24u << 20));     // 4MB
  unsigned short* hbuf = (unsigned short*)(ws + (12u << 20));     // 16MB (aliases q,k,v,ao)
  unsigned short* Wq   = (unsigned short*)(ws + (28u << 20));     // 6MB
  unsigned short* Wo   = (unsigned short*)(ws + (34u << 20));     // 2MB
  unsigned short* W01  = (unsigned short*)(ws + (36u << 20));     // 16MB
  unsigned short* W2   = (unsigned short*)(ws + (52u << 20));     // 8MB

  prep_t<<<4096, 64, 0, stream>>>(qw, kw, vw, ow, w0, w1, w2, Wq, Wo, W01, W2);
  hipMemcpyAsync(h, x, (size_t)BTOK * D_MODEL * sizeof(float),
                 hipMemcpyDeviceToDevice, stream);

  for (int l = 0; l < 4; ++l) {
    size_t bo  = (size_t)l * D_MODEL;
    size_t bho = (size_t)l * HIDE;

    rmsnorm_k<<<BTOK / 4, 256, 0, stream>>>(h, anw + bo, xn);
    gemm3_k<EPI_QKV, 128><<<384, 256, 0, stream>>>(
        xn, Wq + (size_t)l * 786432, qb + bo, kbi + bo, vb + bo,
        q, k, v, BTOK, 3 * D_MODEL, D_MODEL);
    vtrans_k<<<dim3(32, 16), 64, 0, stream>>>(v, vt);
    attn4_k<<<dim3(32, 16), 256, 0, stream>>>(q, k, vt, ao);
    gemm3_k<EPI_RESID, 64><<<256, 256, 0, stream>>>(
        ao, Wo + (size_t)l * 262144, ob + bo, nullptr, nullptr,
        h, nullptr, nullptr, BTOK, D_MODEL, D_MODEL);

    rmsnorm_k<<<BTOK / 4, 256, 0, stream>>>(h, fnw + bo, xn);
    gemm3_k<EPI_PLAIN, 128><<<512, 256, 0, stream>>>(
        xn, W01 + (size_t)l * 2097152, b0 + bho, nullptr, nullptr,
        hbuf, nullptr, nullptr, BTOK, HIDE, D_MODEL);
    gemm3_k<EPI_GATE, 128><<<512, 256, 0, stream>>>(
        xn, W01 + (size_t)l * 2097152 + 1048576, b1 + bho, nullptr, nullptr,
        hbuf, nullptr, nullptr, BTOK, HIDE, D_MODEL);
    gemm3_k<EPI_RESID, 64><<<256, 256, 0, stream>>>(
        hbuf, W2 + (size_t)l * 1048576, b2 + bo, nullptr, nullptr,
        h, nullptr, nullptr, BTOK, D_MODEL, HIDE);
  }
  hipMemcpyAsync(d_out, h, (size_t)BTOK * D_MODEL * sizeof(float),
                 hipMemcpyDeviceToDevice, stream);
}

// Round 7
// 675.707 us; speedup vs baseline: 2.4151x; 1.0527x over previous
//
#include <hip/hip_runtime.h>
#include <math.h>

// ---------------- types ----------------
typedef unsigned int   uint4v __attribute__((ext_vector_type(4)));
typedef float          f32x4  __attribute__((ext_vector_type(4)));
typedef __bf16         bf16x8 __attribute__((ext_vector_type(8)));
typedef unsigned short u16x8  __attribute__((ext_vector_type(8)));
typedef unsigned short u16x4  __attribute__((ext_vector_type(4)));

#define D_MODEL 512
#define SEQ     2048
#define BTOK    4096   // B * SEQ
#define HIDE    2048
#define NHEAD   8
#define HD      64

static __device__ __forceinline__ unsigned short f2bf(float f) {
  __bf16 b = (__bf16)f;                      // native RNE cvt (packable)
  return __builtin_bit_cast(unsigned short, b);
}
static __device__ __forceinline__ float bf2f(unsigned short b) {
  union { unsigned u; float f; } v; v.u = ((unsigned)b) << 16;
  return v.f;
}
static __device__ __forceinline__ bf16x8 ldb8(const unsigned short* p) {
  return __builtin_bit_cast(bf16x8, *(const uint4v*)p);
}
static __device__ __forceinline__ f32x4 mfma16(bf16x8 a, bf16x8 b, f32x4 c) {
  return __builtin_amdgcn_mfma_f32_16x16x32_bf16(a, b, c, 0, 0, 0);
}

typedef unsigned int u32_g __attribute__((address_space(1)));
typedef unsigned int u32_l __attribute__((address_space(3)));
static __device__ __forceinline__ void gload16(const unsigned short* g, unsigned short* l) {
  __builtin_amdgcn_global_load_lds((const u32_g*)(const void*)g,
                                   (u32_l*)(void*)l, 16, 0, 0);
}

#define SWZ(r, off) ((off) ^ (((r) & 7) << 4))
#define QSCALE 0.180336880f   // 0.125 * log2(e)

// ---------------- weight prep: LDS-tiled transpose f32 [K][N] -> bf16 [N][K] ----
__global__ __launch_bounds__(64) void prep_t(
    const float* __restrict__ qw, const float* __restrict__ kw,
    const float* __restrict__ vw, const float* __restrict__ ow,
    const float* __restrict__ w0, const float* __restrict__ w1,
    const float* __restrict__ w2,
    unsigned short* __restrict__ Wq, unsigned short* __restrict__ Wo,
    unsigned short* __restrict__ W01, unsigned short* __restrict__ W2)
{
  int bid = blockIdx.x;
  int l = bid >> 10;
  int r = bid & 1023;
  const float* src; unsigned short* dst;
  int tr, tc, srcN, dstK;
  if (r < 192) {
    int sel = r >> 6, tt = r & 63;
    tr = tt >> 3; tc = tt & 7;
    src = (sel == 0 ? qw : sel == 1 ? kw : vw) + (size_t)l * 262144;
    srcN = 512; dstK = 512;
    dst = Wq + (size_t)l * 786432 + (size_t)(sel * 512 + tc * 64) * 512 + tr * 64;
  } else if (r < 256) {
    int tt = r - 192; tr = tt >> 3; tc = tt & 7;
    src = ow + (size_t)l * 262144; srcN = 512; dstK = 512;
    dst = Wo + (size_t)l * 262144 + (size_t)(tc * 64) * 512 + tr * 64;
  } else if (r < 768) {
    int idx = r - 256; int sel = idx >> 8; int tt = idx & 255;
    tr = tt >> 5; tc = tt & 31;
    src = (sel ? w1 : w0) + (size_t)l * 1048576; srcN = 2048; dstK = 512;
    dst = W01 + (size_t)l * 2097152 + (size_t)sel * 1048576 + (size_t)(tc * 64) * 512 + tr * 64;
  } else {
    int tt = r - 768; tr = tt >> 3; tc = tt & 7;
    src = w2 + (size_t)l * 1048576; srcN = 512; dstK = 2048;
    dst = W2 + (size_t)l * 1048576 + (size_t)(tc * 64) * 2048 + tr * 64;
  }
  src += (size_t)(tr * 64) * srcN + tc * 64;
  __shared__ unsigned short T[64][68];
  int t = threadIdx.x;
  #pragma unroll
  for (int it = 0; it < 16; ++it) {
    int row = it * 4 + (t >> 4);
    int col = (t & 15) * 4;
    f32x4 v4 = *(const f32x4*)(src + (size_t)row * srcN + col);
    u16x4 o; o[0] = f2bf(v4.x); o[1] = f2bf(v4.y); o[2] = f2bf(v4.z); o[3] = f2bf(v4.w);
    *(u16x4*)&T[row][col] = o;
  }
  __syncthreads();
  unsigned short* orow = dst + (size_t)t * dstK;
  #pragma unroll
  for (int j0 = 0; j0 < 8; ++j0) {
    u16x8 o;
    #pragma unroll
    for (int j = 0; j < 8; ++j) o[j] = T[j0 * 8 + j][t];
    *(u16x8*)(orow + j0 * 8) = o;
  }
}

// ---------------- RMSNorm: fp32 in -> bf16 out (4 rows / 256-thr block) ----
__global__ __launch_bounds__(256) void rmsnorm_k(const float* __restrict__ x,
                                                 const float* __restrict__ w,
                                                 unsigned short* __restrict__ out) {
  int row  = blockIdx.x * 4 + (threadIdx.x >> 6);
  int lane = threadIdx.x & 63;
  const float* xr = x + (size_t)row * D_MODEL;
  f32x4 v0 = *(const f32x4*)(xr + lane * 8);
  f32x4 v1 = *(const f32x4*)(xr + lane * 8 + 4);
  float ss = v0.x*v0.x + v0.y*v0.y + v0.z*v0.z + v0.w*v0.w
           + v1.x*v1.x + v1.y*v1.y + v1.z*v1.z + v1.w*v1.w;
  #pragma unroll
  for (int m = 1; m < 64; m <<= 1) ss += __shfl_xor(ss, m, 64);
  float inv = 1.0f / (sqrtf(ss * (1.0f / D_MODEL)) + 1e-6f);
  f32x4 w0 = *(const f32x4*)(w + lane * 8);
  f32x4 w1 = *(const f32x4*)(w + lane * 8 + 4);
  u16x8 o;
  o[0] = f2bf(v0.x * w0.x * inv); o[1] = f2bf(v0.y * w0.y * inv);
  o[2] = f2bf(v0.z * w0.z * inv); o[3] = f2bf(v0.w * w0.w * inv);
  o[4] = f2bf(v1.x * w1.x * inv); o[5] = f2bf(v1.y * w1.y * inv);
  o[6] = f2bf(v1.z * w1.z * inv); o[7] = f2bf(v1.w * w1.w * inv);
  *(u16x8*)(out + (size_t)row * D_MODEL + lane * 8) = o;
}

// ---------------- GEMM v3 (unchanged structure) ----------------
#define EPI_QKV   0
#define EPI_PLAIN 1
#define EPI_GATE  2
#define EPI_RESID 3

template<int EPI, int BN>
__global__ __launch_bounds__(256) void gemm3_k(
    const unsigned short* __restrict__ A,
    const unsigned short* __restrict__ Bt,    // [N][K]
    const float* __restrict__ bias0,
    const float* __restrict__ bias1,
    const float* __restrict__ bias2,
    void* __restrict__ out0,
    void* __restrict__ out1,
    void* __restrict__ out2,
    int M, int N, int K)
{
  constexpr int WGN   = (BN == 128) ? 2 : 1;
  constexpr int MF    = (BN == 128) ? 4 : 2;
  constexpr int NF    = 4;
  constexpr int BROWS = BN / 4;

  __shared__ __attribute__((aligned(16))) unsigned short Al[2][128 * 64];
  __shared__ __attribute__((aligned(16))) unsigned short Bl[2][BN * 64];

  int nblk = gridDim.x;
  int orig = blockIdx.x;
  int qq = nblk >> 3, rr = nblk & 7, xcd = orig & 7, pos = orig >> 3;
  int lid = (xcd < rr ? xcd * (qq + 1) : rr * (qq + 1) + (xcd - rr) * qq) + pos;
  int numN = N / BN;
  int mt = lid / numN, nt = lid % numN;
  int m0 = mt * 128, n0 = nt * BN;

  int tid = threadIdx.x, lane = tid & 63, w = tid >> 6;
  int wm = w / WGN, wn = w % WGN;
  int g = lane >> 4, c = lane & 15;
  int srow = lane >> 3, scol = (lane & 7) * 8;

  const unsigned short* aG = A  + (size_t)(m0 + w * 32 + srow) * K + scol;
  const unsigned short* bG = Bt + (size_t)(n0 + w * BROWS + srow) * K + scol;
  unsigned short* aL = &Al[0][(w * 32 + srow) * 64 + scol];
  unsigned short* bL = &Bl[0][(w * BROWS + srow) * 64 + scol];

  f32x4 acc[MF][NF] = {};
  int KT = K >> 6;

  #pragma unroll
  for (int t = 0; t < 4; ++t)
    gload16(aG + (size_t)(t * 8) * K, aL + t * 8 * 64);
  #pragma unroll
  for (int t = 0; t < BROWS / 8; ++t)
    gload16(bG + (size_t)(t * 8) * K, bL + t * 8 * 64);

  for (int kt = 0; kt < KT; ++kt) {
    int buf = kt & 1;
    __syncthreads();
    if (kt + 1 < KT) {
      int nb = buf ^ 1;
      const unsigned short* aGk = aG + (kt + 1) * 64;
      const unsigned short* bGk = bG + (kt + 1) * 64;
      #pragma unroll
      for (int t = 0; t < 4; ++t)
        gload16(aGk + (size_t)(t * 8) * K, aL + nb * (128 * 64) + t * 8 * 64);
      #pragma unroll
      for (int t = 0; t < BROWS / 8; ++t)
        gload16(bGk + (size_t)(t * 8) * K, bL + nb * (BN * 64) + t * 8 * 64);
    }
    const unsigned short* Ab = &Al[buf][0];
    const unsigned short* Bb = &Bl[buf][0];
    #pragma unroll
    for (int ks = 0; ks < 2; ++ks) {
      bf16x8 af[MF], bfr[NF];
      #pragma unroll
      for (int i = 0; i < MF; ++i)
        af[i] = ldb8(Ab + (wm * (MF * 16) + i * 16 + c) * 64 + ks * 32 + g * 8);
      #pragma unroll
      for (int j = 0; j < NF; ++j)
        bfr[j] = ldb8(Bb + (wn * (NF * 16) + j * 16 + c) * 64 + ks * 32 + g * 8);
      #pragma unroll
      for (int i = 0; i < MF; ++i)
        #pragma unroll
        for (int j = 0; j < NF; ++j)
          acc[i][j] = mfma16(af[i], bfr[j], acc[i][j]);
    }
  }

  #pragma unroll
  for (int i = 0; i < MF; ++i) {
    int mrow = m0 + wm * (MF * 16) + i * 16 + g * 4;
    #pragma unroll
    for (int j = 0; j < NF; ++j) {
      int n = n0 + wn * (NF * 16) + j * 16 + c;
      if (EPI == EPI_QKV) {
        int sel  = n >> 9;
        int nloc = n & 511;
        const float* bp = sel == 0 ? bias0 : sel == 1 ? bias1 : bias2;
        unsigned short* o = (unsigned short*)(sel == 0 ? out0 : sel == 1 ? out1 : out2);
        float sc = (sel == 0) ? QSCALE : 1.0f;   // fold 1/sqrt(hd)*log2e into q
        float bn = bp[nloc];
        #pragma unroll
        for (int ii = 0; ii < 4; ++ii)
          o[(size_t)(mrow + ii) * D_MODEL + nloc] = f2bf((acc[i][j][ii] + bn) * sc);
      } else if (EPI == EPI_PLAIN) {
        float bn = bias0[n];
        unsigned short* o = (unsigned short*)out0;
        #pragma unroll
        for (int ii = 0; ii < 4; ++ii)
          o[(size_t)(mrow + ii) * N + n] = f2bf(acc[i][j][ii] + bn);
      } else if (EPI == EPI_GATE) {
        float bn = bias0[n];
        unsigned short* o = (unsigned short*)out0;
        #pragma unroll
        for (int ii = 0; ii < 4; ++ii) {
          size_t idx = (size_t)(mrow + ii) * N + n;
          float h1 = acc[i][j][ii] + bn;
          float s  = h1 / (1.0f + __expf(-h1));
          o[idx] = f2bf(bf2f(o[idx]) * s);
        }
      } else {  // EPI_RESID
        float bn = bias0[n];
        float* O = (float*)out0;
        #pragma unroll
        for (int ii = 0; ii < 4; ++ii) {
          size_t idx = (size_t)(mrow + ii) * N + n;
          O[idx] += acc[i][j][ii] + bn;
        }
      }
    }
  }
}

// ---------------- V transpose: v [B*S][512] -> vt [bh][d][s] ----------------
__global__ __launch_bounds__(64) void vtrans_k(const unsigned short* __restrict__ V,
                                               unsigned short* __restrict__ VT) {
  __shared__ unsigned short T[64][76];
  int t = threadIdx.x;
  int s0 = blockIdx.x * 64;
  int bh = blockIdx.y, b = bh >> 3, h = bh & 7;
  const unsigned short* src = V + (size_t)(b * SEQ + s0) * D_MODEL + h * HD;
  #pragma unroll
  for (int j0 = 0; j0 < 8; ++j0) {
    u16x8 vv = *(const u16x8*)(src + (size_t)t * D_MODEL + j0 * 8);
    *(u16x8*)&T[t][j0 * 8] = vv;
  }
  __syncthreads();
  unsigned short* dst = VT + ((size_t)bh * HD + t) * SEQ + s0;
  #pragma unroll
  for (int j0 = 0; j0 < 8; ++j0) {
    u16x8 o;
    #pragma unroll
    for (int j = 0; j < 8; ++j) o[j] = T[j0 * 8 + j][t];
    *(u16x8*)(dst + j0 * 8) = o;
  }
}

// ---------------- attention v5: split-K flash, no-max softmax ------------
// Work unit: (bh, q-chunk of 64, key-split of <=8 kv-tiles). Partials are
// exactly linear (no-max): O_tot = sum O_s, s_tot = sum s_s.
struct Stg { uint4v k0, k1, v0, v1; };

static __device__ __forceinline__ Stg stage_load(const unsigned short* Kp,
                                                 const unsigned short* Vp,
                                                 int kbase, int srow, int sslot) {
  Stg s;
  const unsigned short* kr = Kp + (size_t)(kbase + srow) * D_MODEL + sslot * 8;
  s.k0 = *(const uint4v*)kr;
  s.k1 = *(const uint4v*)(kr + 32);
  const unsigned short* vr = Vp + (size_t)srow * SEQ + kbase + sslot * 8;
  s.v0 = *(const uint4v*)vr;
  s.v1 = *(const uint4v*)(vr + 32);
  return s;
}
static __device__ __forceinline__ void stage_write(unsigned short* Klb, unsigned short* Vlb,
                                                   const Stg& s, int srow, int sslot) {
  char* kb = (char*)Klb;
  *(uint4v*)(kb + SWZ(srow, srow * 128 + sslot * 16))       = s.k0;
  *(uint4v*)(kb + SWZ(srow, srow * 128 + (sslot + 4) * 16)) = s.k1;
  char* vb = (char*)Vlb;
  *(uint4v*)(vb + SWZ(srow, srow * 128 + sslot * 16))       = s.v0;
  *(uint4v*)(vb + SWZ(srow, srow * 128 + (sslot + 4) * 16)) = s.v1;
}

template<bool MASKED>
static __device__ __forceinline__ void attn_tile(
    const unsigned short* Klb, const unsigned short* Vlb,
    bf16x8 qf0, bf16x8 qf1, f32x4* oacc, float& ps,
    int g, int c, int kbase, int qrow)
{
  f32x4 z[4];
  #pragma unroll
  for (int hh = 0; hh < 4; ++hh) {
    int r = hh * 16 + c;
    const char* base = (const char*)Klb;
    bf16x8 k0 = ldb8((const unsigned short*)(base + SWZ(r, r * 128 + g * 16)));
    bf16x8 k1 = ldb8((const unsigned short*)(base + SWZ(r, r * 128 + 64 + g * 16)));
    f32x4 t = {};
    t = mfma16(k0, qf0, t);   // swapped: K rows as A, Q rows as B
    t = mfma16(k1, qf1, t);
    z[hh] = t;
  }
  u16x8 pa0, pa1;
  #pragma unroll
  for (int hh = 0; hh < 4; ++hh) {
    #pragma unroll
    for (int i = 0; i < 4; ++i) {
      float p = exp2f(z[hh][i]);
      if (MASKED && (kbase + hh * 16 + g * 4 + i > qrow)) p = 0.0f;
      ps += p;
      unsigned short pb = f2bf(p);
      if (hh < 2) pa0[hh * 4 + i] = pb;
      else        pa1[(hh - 2) * 4 + i] = pb;
    }
  }
  bf16x8 af0 = __builtin_bit_cast(bf16x8, pa0);
  bf16x8 af1 = __builtin_bit_cast(bf16x8, pa1);
  #pragma unroll
  for (int db = 0; db < 4; ++db) {
    int r = db * 16 + c;
    const char* base = (const char*)Vlb;
    u16x4 v00 = *(const u16x4*)(base + SWZ(r, r * 128 + g * 8));
    u16x4 v01 = *(const u16x4*)(base + SWZ(r, r * 128 + 32 + g * 8));
    u16x4 v10 = *(const u16x4*)(base + SWZ(r, r * 128 + 64 + g * 8));
    u16x4 v11 = *(const u16x4*)(base + SWZ(r, r * 128 + 96 + g * 8));
    u16x8 vb0, vb1;
    #pragma unroll
    for (int j = 0; j < 4; ++j) {
      vb0[j] = v00[j]; vb0[4 + j] = v01[j];
      vb1[j] = v10[j]; vb1[4 + j] = v11[j];
    }
    oacc[db] = mfma16(af0, __builtin_bit_cast(bf16x8, vb0), oacc[db]);
    oacc[db] = mfma16(af1, __builtin_bit_cast(bf16x8, vb1), oacc[db]);
  }
}

__global__ __launch_bounds__(256) void attn5_k(const unsigned short* __restrict__ Q,
                                               const unsigned short* __restrict__ K,
                                               const unsigned short* __restrict__ VT,
                                               unsigned short* __restrict__ O,
                                               float* __restrict__ Oparts,
                                               float* __restrict__ Sparts)
{
  __shared__ __attribute__((aligned(16))) unsigned short Kl[2][64 * 64];
  __shared__ __attribute__((aligned(16))) unsigned short Vl[2][64 * 64];
  int tid = threadIdx.x, lane = tid & 63, w = tid >> 6;
  int g = lane >> 4, cl = lane & 15;

  // decode (chunk c, split s) from z = 79-blockIdx.x (heavy-first)
  int z = 79 - (int)blockIdx.x;
  int c, sp;
  if (z < 8)        { c = z;                    sp = 0; }
  else if (z < 24)  { int t2 = z - 8;  c = 8  + (t2 >> 1); sp = t2 & 1; }
  else if (z < 48)  { int t2 = z - 24; c = 16 + t2 / 3;    sp = t2 % 3; }
  else              { int t2 = z - 48; c = 24 + (t2 >> 2); sp = t2 & 3; }
  int kt0 = sp * 8;
  int kt1 = min(c + 1, kt0 + 8);
  bool lastsplit = (kt1 == c + 1);

  int bh = blockIdx.y, b = bh >> 3, h = bh & 7;
  int q0 = c * 64;
  const unsigned short* Qp = Q + (size_t)(b * SEQ) * D_MODEL + h * HD;
  const unsigned short* Kp = K + (size_t)(b * SEQ) * D_MODEL + h * HD;
  const unsigned short* Vp = VT + (size_t)bh * HD * SEQ;

  int qrow = q0 + w * 16 + cl;
  bf16x8 qf0 = ldb8(Qp + (size_t)qrow * D_MODEL + g * 8);
  bf16x8 qf1 = ldb8(Qp + (size_t)qrow * D_MODEL + 32 + g * 8);

  f32x4 oacc[4] = {};
  float ps = 0.0f;
  int srow = tid >> 2, sslot = tid & 3;

  Stg s0 = stage_load(Kp, Vp, kt0 * 64, srow, sslot);
  stage_write(&Kl[0][0], &Vl[0][0], s0, srow, sslot);
  __syncthreads();

  int buf = 0;
  for (int kt = kt0; kt < kt1 - 1; ++kt) {
    Stg sn = stage_load(Kp, Vp, (kt + 1) * 64, srow, sslot);
    attn_tile<false>(&Kl[buf][0], &Vl[buf][0], qf0, qf1, oacc, ps, g, cl, 0, 0);
    stage_write(&Kl[buf ^ 1][0], &Vl[buf ^ 1][0], sn, srow, sslot);
    __syncthreads();
    buf ^= 1;
  }
  if (lastsplit)
    attn_tile<true>(&Kl[buf][0], &Vl[buf][0], qf0, qf1, oacc, ps, g, cl,
                    (kt1 - 1) * 64, qrow);
  else
    attn_tile<false>(&Kl[buf][0], &Vl[buf][0], qf0, qf1, oacc, ps, g, cl, 0, 0);

  // full row-sum for q = cl over this block's key range
  ps += __shfl_xor(ps, 16, 64);
  ps += __shfl_xor(ps, 32, 64);

  if (c < 8) {
    // single split: normalize and write bf16 directly
    f32x4 inv;
    #pragma unroll
    for (int i = 0; i < 4; ++i) inv[i] = 1.0f / __shfl(ps, g * 4 + i, 64);
    #pragma unroll
    for (int db = 0; db < 4; ++db)
      #pragma unroll
      for (int i = 0; i < 4; ++i)
        O[(size_t)(b * SEQ + q0 + w * 16 + g * 4 + i) * D_MODEL + h * HD + db * 16 + cl] =
            f2bf(oacc[db][i] * inv[i]);
  } else {
    size_t slot = ((size_t)bh * 24 + (c - 8)) * 4 + sp;
    float* Op = Oparts + slot * 4096;
    float* Sp = Sparts + slot * 64;
    #pragma unroll
    for (int db = 0; db < 4; ++db)
      #pragma unroll
      for (int i = 0; i < 4; ++i)
        Op[(w * 16 + g * 4 + i) * 64 + db * 16 + cl] = oacc[db][i];
    if (g == 0) Sp[w * 16 + cl] = ps;
  }
}

// combine partials for chunks 8..31: O = sum(Op)/sum(Sp)
__global__ __launch_bounds__(256) void attn_comb_k(const float* __restrict__ Oparts,
                                                   const float* __restrict__ Sparts,
                                                   unsigned short* __restrict__ O) {
  int t  = threadIdx.x;
  int c  = 8 + (int)(blockIdx.x % 24);
  int bh = (int)(blockIdx.x / 24);
  int b = bh >> 3, h = bh & 7;
  int ns = (c + 8) >> 3;                 // ceil((c+1)/8), c>=8
  size_t slot = ((size_t)bh * 24 + (c - 8)) * 4;
  const float* O0 = Oparts + slot * 4096;
  const float* S0 = Sparts + slot * 64;
  int r = t >> 2, d0 = (t & 3) * 16;
  f32x4 a0 = {}, a1 = {}, a2 = {}, a3 = {};
  float s = 0.0f;
  for (int si = 0; si < ns; ++si) {
    const float* o = O0 + si * 4096 + r * 64 + d0;
    a0 += *(const f32x4*)(o);
    a1 += *(const f32x4*)(o + 4);
    a2 += *(const f32x4*)(o + 8);
    a3 += *(const f32x4*)(o + 12);
    s  += S0[si * 64 + r];
  }
  float inv = 1.0f / s;
  u16x8 w0, w1;
  #pragma unroll
  for (int j = 0; j < 4; ++j) {
    w0[j]     = f2bf(a0[j] * inv); w0[4 + j] = f2bf(a1[j] * inv);
    w1[j]     = f2bf(a2[j] * inv); w1[4 + j] = f2bf(a3[j] * inv);
  }
  unsigned short* dst = O + (size_t)(b * SEQ + c * 64 + r) * D_MODEL + h * HD + d0;
  *(u16x8*)(dst)     = w0;
  *(u16x8*)(dst + 8) = w1;
}

// ---------------- launch ----------------
extern "C" void kernel_launch(void* const* d_in, const int* in_sizes, int n_in,
                              void* d_out, int out_size, void* d_ws, size_t ws_size,
                              hipStream_t stream) {
  (void)in_sizes; (void)n_in; (void)out_size; (void)ws_size;
  const float* x   = (const float*)d_in[0];
  const float* qw  = (const float*)d_in[1];
  const float* qb  = (const float*)d_in[2];
  const float* kw  = (const float*)d_in[3];
  const float* kbi = (const float*)d_in[4];
  const float* vw  = (const float*)d_in[5];
  const float* vb  = (const float*)d_in[6];
  const float* ow  = (const float*)d_in[7];
  const float* ob  = (const float*)d_in[8];
  const float* w0  = (const float*)d_in[9];
  const float* b0  = (const float*)d_in[10];
  const float* w1  = (const float*)d_in[11];
  const float* b1  = (const float*)d_in[12];
  const float* w2  = (const float*)d_in[13];
  const float* b2  = (const float*)d_in[14];
  const float* anw = (const float*)d_in[15];
  const float* fnw = (const float*)d_in[16];

  char* ws = (char*)d_ws;
  float*          h    = (float*)ws;                              // 0..8MB fp32 residual
  unsigned short* xn   = (unsigned short*)(ws + (8u  << 20));     // 4MB (aliases vt)
  unsigned short* vt   = (unsigned short*)(ws + (8u  << 20));     // 4MB [bh][d][s]
  unsigned short* q    = (unsigned short*)(ws + (12u << 20));     // 4MB
  unsigned short* k    = (unsigned short*)(ws + (16u << 20));     // 4MB
  unsigned short* v    = (unsigned short*)(ws + (20u << 20));     // 4MB
  unsigned short* ao   = (unsigned short*)(ws + (24u << 20));     // 4MB
  unsigned short* hbuf = (unsigned short*)(ws + (12u << 20));     // 16MB (aliases q,k,v,ao)
  unsigned short* Wq   = (unsigned short*)(ws + (28u << 20));     // 6MB
  unsigned short* Wo   = (unsigned short*)(ws + (34u << 20));     // 2MB
  unsigned short* W01  = (unsigned short*)(ws + (36u << 20));     // 16MB
  unsigned short* W2   = (unsigned short*)(ws + (52u << 20));     // 8MB
  float*          Opar = (float*)(ws + (60u << 20));              // 24MB (1536 x 16KB)
  float*          Spar = (float*)(ws + (84u << 20));              // 0.4MB

  prep_t<<<4096, 64, 0, stream>>>(qw, kw, vw, ow, w0, w1, w2, Wq, Wo, W01, W2);
  hipMemcpyAsync(h, x, (size_t)BTOK * D_MODEL * sizeof(float),
                 hipMemcpyDeviceToDevice, stream);

  for (int l = 0; l < 4; ++l) {
    size_t bo  = (size_t)l * D_MODEL;
    size_t bho = (size_t)l * HIDE;

    rmsnorm_k<<<BTOK / 4, 256, 0, stream>>>(h, anw + bo, xn);
    gemm3_k<EPI_QKV, 128><<<384, 256, 0, stream>>>(
        xn, Wq + (size_t)l * 786432, qb + bo, kbi + bo, vb + bo,
        q, k, v, BTOK, 3 * D_MODEL, D_MODEL);
    vtrans_k<<<dim3(32, 16), 64, 0, stream>>>(v, vt);
    attn5_k<<<dim3(80, 16), 256, 0, stream>>>(q, k, vt, ao, Opar, Spar);
    attn_comb_k<<<384, 256, 0, stream>>>(Opar, Spar, ao);
    gemm3_k<EPI_RESID, 64><<<256, 256, 0, stream>>>(
        ao, Wo + (size_t)l * 262144, ob + bo, nullptr, nullptr,
        h, nullptr, nullptr, BTOK, D_MODEL, D_MODEL);

    rmsnorm_k<<<BTOK / 4, 256, 0, stream>>>(h, fnw + bo, xn);
    gemm3_k<EPI_PLAIN, 128><<<512, 256, 0, stream>>>(
        xn, W01 + (size_t)l * 2097152, b0 + bho, nullptr, nullptr,
        hbuf, nullptr, nullptr, BTOK, HIDE, D_MODEL);
    gemm3_k<EPI_GATE, 128><<<512, 256, 0, stream>>>(
        xn, W01 + (size_t)l * 2097152 + 1048576, b1 + bho, nullptr, nullptr,
        hbuf, nullptr, nullptr, BTOK, HIDE, D_MODEL);
    gemm3_k<EPI_RESID, 64><<<256, 256, 0, stream>>>(
        hbuf, W2 + (size_t)l * 1048576, b2 + bo, nullptr, nullptr,
        h, nullptr, nullptr, BTOK, D_MODEL, HIDE);
  }
  hipMemcpyAsync(d_out, h, (size_t)BTOK * D_MODEL * sizeof(float),
                 hipMemcpyDeviceToDevice, stream);
}

// Round 8
// 615.963 us; speedup vs baseline: 2.6493x; 1.0970x over previous
//
#include <hip/hip_runtime.h>
#include <math.h>

// ---------------- types ----------------
typedef unsigned int   uint4v __attribute__((ext_vector_type(4)));
typedef float          f32x4  __attribute__((ext_vector_type(4)));
typedef __bf16         bf16x8 __attribute__((ext_vector_type(8)));
typedef unsigned short u16x8  __attribute__((ext_vector_type(8)));
typedef unsigned short u16x4  __attribute__((ext_vector_type(4)));

#define D_MODEL 512
#define SEQ     2048
#define BTOK    4096   // B * SEQ
#define HIDE    2048
#define NHEAD   8
#define HD      64

static __device__ __forceinline__ unsigned short f2bf(float f) {
  __bf16 b = (__bf16)f;
  return __builtin_bit_cast(unsigned short, b);
}
static __device__ __forceinline__ float bf2f(unsigned short b) {
  union { unsigned u; float f; } v; v.u = ((unsigned)b) << 16;
  return v.f;
}
static __device__ __forceinline__ bf16x8 ldb8(const unsigned short* p) {
  return __builtin_bit_cast(bf16x8, *(const uint4v*)p);
}
static __device__ __forceinline__ f32x4 mfma16(bf16x8 a, bf16x8 b, f32x4 c) {
  return __builtin_amdgcn_mfma_f32_16x16x32_bf16(a, b, c, 0, 0, 0);
}

typedef unsigned int u32_g __attribute__((address_space(1)));
typedef unsigned int u32_l __attribute__((address_space(3)));
static __device__ __forceinline__ void gload16(const unsigned short* g, unsigned short* l) {
  __builtin_amdgcn_global_load_lds((const u32_g*)(const void*)g,
                                   (u32_l*)(void*)l, 16, 0, 0);
}

#define SWZ(r, off) ((off) ^ (((r) & 7) << 4))
#define QSCALE 0.180336880f   // 0.125 * log2(e)

// ---------------- weight prep: LDS-tiled transpose f32 [K][N] -> bf16 [N][K] ----
__global__ __launch_bounds__(64) void prep_t(
    const float* __restrict__ qw, const float* __restrict__ kw,
    const float* __restrict__ vw, const float* __restrict__ ow,
    const float* __restrict__ w0, const float* __restrict__ w1,
    const float* __restrict__ w2,
    unsigned short* __restrict__ Wq, unsigned short* __restrict__ Wo,
    unsigned short* __restrict__ W01, unsigned short* __restrict__ W2)
{
  int bid = blockIdx.x;
  int l = bid >> 10;
  int r = bid & 1023;
  const float* src; unsigned short* dst;
  int tr, tc, srcN, dstK;
  if (r < 192) {
    int sel = r >> 6, tt = r & 63;
    tr = tt >> 3; tc = tt & 7;
    src = (sel == 0 ? qw : sel == 1 ? kw : vw) + (size_t)l * 262144;
    srcN = 512; dstK = 512;
    dst = Wq + (size_t)l * 786432 + (size_t)(sel * 512 + tc * 64) * 512 + tr * 64;
  } else if (r < 256) {
    int tt = r - 192; tr = tt >> 3; tc = tt & 7;
    src = ow + (size_t)l * 262144; srcN = 512; dstK = 512;
    dst = Wo + (size_t)l * 262144 + (size_t)(tc * 64) * 512 + tr * 64;
  } else if (r < 768) {
    int idx = r - 256; int sel = idx >> 8; int tt = idx & 255;
    tr = tt >> 5; tc = tt & 31;
    src = (sel ? w1 : w0) + (size_t)l * 1048576; srcN = 2048; dstK = 512;
    dst = W01 + (size_t)l * 2097152 + (size_t)sel * 1048576 + (size_t)(tc * 64) * 512 + tr * 64;
  } else {
    int tt = r - 768; tr = tt >> 3; tc = tt & 7;
    src = w2 + (size_t)l * 1048576; srcN = 512; dstK = 2048;
    dst = W2 + (size_t)l * 1048576 + (size_t)(tc * 64) * 2048 + tr * 64;
  }
  src += (size_t)(tr * 64) * srcN + tc * 64;
  __shared__ unsigned short T[64][68];
  int t = threadIdx.x;
  #pragma unroll
  for (int it = 0; it < 16; ++it) {
    int row = it * 4 + (t >> 4);
    int col = (t & 15) * 4;
    f32x4 v4 = *(const f32x4*)(src + (size_t)row * srcN + col);
    u16x4 o; o[0] = f2bf(v4.x); o[1] = f2bf(v4.y); o[2] = f2bf(v4.z); o[3] = f2bf(v4.w);
    *(u16x4*)&T[row][col] = o;
  }
  __syncthreads();
  unsigned short* orow = dst + (size_t)t * dstK;
  #pragma unroll
  for (int j0 = 0; j0 < 8; ++j0) {
    u16x8 o;
    #pragma unroll
    for (int j = 0; j < 8; ++j) o[j] = T[j0 * 8 + j][t];
    *(u16x8*)(orow + j0 * 8) = o;
  }
}

// ---------------- initrms: h = x; xn = rms(x)*w ----------------
__global__ __launch_bounds__(256) void initrms_k(const float* __restrict__ x,
                                                 const float* __restrict__ w,
                                                 float* __restrict__ h,
                                                 unsigned short* __restrict__ xn) {
  int row  = blockIdx.x * 4 + (threadIdx.x >> 6);
  int lane = threadIdx.x & 63;
  const float* xr = x + (size_t)row * D_MODEL + lane * 8;
  f32x4 v0 = *(const f32x4*)(xr);
  f32x4 v1 = *(const f32x4*)(xr + 4);
  *(f32x4*)(h + (size_t)row * D_MODEL + lane * 8)     = v0;
  *(f32x4*)(h + (size_t)row * D_MODEL + lane * 8 + 4) = v1;
  float ss = v0.x*v0.x + v0.y*v0.y + v0.z*v0.z + v0.w*v0.w
           + v1.x*v1.x + v1.y*v1.y + v1.z*v1.z + v1.w*v1.w;
  #pragma unroll
  for (int m = 1; m < 64; m <<= 1) ss += __shfl_xor(ss, m, 64);
  float inv = 1.0f / (sqrtf(ss * (1.0f / D_MODEL)) + 1e-6f);
  f32x4 w0 = *(const f32x4*)(w + lane * 8);
  f32x4 w1 = *(const f32x4*)(w + lane * 8 + 4);
  u16x8 o;
  o[0] = f2bf(v0.x * w0.x * inv); o[1] = f2bf(v0.y * w0.y * inv);
  o[2] = f2bf(v0.z * w0.z * inv); o[3] = f2bf(v0.w * w0.w * inv);
  o[4] = f2bf(v1.x * w1.x * inv); o[5] = f2bf(v1.y * w1.y * inv);
  o[6] = f2bf(v1.z * w1.z * inv); o[7] = f2bf(v1.w * w1.w * inv);
  *(u16x8*)(xn + (size_t)row * D_MODEL + lane * 8) = o;
}

// ---------------- addrms: h += y(bf16); xn = rms(h)*w ----------------
__global__ __launch_bounds__(256) void addrms_k(float* __restrict__ h,
                                                const unsigned short* __restrict__ y,
                                                const float* __restrict__ w,
                                                unsigned short* __restrict__ xn) {
  int row  = blockIdx.x * 4 + (threadIdx.x >> 6);
  int lane = threadIdx.x & 63;
  float* hr = h + (size_t)row * D_MODEL + lane * 8;
  f32x4 v0 = *(const f32x4*)(hr);
  f32x4 v1 = *(const f32x4*)(hr + 4);
  u16x8 yy = *(const u16x8*)(y + (size_t)row * D_MODEL + lane * 8);
  v0.x += bf2f(yy[0]); v0.y += bf2f(yy[1]); v0.z += bf2f(yy[2]); v0.w += bf2f(yy[3]);
  v1.x += bf2f(yy[4]); v1.y += bf2f(yy[5]); v1.z += bf2f(yy[6]); v1.w += bf2f(yy[7]);
  *(f32x4*)(hr)     = v0;
  *(f32x4*)(hr + 4) = v1;
  float ss = v0.x*v0.x + v0.y*v0.y + v0.z*v0.z + v0.w*v0.w
           + v1.x*v1.x + v1.y*v1.y + v1.z*v1.z + v1.w*v1.w;
  #pragma unroll
  for (int m = 1; m < 64; m <<= 1) ss += __shfl_xor(ss, m, 64);
  float inv = 1.0f / (sqrtf(ss * (1.0f / D_MODEL)) + 1e-6f);
  f32x4 w0 = *(const f32x4*)(w + lane * 8);
  f32x4 w1 = *(const f32x4*)(w + lane * 8 + 4);
  u16x8 o;
  o[0] = f2bf(v0.x * w0.x * inv); o[1] = f2bf(v0.y * w0.y * inv);
  o[2] = f2bf(v0.z * w0.z * inv); o[3] = f2bf(v0.w * w0.w * inv);
  o[4] = f2bf(v1.x * w1.x * inv); o[5] = f2bf(v1.y * w1.y * inv);
  o[6] = f2bf(v1.z * w1.z * inv); o[7] = f2bf(v1.w * w1.w * inv);
  *(u16x8*)(xn + (size_t)row * D_MODEL + lane * 8) = o;
}

// ---------------- GEMM v4: template<EPI, BM, BN>, 4 waves (2x2) ----------------
#define EPI_QKV   0
#define EPI_PLAIN 1
#define EPI_GATE  2

template<int EPI, int BM, int BN>
__global__ __launch_bounds__(256) void gemm3_k(
    const unsigned short* __restrict__ A,
    const unsigned short* __restrict__ Bt,    // [N][K]
    const float* __restrict__ bias0,
    const float* __restrict__ bias1,
    const float* __restrict__ bias2,
    void* __restrict__ out0,
    void* __restrict__ out1,
    void* __restrict__ out2,
    int M, int N, int K)
{
  constexpr int MF = BM / 32;     // frags per wave along m (WM=2)
  constexpr int NF = BN / 32;     // frags per wave along n (WN=2)
  constexpr int ALOADS = BM / 32; // gload16 per thread for A
  constexpr int BLOADS = BN / 32;

  __shared__ __attribute__((aligned(16))) unsigned short Al[2][BM * 64];
  __shared__ __attribute__((aligned(16))) unsigned short Bl[2][BN * 64];

  int nblk = gridDim.x;
  int orig = blockIdx.x;
  int qq = nblk >> 3, rr = nblk & 7, xcd = orig & 7, pos = orig >> 3;
  int lid = (xcd < rr ? xcd * (qq + 1) : rr * (qq + 1) + (xcd - rr) * qq) + pos;
  int numN = N / BN;
  int mt = lid / numN, nt = lid % numN;
  int m0 = mt * BM, n0 = nt * BN;

  int tid = threadIdx.x, lane = tid & 63, w = tid >> 6;
  int wm = w >> 1, wn = w & 1;
  int g = lane >> 4, c = lane & 15;
  int srow = lane >> 3, scol = (lane & 7) * 8;

  const unsigned short* aG = A  + (size_t)(m0 + w * (BM / 4) + srow) * K + scol;
  const unsigned short* bG = Bt + (size_t)(n0 + w * (BN / 4) + srow) * K + scol;
  unsigned short* aL = &Al[0][(w * (BM / 4) + srow) * 64 + scol];
  unsigned short* bL = &Bl[0][(w * (BN / 4) + srow) * 64 + scol];

  f32x4 acc[MF][NF] = {};
  int KT = K >> 6;

  #pragma unroll
  for (int t = 0; t < ALOADS; ++t)
    gload16(aG + (size_t)(t * 8) * K, aL + t * 8 * 64);
  #pragma unroll
  for (int t = 0; t < BLOADS; ++t)
    gload16(bG + (size_t)(t * 8) * K, bL + t * 8 * 64);

  for (int kt = 0; kt < KT; ++kt) {
    int buf = kt & 1;
    __syncthreads();
    if (kt + 1 < KT) {
      int nb = buf ^ 1;
      const unsigned short* aGk = aG + (kt + 1) * 64;
      const unsigned short* bGk = bG + (kt + 1) * 64;
      #pragma unroll
      for (int t = 0; t < ALOADS; ++t)
        gload16(aGk + (size_t)(t * 8) * K, aL + nb * (BM * 64) + t * 8 * 64);
      #pragma unroll
      for (int t = 0; t < BLOADS; ++t)
        gload16(bGk + (size_t)(t * 8) * K, bL + nb * (BN * 64) + t * 8 * 64);
    }
    const unsigned short* Ab = &Al[buf][0];
    const unsigned short* Bb = &Bl[buf][0];
    #pragma unroll
    for (int ks = 0; ks < 2; ++ks) {
      bf16x8 af[MF], bfr[NF];
      #pragma unroll
      for (int i = 0; i < MF; ++i)
        af[i] = ldb8(Ab + (wm * (MF * 16) + i * 16 + c) * 64 + ks * 32 + g * 8);
      #pragma unroll
      for (int j = 0; j < NF; ++j)
        bfr[j] = ldb8(Bb + (wn * (NF * 16) + j * 16 + c) * 64 + ks * 32 + g * 8);
      #pragma unroll
      for (int i = 0; i < MF; ++i)
        #pragma unroll
        for (int j = 0; j < NF; ++j)
          acc[i][j] = mfma16(af[i], bfr[j], acc[i][j]);
    }
  }

  #pragma unroll
  for (int i = 0; i < MF; ++i) {
    int mrow = m0 + wm * (MF * 16) + i * 16 + g * 4;
    #pragma unroll
    for (int j = 0; j < NF; ++j) {
      int n = n0 + wn * (NF * 16) + j * 16 + c;
      if (EPI == EPI_QKV) {
        int sel  = n >> 9;
        int nloc = n & 511;
        const float* bp = sel == 0 ? bias0 : sel == 1 ? bias1 : bias2;
        unsigned short* o = (unsigned short*)(sel == 0 ? out0 : sel == 1 ? out1 : out2);
        float sc = (sel == 0) ? QSCALE : 1.0f;
        float bn = bp[nloc];
        #pragma unroll
        for (int ii = 0; ii < 4; ++ii)
          o[(size_t)(mrow + ii) * D_MODEL + nloc] = f2bf((acc[i][j][ii] + bn) * sc);
      } else if (EPI == EPI_PLAIN) {
        float bn = bias0[n];
        unsigned short* o = (unsigned short*)out0;
        #pragma unroll
        for (int ii = 0; ii < 4; ++ii)
          o[(size_t)(mrow + ii) * N + n] = f2bf(acc[i][j][ii] + bn);
      } else {  // EPI_GATE: out *= silu(acc + b)
        float bn = bias0[n];
        unsigned short* o = (unsigned short*)out0;
        #pragma unroll
        for (int ii = 0; ii < 4; ++ii) {
          size_t idx = (size_t)(mrow + ii) * N + n;
          float h1 = acc[i][j][ii] + bn;
          float s  = h1 / (1.0f + __expf(-h1));
          o[idx] = f2bf(bf2f(o[idx]) * s);
        }
      }
    }
  }
}

// ---------------- V transpose: v [B*S][512] -> vt [bh][d][s] ----------------
__global__ __launch_bounds__(64) void vtrans_k(const unsigned short* __restrict__ V,
                                               unsigned short* __restrict__ VT) {
  __shared__ unsigned short T[64][76];
  int t = threadIdx.x;
  int s0 = blockIdx.x * 64;
  int bh = blockIdx.y, b = bh >> 3, h = bh & 7;
  const unsigned short* src = V + (size_t)(b * SEQ + s0) * D_MODEL + h * HD;
  #pragma unroll
  for (int j0 = 0; j0 < 8; ++j0) {
    u16x8 vv = *(const u16x8*)(src + (size_t)t * D_MODEL + j0 * 8);
    *(u16x8*)&T[t][j0 * 8] = vv;
  }
  __syncthreads();
  unsigned short* dst = VT + ((size_t)bh * HD + t) * SEQ + s0;
  #pragma unroll
  for (int j0 = 0; j0 < 8; ++j0) {
    u16x8 o;
    #pragma unroll
    for (int j = 0; j < 8; ++j) o[j] = T[j0 * 8 + j][t];
    *(u16x8*)(dst + j0 * 8) = o;
  }
}

// ---------------- attention v5: split-K flash, no-max softmax ------------
struct Stg { uint4v k0, k1, v0, v1; };

static __device__ __forceinline__ Stg stage_load(const unsigned short* Kp,
                                                 const unsigned short* Vp,
                                                 int kbase, int srow, int sslot) {
  Stg s;
  const unsigned short* kr = Kp + (size_t)(kbase + srow) * D_MODEL + sslot * 8;
  s.k0 = *(const uint4v*)kr;
  s.k1 = *(const uint4v*)(kr + 32);
  const unsigned short* vr = Vp + (size_t)srow * SEQ + kbase + sslot * 8;
  s.v0 = *(const uint4v*)vr;
  s.v1 = *(const uint4v*)(vr + 32);
  return s;
}
static __device__ __forceinline__ void stage_write(unsigned short* Klb, unsigned short* Vlb,
                                                   const Stg& s, int srow, int sslot) {
  char* kb = (char*)Klb;
  *(uint4v*)(kb + SWZ(srow, srow * 128 + sslot * 16))       = s.k0;
  *(uint4v*)(kb + SWZ(srow, srow * 128 + (sslot + 4) * 16)) = s.k1;
  char* vb = (char*)Vlb;
  *(uint4v*)(vb + SWZ(srow, srow * 128 + sslot * 16))       = s.v0;
  *(uint4v*)(vb + SWZ(srow, srow * 128 + (sslot + 4) * 16)) = s.v1;
}

template<bool MASKED>
static __device__ __forceinline__ void attn_tile(
    const unsigned short* Klb, const unsigned short* Vlb,
    bf16x8 qf0, bf16x8 qf1, f32x4* oacc, float& ps,
    int g, int c, int kbase, int qrow)
{
  f32x4 z[4];
  #pragma unroll
  for (int hh = 0; hh < 4; ++hh) {
    int r = hh * 16 + c;
    const char* base = (const char*)Klb;
    bf16x8 k0 = ldb8((const unsigned short*)(base + SWZ(r, r * 128 + g * 16)));
    bf16x8 k1 = ldb8((const unsigned short*)(base + SWZ(r, r * 128 + 64 + g * 16)));
    f32x4 t = {};
    t = mfma16(k0, qf0, t);
    t = mfma16(k1, qf1, t);
    z[hh] = t;
  }
  u16x8 pa0, pa1;
  #pragma unroll
  for (int hh = 0; hh < 4; ++hh) {
    #pragma unroll
    for (int i = 0; i < 4; ++i) {
      float p = exp2f(z[hh][i]);
      if (MASKED && (kbase + hh * 16 + g * 4 + i > qrow)) p = 0.0f;
      ps += p;
      unsigned short pb = f2bf(p);
      if (hh < 2) pa0[hh * 4 + i] = pb;
      else        pa1[(hh - 2) * 4 + i] = pb;
    }
  }
  bf16x8 af0 = __builtin_bit_cast(bf16x8, pa0);
  bf16x8 af1 = __builtin_bit_cast(bf16x8, pa1);
  #pragma unroll
  for (int db = 0; db < 4; ++db) {
    int r = db * 16 + c;
    const char* base = (const char*)Vlb;
    u16x4 v00 = *(const u16x4*)(base + SWZ(r, r * 128 + g * 8));
    u16x4 v01 = *(const u16x4*)(base + SWZ(r, r * 128 + 32 + g * 8));
    u16x4 v10 = *(const u16x4*)(base + SWZ(r, r * 128 + 64 + g * 8));
    u16x4 v11 = *(const u16x4*)(base + SWZ(r, r * 128 + 96 + g * 8));
    u16x8 vb0, vb1;
    #pragma unroll
    for (int j = 0; j < 4; ++j) {
      vb0[j] = v00[j]; vb0[4 + j] = v01[j];
      vb1[j] = v10[j]; vb1[4 + j] = v11[j];
    }
    oacc[db] = mfma16(af0, __builtin_bit_cast(bf16x8, vb0), oacc[db]);
    oacc[db] = mfma16(af1, __builtin_bit_cast(bf16x8, vb1), oacc[db]);
  }
}

// packed split-slot base within a bh (72 slots total)
static __device__ __forceinline__ int slot_base(int c) {
  if (c < 16) return (c - 8) * 2;
  if (c < 24) return 16 + (c - 16) * 3;
  return 40 + (c - 24) * 4;
}

__global__ __launch_bounds__(256) void attn5_k(const unsigned short* __restrict__ Q,
                                               const unsigned short* __restrict__ K,
                                               const unsigned short* __restrict__ VT,
                                               unsigned short* __restrict__ O,
                                               float* __restrict__ Oparts,
                                               float* __restrict__ Sparts)
{
  __shared__ __attribute__((aligned(16))) unsigned short Kl[2][64 * 64];
  __shared__ __attribute__((aligned(16))) unsigned short Vl[2][64 * 64];
  int tid = threadIdx.x, lane = tid & 63, w = tid >> 6;
  int g = lane >> 4, cl = lane & 15;

  int z = 79 - (int)blockIdx.x;
  int c, sp;
  if (z < 8)        { c = z;                    sp = 0; }
  else if (z < 24)  { int t2 = z - 8;  c = 8  + (t2 >> 1); sp = t2 & 1; }
  else if (z < 48)  { int t2 = z - 24; c = 16 + t2 / 3;    sp = t2 % 3; }
  else              { int t2 = z - 48; c = 24 + (t2 >> 2); sp = t2 & 3; }
  int kt0 = sp * 8;
  int kt1 = min(c + 1, kt0 + 8);
  bool lastsplit = (kt1 == c + 1);

  int bh = blockIdx.y, b = bh >> 3, h = bh & 7;
  int q0 = c * 64;
  const unsigned short* Qp = Q + (size_t)(b * SEQ) * D_MODEL + h * HD;
  const unsigned short* Kp = K + (size_t)(b * SEQ) * D_MODEL + h * HD;
  const unsigned short* Vp = VT + (size_t)bh * HD * SEQ;

  int qrow = q0 + w * 16 + cl;
  bf16x8 qf0 = ldb8(Qp + (size_t)qrow * D_MODEL + g * 8);
  bf16x8 qf1 = ldb8(Qp + (size_t)qrow * D_MODEL + 32 + g * 8);

  f32x4 oacc[4] = {};
  float ps = 0.0f;
  int srow = tid >> 2, sslot = tid & 3;

  Stg s0 = stage_load(Kp, Vp, kt0 * 64, srow, sslot);
  stage_write(&Kl[0][0], &Vl[0][0], s0, srow, sslot);
  __syncthreads();

  int buf = 0;
  for (int kt = kt0; kt < kt1 - 1; ++kt) {
    Stg sn = stage_load(Kp, Vp, (kt + 1) * 64, srow, sslot);
    attn_tile<false>(&Kl[buf][0], &Vl[buf][0], qf0, qf1, oacc, ps, g, cl, 0, 0);
    stage_write(&Kl[buf ^ 1][0], &Vl[buf ^ 1][0], sn, srow, sslot);
    __syncthreads();
    buf ^= 1;
  }
  if (lastsplit)
    attn_tile<true>(&Kl[buf][0], &Vl[buf][0], qf0, qf1, oacc, ps, g, cl,
                    (kt1 - 1) * 64, qrow);
  else
    attn_tile<false>(&Kl[buf][0], &Vl[buf][0], qf0, qf1, oacc, ps, g, cl, 0, 0);

  ps += __shfl_xor(ps, 16, 64);
  ps += __shfl_xor(ps, 32, 64);

  if (c < 8) {
    f32x4 inv;
    #pragma unroll
    for (int i = 0; i < 4; ++i) inv[i] = 1.0f / __shfl(ps, g * 4 + i, 64);
    #pragma unroll
    for (int db = 0; db < 4; ++db)
      #pragma unroll
      for (int i = 0; i < 4; ++i)
        O[(size_t)(b * SEQ + q0 + w * 16 + g * 4 + i) * D_MODEL + h * HD + db * 16 + cl] =
            f2bf(oacc[db][i] * inv[i]);
  } else {
    size_t slot = (size_t)bh * 72 + slot_base(c) + sp;
    float* Op = Oparts + slot * 4096;
    float* Sp = Sparts + slot * 64;
    #pragma unroll
    for (int db = 0; db < 4; ++db)
      #pragma unroll
      for (int i = 0; i < 4; ++i)
        Op[(w * 16 + g * 4 + i) * 64 + db * 16 + cl] = oacc[db][i];
    if (g == 0) Sp[w * 16 + cl] = ps;
  }
}

__global__ __launch_bounds__(256) void attn_comb_k(const float* __restrict__ Oparts,
                                                   const float* __restrict__ Sparts,
                                                   unsigned short* __restrict__ O) {
  int t  = threadIdx.x;
  int c  = 8 + (int)(blockIdx.x % 24);
  int bh = (int)(blockIdx.x / 24);
  int b = bh >> 3, h = bh & 7;
  int ns = (c + 8) >> 3;
  size_t slot = (size_t)bh * 72 + slot_base(c);
  const float* O0 = Oparts + slot * 4096;
  const float* S0 = Sparts + slot * 64;
  int r = t >> 2, d0 = (t & 3) * 16;
  f32x4 a0 = {}, a1 = {}, a2 = {}, a3 = {};
  float s = 0.0f;
  for (int si = 0; si < ns; ++si) {
    const float* o = O0 + si * 4096 + r * 64 + d0;
    a0 += *(const f32x4*)(o);
    a1 += *(const f32x4*)(o + 4);
    a2 += *(const f32x4*)(o + 8);
    a3 += *(const f32x4*)(o + 12);
    s  += S0[si * 64 + r];
  }
  float inv = 1.0f / s;
  u16x8 w0, w1;
  #pragma unroll
  for (int j = 0; j < 4; ++j) {
    w0[j]     = f2bf(a0[j] * inv); w0[4 + j] = f2bf(a1[j] * inv);
    w1[j]     = f2bf(a2[j] * inv); w1[4 + j] = f2bf(a3[j] * inv);
  }
  unsigned short* dst = O + (size_t)(b * SEQ + c * 64 + r) * D_MODEL + h * HD + d0;
  *(u16x8*)(dst)     = w0;
  *(u16x8*)(dst + 8) = w1;
}

// ---------------- launch ----------------
extern "C" void kernel_launch(void* const* d_in, const int* in_sizes, int n_in,
                              void* d_out, int out_size, void* d_ws, size_t ws_size,
                              hipStream_t stream) {
  (void)in_sizes; (void)n_in; (void)out_size; (void)ws_size;
  const float* x   = (const float*)d_in[0];
  const float* qw  = (const float*)d_in[1];
  const float* qb  = (const float*)d_in[2];
  const float* kw  = (const float*)d_in[3];
  const float* kbi = (const float*)d_in[4];
  const float* vw  = (const float*)d_in[5];
  const float* vb  = (const float*)d_in[6];
  const float* ow  = (const float*)d_in[7];
  const float* ob  = (const float*)d_in[8];
  const float* w0  = (const float*)d_in[9];
  const float* b0  = (const float*)d_in[10];
  const float* w1  = (const float*)d_in[11];
  const float* b1  = (const float*)d_in[12];
  const float* w2  = (const float*)d_in[13];
  const float* b2  = (const float*)d_in[14];
  const float* anw = (const float*)d_in[15];
  const float* fnw = (const float*)d_in[16];

  char* ws = (char*)d_ws;
  float*          h    = (float*)ws;                              // 0-8MB fp32 residual
  unsigned short* xn   = (unsigned short*)(ws + (8u  << 20));     // 8-12
  unsigned short* q    = (unsigned short*)(ws + (12u << 20));     // 12-16
  unsigned short* k    = (unsigned short*)(ws + (16u << 20));     // 16-20
  unsigned short* v    = (unsigned short*)(ws + (20u << 20));     // 20-24
  unsigned short* vt   = (unsigned short*)(ws + (24u << 20));     // 24-28
  unsigned short* ao   = (unsigned short*)(ws + (28u << 20));     // 28-32
  unsigned short* y    = (unsigned short*)(ws + (32u << 20));     // 32-36
  unsigned short* hbuf = (unsigned short*)(ws + (12u << 20));     // 12-28 (aliases q,k,v,vt)
  unsigned short* Wq   = (unsigned short*)(ws + (36u << 20));     // 36-42
  unsigned short* Wo   = (unsigned short*)(ws + (42u << 20));     // 42-44
  unsigned short* W01  = (unsigned short*)(ws + (44u << 20));     // 44-60
  unsigned short* W2   = (unsigned short*)(ws + (60u << 20));     // 60-68
  float*          Opar = (float*)(ws + (68u << 20));              // 68-86 (18MB)
  float*          Spar = (float*)(ws + (86u << 20));              // 86-86.3

  prep_t<<<4096, 64, 0, stream>>>(qw, kw, vw, ow, w0, w1, w2, Wq, Wo, W01, W2);
  initrms_k<<<BTOK / 4, 256, 0, stream>>>(x, anw, h, xn);

  for (int l = 0; l < 4; ++l) {
    size_t bo  = (size_t)l * D_MODEL;
    size_t bho = (size_t)l * HIDE;

    gemm3_k<EPI_QKV, 128, 64><<<768, 256, 0, stream>>>(
        xn, Wq + (size_t)l * 786432, qb + bo, kbi + bo, vb + bo,
        q, k, v, BTOK, 3 * D_MODEL, D_MODEL);
    vtrans_k<<<dim3(32, 16), 64, 0, stream>>>(v, vt);
    attn5_k<<<dim3(80, 16), 256, 0, stream>>>(q, k, vt, ao, Opar, Spar);
    attn_comb_k<<<384, 256, 0, stream>>>(Opar, Spar, ao);
    gemm3_k<EPI_PLAIN, 64, 64><<<512, 256, 0, stream>>>(
        ao, Wo + (size_t)l * 262144, ob + bo, nullptr, nullptr,
        y, nullptr, nullptr, BTOK, D_MODEL, D_MODEL);
    addrms_k<<<BTOK / 4, 256, 0, stream>>>(h, y, fnw + bo, xn);

    gemm3_k<EPI_PLAIN, 128, 128><<<512, 256, 0, stream>>>(
        xn, W01 + (size_t)l * 2097152, b0 + bho, nullptr, nullptr,
        hbuf, nullptr, nullptr, BTOK, HIDE, D_MODEL);
    gemm3_k<EPI_GATE, 128, 128><<<512, 256, 0, stream>>>(
        xn, W01 + (size_t)l * 2097152 + 1048576, b1 + bho, nullptr, nullptr,
        hbuf, nullptr, nullptr, BTOK, HIDE, D_MODEL);
    gemm3_k<EPI_PLAIN, 64, 64><<<512, 256, 0, stream>>>(
        hbuf, W2 + (size_t)l * 1048576, b2 + bo, nullptr, nullptr,
        y, nullptr, nullptr, BTOK, D_MODEL, HIDE);
    addrms_k<<<BTOK / 4, 256, 0, stream>>>(
        h, y, (l < 3 ? anw + bo + D_MODEL : anw), xn);
  }
  hipMemcpyAsync(d_out, h, (size_t)BTOK * D_MODEL * sizeof(float),
                 hipMemcpyDeviceToDevice, stream);
}

// Round 9
// 536.571 us; speedup vs baseline: 3.0413x; 1.1480x over previous
//
#include <hip/hip_runtime.h>
#include <math.h>

// ---------------- types ----------------
typedef unsigned int   uint4v __attribute__((ext_vector_type(4)));
typedef float          f32x4  __attribute__((ext_vector_type(4)));
typedef __bf16         bf16x8 __attribute__((ext_vector_type(8)));
typedef unsigned short u16x8  __attribute__((ext_vector_type(8)));
typedef unsigned short u16x4  __attribute__((ext_vector_type(4)));

#define D_MODEL 512
#define SEQ     2048
#define BTOK    4096   // B * SEQ
#define HIDE    2048
#define NHEAD   8
#define HD      64

static __device__ __forceinline__ unsigned short f2bf(float f) {
  __bf16 b = (__bf16)f;
  return __builtin_bit_cast(unsigned short, b);
}
static __device__ __forceinline__ float bf2f(unsigned short b) {
  union { unsigned u; float f; } v; v.u = ((unsigned)b) << 16;
  return v.f;
}
static __device__ __forceinline__ bf16x8 ldb8(const unsigned short* p) {
  return __builtin_bit_cast(bf16x8, *(const uint4v*)p);
}
static __device__ __forceinline__ f32x4 mfma16(bf16x8 a, bf16x8 b, f32x4 c) {
  return __builtin_amdgcn_mfma_f32_16x16x32_bf16(a, b, c, 0, 0, 0);
}

typedef unsigned int u32_g __attribute__((address_space(1)));
typedef unsigned int u32_l __attribute__((address_space(3)));
static __device__ __forceinline__ void gload16(const unsigned short* g, unsigned short* l) {
  __builtin_amdgcn_global_load_lds((const u32_g*)(const void*)g,
                                   (u32_l*)(void*)l, 16, 0, 0);
}

#define SWZ(r, off) ((off) ^ (((r) & 7) << 4))
#define QSCALE 0.180336880f   // 0.125 * log2(e)

// ---------------- weight prep: LDS-tiled transpose f32 [K][N] -> bf16 [N][K] ----
__global__ __launch_bounds__(64) void prep_t(
    const float* __restrict__ qw, const float* __restrict__ kw,
    const float* __restrict__ vw, const float* __restrict__ ow,
    const float* __restrict__ w0, const float* __restrict__ w1,
    const float* __restrict__ w2,
    unsigned short* __restrict__ Wq, unsigned short* __restrict__ Wo,
    unsigned short* __restrict__ W01, unsigned short* __restrict__ W2)
{
  int bid = blockIdx.x;
  int l = bid >> 10;
  int r = bid & 1023;
  const float* src; unsigned short* dst;
  int tr, tc, srcN, dstK;
  if (r < 192) {
    int sel = r >> 6, tt = r & 63;
    tr = tt >> 3; tc = tt & 7;
    src = (sel == 0 ? qw : sel == 1 ? kw : vw) + (size_t)l * 262144;
    srcN = 512; dstK = 512;
    dst = Wq + (size_t)l * 786432 + (size_t)(sel * 512 + tc * 64) * 512 + tr * 64;
  } else if (r < 256) {
    int tt = r - 192; tr = tt >> 3; tc = tt & 7;
    src = ow + (size_t)l * 262144; srcN = 512; dstK = 512;
    dst = Wo + (size_t)l * 262144 + (size_t)(tc * 64) * 512 + tr * 64;
  } else if (r < 768) {
    int idx = r - 256; int sel = idx >> 8; int tt = idx & 255;
    tr = tt >> 5; tc = tt & 31;
    src = (sel ? w1 : w0) + (size_t)l * 1048576; srcN = 2048; dstK = 512;
    dst = W01 + (size_t)l * 2097152 + (size_t)sel * 1048576 + (size_t)(tc * 64) * 512 + tr * 64;
  } else {
    int tt = r - 768; tr = tt >> 3; tc = tt & 7;
    src = w2 + (size_t)l * 1048576; srcN = 512; dstK = 2048;
    dst = W2 + (size_t)l * 1048576 + (size_t)(tc * 64) * 2048 + tr * 64;
  }
  src += (size_t)(tr * 64) * srcN + tc * 64;
  __shared__ unsigned short T[64][68];
  int t = threadIdx.x;
  #pragma unroll
  for (int it = 0; it < 16; ++it) {
    int row = it * 4 + (t >> 4);
    int col = (t & 15) * 4;
    f32x4 v4 = *(const f32x4*)(src + (size_t)row * srcN + col);
    u16x4 o; o[0] = f2bf(v4.x); o[1] = f2bf(v4.y); o[2] = f2bf(v4.z); o[3] = f2bf(v4.w);
    *(u16x4*)&T[row][col] = o;
  }
  __syncthreads();
  unsigned short* orow = dst + (size_t)t * dstK;
  #pragma unroll
  for (int j0 = 0; j0 < 8; ++j0) {
    u16x8 o;
    #pragma unroll
    for (int j = 0; j < 8; ++j) o[j] = T[j0 * 8 + j][t];
    *(u16x8*)(orow + j0 * 8) = o;
  }
}

// ---------------- initrms: h = x; xn = rms(x)*w ----------------
__global__ __launch_bounds__(256) void initrms_k(const float* __restrict__ x,
                                                 const float* __restrict__ w,
                                                 float* __restrict__ h,
                                                 unsigned short* __restrict__ xn) {
  int row  = blockIdx.x * 4 + (threadIdx.x >> 6);
  int lane = threadIdx.x & 63;
  const float* xr = x + (size_t)row * D_MODEL + lane * 8;
  f32x4 v0 = *(const f32x4*)(xr);
  f32x4 v1 = *(const f32x4*)(xr + 4);
  *(f32x4*)(h + (size_t)row * D_MODEL + lane * 8)     = v0;
  *(f32x4*)(h + (size_t)row * D_MODEL + lane * 8 + 4) = v1;
  float ss = v0.x*v0.x + v0.y*v0.y + v0.z*v0.z + v0.w*v0.w
           + v1.x*v1.x + v1.y*v1.y + v1.z*v1.z + v1.w*v1.w;
  #pragma unroll
  for (int m = 1; m < 64; m <<= 1) ss += __shfl_xor(ss, m, 64);
  float inv = 1.0f / (sqrtf(ss * (1.0f / D_MODEL)) + 1e-6f);
  f32x4 w0 = *(const f32x4*)(w + lane * 8);
  f32x4 w1 = *(const f32x4*)(w + lane * 8 + 4);
  u16x8 o;
  o[0] = f2bf(v0.x * w0.x * inv); o[1] = f2bf(v0.y * w0.y * inv);
  o[2] = f2bf(v0.z * w0.z * inv); o[3] = f2bf(v0.w * w0.w * inv);
  o[4] = f2bf(v1.x * w1.x * inv); o[5] = f2bf(v1.y * w1.y * inv);
  o[6] = f2bf(v1.z * w1.z * inv); o[7] = f2bf(v1.w * w1.w * inv);
  *(u16x8*)(xn + (size_t)row * D_MODEL + lane * 8) = o;
}

// ---------------- addrms: h += y(bf16); xn = rms(h)*w ----------------
__global__ __launch_bounds__(256) void addrms_k(float* __restrict__ h,
                                                const unsigned short* __restrict__ y,
                                                const float* __restrict__ w,
                                                unsigned short* __restrict__ xn) {
  int row  = blockIdx.x * 4 + (threadIdx.x >> 6);
  int lane = threadIdx.x & 63;
  float* hr = h + (size_t)row * D_MODEL + lane * 8;
  f32x4 v0 = *(const f32x4*)(hr);
  f32x4 v1 = *(const f32x4*)(hr + 4);
  u16x8 yy = *(const u16x8*)(y + (size_t)row * D_MODEL + lane * 8);
  v0.x += bf2f(yy[0]); v0.y += bf2f(yy[1]); v0.z += bf2f(yy[2]); v0.w += bf2f(yy[3]);
  v1.x += bf2f(yy[4]); v1.y += bf2f(yy[5]); v1.z += bf2f(yy[6]); v1.w += bf2f(yy[7]);
  *(f32x4*)(hr)     = v0;
  *(f32x4*)(hr + 4) = v1;
  float ss = v0.x*v0.x + v0.y*v0.y + v0.z*v0.z + v0.w*v0.w
           + v1.x*v1.x + v1.y*v1.y + v1.z*v1.z + v1.w*v1.w;
  #pragma unroll
  for (int m = 1; m < 64; m <<= 1) ss += __shfl_xor(ss, m, 64);
  float inv = 1.0f / (sqrtf(ss * (1.0f / D_MODEL)) + 1e-6f);
  f32x4 w0 = *(const f32x4*)(w + lane * 8);
  f32x4 w1 = *(const f32x4*)(w + lane * 8 + 4);
  u16x8 o;
  o[0] = f2bf(v0.x * w0.x * inv); o[1] = f2bf(v0.y * w0.y * inv);
  o[2] = f2bf(v0.z * w0.z * inv); o[3] = f2bf(v0.w * w0.w * inv);
  o[4] = f2bf(v1.x * w1.x * inv); o[5] = f2bf(v1.y * w1.y * inv);
  o[6] = f2bf(v1.z * w1.z * inv); o[7] = f2bf(v1.w * w1.w * inv);
  *(u16x8*)(xn + (size_t)row * D_MODEL + lane * 8) = o;
}

// ---------------- GEMM v5: m97 single-buffer 2-barrier + T2 swizzle ----------
// LDS[row][s] holds global[row][s ^ (row&7)] (16B slots); gload_lds dest is
// lane-linear, the source column is pre-swizzled (rule #21-safe).
#define EPI_QKV   0
#define EPI_PLAIN 1
#define EPI_GATE  2

template<int EPI, int BM, int BN>
__global__ __launch_bounds__(256) void gemm5_k(
    const unsigned short* __restrict__ A,
    const unsigned short* __restrict__ Bt,    // [N][K]
    const float* __restrict__ bias0,
    const float* __restrict__ bias1,
    const float* __restrict__ bias2,
    void* __restrict__ out0,
    void* __restrict__ out1,
    void* __restrict__ out2,
    int M, int N, int K)
{
  constexpr int MF = BM / 32;     // frags per wave along m (2x2 waves)
  constexpr int NF = BN / 32;
  constexpr int ALOADS = BM / 32;
  constexpr int BLOADS = BN / 32;

  __shared__ __attribute__((aligned(16))) unsigned short Al[BM * 64];
  __shared__ __attribute__((aligned(16))) unsigned short Bl[BN * 64];

  int nblk = gridDim.x;
  int orig = blockIdx.x;
  int qq = nblk >> 3, rr = nblk & 7, xcd = orig & 7, pos = orig >> 3;
  int lid = (xcd < rr ? xcd * (qq + 1) : rr * (qq + 1) + (xcd - rr) * qq) + pos;
  int numN = N / BN;
  int mt = lid / numN, nt = lid % numN;
  int m0 = mt * BM, n0 = nt * BN;

  int tid = threadIdx.x, lane = tid & 63, w = tid >> 6;
  int wm = w >> 1, wn = w & 1;
  int g = lane >> 4, c = lane & 15;
  int srow = lane >> 3, sslot = lane & 7;
  int sgc = (sslot ^ srow) * 8;            // pre-swizzled global col (elements)

  const unsigned short* aG = A  + (size_t)(m0 + w * (BM / 4) + srow) * K + sgc;
  const unsigned short* bG = Bt + (size_t)(n0 + w * (BN / 4) + srow) * K + sgc;
  unsigned short* aL = &Al[(w * (BM / 4) + srow) * 64 + sslot * 8];
  unsigned short* bL = &Bl[(w * (BN / 4) + srow) * 64 + sslot * 8];

  f32x4 acc[MF][NF] = {};
  int KT = K >> 6;
  int rk = c & 7;                           // read-side swizzle key

  for (int kt = 0; kt < KT; ++kt) {
    if (kt) __syncthreads();                // all waves done reading prev tile
    #pragma unroll
    for (int t = 0; t < ALOADS; ++t)
      gload16(aG + (size_t)(t * 8) * K + kt * 64, aL + t * 8 * 64);
    #pragma unroll
    for (int t = 0; t < BLOADS; ++t)
      gload16(bG + (size_t)(t * 8) * K + kt * 64, bL + t * 8 * 64);
    __syncthreads();                        // vmcnt(0) drained -> tile ready
    #pragma unroll
    for (int ks = 0; ks < 2; ++ks) {
      int slot = (ks * 4 + g) ^ rk;
      bf16x8 af[MF], bfr[NF];
      #pragma unroll
      for (int i = 0; i < MF; ++i)
        af[i] = ldb8(&Al[(wm * (MF * 16) + i * 16 + c) * 64 + slot * 8]);
      #pragma unroll
      for (int j = 0; j < NF; ++j)
        bfr[j] = ldb8(&Bl[(wn * (NF * 16) + j * 16 + c) * 64 + slot * 8]);
      #pragma unroll
      for (int i = 0; i < MF; ++i)
        #pragma unroll
        for (int j = 0; j < NF; ++j)
          acc[i][j] = mfma16(af[i], bfr[j], acc[i][j]);
    }
  }

  #pragma unroll
  for (int i = 0; i < MF; ++i) {
    int mrow = m0 + wm * (MF * 16) + i * 16 + g * 4;
    #pragma unroll
    for (int j = 0; j < NF; ++j) {
      int n = n0 + wn * (NF * 16) + j * 16 + c;
      if (EPI == EPI_QKV) {
        int sel  = n >> 9;
        int nloc = n & 511;
        const float* bp = sel == 0 ? bias0 : sel == 1 ? bias1 : bias2;
        unsigned short* o = (unsigned short*)(sel == 0 ? out0 : sel == 1 ? out1 : out2);
        float sc = (sel == 0) ? QSCALE : 1.0f;
        float bn = bp[nloc];
        #pragma unroll
        for (int ii = 0; ii < 4; ++ii)
          o[(size_t)(mrow + ii) * D_MODEL + nloc] = f2bf((acc[i][j][ii] + bn) * sc);
      } else if (EPI == EPI_PLAIN) {
        float bn = bias0[n];
        unsigned short* o = (unsigned short*)out0;
        #pragma unroll
        for (int ii = 0; ii < 4; ++ii)
          o[(size_t)(mrow + ii) * N + n] = f2bf(acc[i][j][ii] + bn);
      } else {  // EPI_GATE: out *= silu(acc + b)
        float bn = bias0[n];
        unsigned short* o = (unsigned short*)out0;
        #pragma unroll
        for (int ii = 0; ii < 4; ++ii) {
          size_t idx = (size_t)(mrow + ii) * N + n;
          float h1 = acc[i][j][ii] + bn;
          float s  = h1 / (1.0f + __expf(-h1));
          o[idx] = f2bf(bf2f(o[idx]) * s);
        }
      }
    }
  }
}

// ---------------- V transpose: v [B*S][512] -> vt [bh][d][s] ----------------
__global__ __launch_bounds__(64) void vtrans_k(const unsigned short* __restrict__ V,
                                               unsigned short* __restrict__ VT) {
  __shared__ unsigned short T[64][76];
  int t = threadIdx.x;
  int s0 = blockIdx.x * 64;
  int bh = blockIdx.y, b = bh >> 3, h = bh & 7;
  const unsigned short* src = V + (size_t)(b * SEQ + s0) * D_MODEL + h * HD;
  #pragma unroll
  for (int j0 = 0; j0 < 8; ++j0) {
    u16x8 vv = *(const u16x8*)(src + (size_t)t * D_MODEL + j0 * 8);
    *(u16x8*)&T[t][j0 * 8] = vv;
  }
  __syncthreads();
  unsigned short* dst = VT + ((size_t)bh * HD + t) * SEQ + s0;
  #pragma unroll
  for (int j0 = 0; j0 < 8; ++j0) {
    u16x8 o;
    #pragma unroll
    for (int j = 0; j < 8; ++j) o[j] = T[j0 * 8 + j][t];
    *(u16x8*)(dst + j0 * 8) = o;
  }
}

// ---------------- attention v5: split-K flash, no-max softmax ------------
struct Stg { uint4v k0, k1, v0, v1; };

static __device__ __forceinline__ Stg stage_load(const unsigned short* Kp,
                                                 const unsigned short* Vp,
                                                 int kbase, int srow, int sslot) {
  Stg s;
  const unsigned short* kr = Kp + (size_t)(kbase + srow) * D_MODEL + sslot * 8;
  s.k0 = *(const uint4v*)kr;
  s.k1 = *(const uint4v*)(kr + 32);
  const unsigned short* vr = Vp + (size_t)srow * SEQ + kbase + sslot * 8;
  s.v0 = *(const uint4v*)vr;
  s.v1 = *(const uint4v*)(vr + 32);
  return s;
}
static __device__ __forceinline__ void stage_write(unsigned short* Klb, unsigned short* Vlb,
                                                   const Stg& s, int srow, int sslot) {
  char* kb = (char*)Klb;
  *(uint4v*)(kb + SWZ(srow, srow * 128 + sslot * 16))       = s.k0;
  *(uint4v*)(kb + SWZ(srow, srow * 128 + (sslot + 4) * 16)) = s.k1;
  char* vb = (char*)Vlb;
  *(uint4v*)(vb + SWZ(srow, srow * 128 + sslot * 16))       = s.v0;
  *(uint4v*)(vb + SWZ(srow, srow * 128 + (sslot + 4) * 16)) = s.v1;
}

template<bool MASKED>
static __device__ __forceinline__ void attn_tile(
    const unsigned short* Klb, const unsigned short* Vlb,
    bf16x8 qf0, bf16x8 qf1, f32x4* oacc, float& ps,
    int g, int c, int kbase, int qrow)
{
  f32x4 z[4];
  #pragma unroll
  for (int hh = 0; hh < 4; ++hh) {
    int r = hh * 16 + c;
    const char* base = (const char*)Klb;
    bf16x8 k0 = ldb8((const unsigned short*)(base + SWZ(r, r * 128 + g * 16)));
    bf16x8 k1 = ldb8((const unsigned short*)(base + SWZ(r, r * 128 + 64 + g * 16)));
    f32x4 t = {};
    t = mfma16(k0, qf0, t);
    t = mfma16(k1, qf1, t);
    z[hh] = t;
  }
  u16x8 pa0, pa1;
  #pragma unroll
  for (int hh = 0; hh < 4; ++hh) {
    #pragma unroll
    for (int i = 0; i < 4; ++i) {
      float p = exp2f(z[hh][i]);
      if (MASKED && (kbase + hh * 16 + g * 4 + i > qrow)) p = 0.0f;
      ps += p;
      unsigned short pb = f2bf(p);
      if (hh < 2) pa0[hh * 4 + i] = pb;
      else        pa1[(hh - 2) * 4 + i] = pb;
    }
  }
  bf16x8 af0 = __builtin_bit_cast(bf16x8, pa0);
  bf16x8 af1 = __builtin_bit_cast(bf16x8, pa1);
  #pragma unroll
  for (int db = 0; db < 4; ++db) {
    int r = db * 16 + c;
    const char* base = (const char*)Vlb;
    u16x4 v00 = *(const u16x4*)(base + SWZ(r, r * 128 + g * 8));
    u16x4 v01 = *(const u16x4*)(base + SWZ(r, r * 128 + 32 + g * 8));
    u16x4 v10 = *(const u16x4*)(base + SWZ(r, r * 128 + 64 + g * 8));
    u16x4 v11 = *(const u16x4*)(base + SWZ(r, r * 128 + 96 + g * 8));
    u16x8 vb0, vb1;
    #pragma unroll
    for (int j = 0; j < 4; ++j) {
      vb0[j] = v00[j]; vb0[4 + j] = v01[j];
      vb1[j] = v10[j]; vb1[4 + j] = v11[j];
    }
    oacc[db] = mfma16(af0, __builtin_bit_cast(bf16x8, vb0), oacc[db]);
    oacc[db] = mfma16(af1, __builtin_bit_cast(bf16x8, vb1), oacc[db]);
  }
}

static __device__ __forceinline__ int slot_base(int c) {
  if (c < 16) return (c - 8) * 2;
  if (c < 24) return 16 + (c - 16) * 3;
  return 40 + (c - 24) * 4;
}

__global__ __launch_bounds__(256) void attn5_k(const unsigned short* __restrict__ Q,
                                               const unsigned short* __restrict__ K,
                                               const unsigned short* __restrict__ VT,
                                               unsigned short* __restrict__ O,
                                               float* __restrict__ Oparts,
                                               float* __restrict__ Sparts)
{
  __shared__ __attribute__((aligned(16))) unsigned short Kl[2][64 * 64];
  __shared__ __attribute__((aligned(16))) unsigned short Vl[2][64 * 64];
  int tid = threadIdx.x, lane = tid & 63, w = tid >> 6;
  int g = lane >> 4, cl = lane & 15;

  int z = 79 - (int)blockIdx.x;
  int c, sp;
  if (z < 8)        { c = z;                    sp = 0; }
  else if (z < 24)  { int t2 = z - 8;  c = 8  + (t2 >> 1); sp = t2 & 1; }
  else if (z < 48)  { int t2 = z - 24; c = 16 + t2 / 3;    sp = t2 % 3; }
  else              { int t2 = z - 48; c = 24 + (t2 >> 2); sp = t2 & 3; }
  int kt0 = sp * 8;
  int kt1 = min(c + 1, kt0 + 8);
  bool lastsplit = (kt1 == c + 1);

  int bh = blockIdx.y, b = bh >> 3, h = bh & 7;
  int q0 = c * 64;
  const unsigned short* Qp = Q + (size_t)(b * SEQ) * D_MODEL + h * HD;
  const unsigned short* Kp = K + (size_t)(b * SEQ) * D_MODEL + h * HD;
  const unsigned short* Vp = VT + (size_t)bh * HD * SEQ;

  int qrow = q0 + w * 16 + cl;
  bf16x8 qf0 = ldb8(Qp + (size_t)qrow * D_MODEL + g * 8);
  bf16x8 qf1 = ldb8(Qp + (size_t)qrow * D_MODEL + 32 + g * 8);

  f32x4 oacc[4] = {};
  float ps = 0.0f;
  int srow = tid >> 2, sslot = tid & 3;

  Stg s0 = stage_load(Kp, Vp, kt0 * 64, srow, sslot);
  stage_write(&Kl[0][0], &Vl[0][0], s0, srow, sslot);
  __syncthreads();

  int buf = 0;
  for (int kt = kt0; kt < kt1 - 1; ++kt) {
    Stg sn = stage_load(Kp, Vp, (kt + 1) * 64, srow, sslot);
    attn_tile<false>(&Kl[buf][0], &Vl[buf][0], qf0, qf1, oacc, ps, g, cl, 0, 0);
    stage_write(&Kl[buf ^ 1][0], &Vl[buf ^ 1][0], sn, srow, sslot);
    __syncthreads();
    buf ^= 1;
  }
  if (lastsplit)
    attn_tile<true>(&Kl[buf][0], &Vl[buf][0], qf0, qf1, oacc, ps, g, cl,
                    (kt1 - 1) * 64, qrow);
  else
    attn_tile<false>(&Kl[buf][0], &Vl[buf][0], qf0, qf1, oacc, ps, g, cl, 0, 0);

  ps += __shfl_xor(ps, 16, 64);
  ps += __shfl_xor(ps, 32, 64);

  if (c < 8) {
    f32x4 inv;
    #pragma unroll
    for (int i = 0; i < 4; ++i) inv[i] = 1.0f / __shfl(ps, g * 4 + i, 64);
    #pragma unroll
    for (int db = 0; db < 4; ++db)
      #pragma unroll
      for (int i = 0; i < 4; ++i)
        O[(size_t)(b * SEQ + q0 + w * 16 + g * 4 + i) * D_MODEL + h * HD + db * 16 + cl] =
            f2bf(oacc[db][i] * inv[i]);
  } else {
    size_t slot = (size_t)bh * 72 + slot_base(c) + sp;
    float* Op = Oparts + slot * 4096;
    float* Sp = Sparts + slot * 64;
    #pragma unroll
    for (int db = 0; db < 4; ++db)
      #pragma unroll
      for (int i = 0; i < 4; ++i)
        Op[(w * 16 + g * 4 + i) * 64 + db * 16 + cl] = oacc[db][i];
    if (g == 0) Sp[w * 16 + cl] = ps;
  }
}

__global__ __launch_bounds__(256) void attn_comb_k(const float* __restrict__ Oparts,
                                                   const float* __restrict__ Sparts,
                                                   unsigned short* __restrict__ O) {
  int t  = threadIdx.x;
  int c  = 8 + (int)(blockIdx.x % 24);
  int bh = (int)(blockIdx.x / 24);
  int b = bh >> 3, h = bh & 7;
  int ns = (c + 8) >> 3;
  size_t slot = (size_t)bh * 72 + slot_base(c);
  const float* O0 = Oparts + slot * 4096;
  const float* S0 = Sparts + slot * 64;
  int r = t >> 2, d0 = (t & 3) * 16;
  f32x4 a0 = {}, a1 = {}, a2 = {}, a3 = {};
  float s = 0.0f;
  for (int si = 0; si < ns; ++si) {
    const float* o = O0 + si * 4096 + r * 64 + d0;
    a0 += *(const f32x4*)(o);
    a1 += *(const f32x4*)(o + 4);
    a2 += *(const f32x4*)(o + 8);
    a3 += *(const f32x4*)(o + 12);
    s  += S0[si * 64 + r];
  }
  float inv = 1.0f / s;
  u16x8 w0, w1;
  #pragma unroll
  for (int j = 0; j < 4; ++j) {
    w0[j]     = f2bf(a0[j] * inv); w0[4 + j] = f2bf(a1[j] * inv);
    w1[j]     = f2bf(a2[j] * inv); w1[4 + j] = f2bf(a3[j] * inv);
  }
  unsigned short* dst = O + (size_t)(b * SEQ + c * 64 + r) * D_MODEL + h * HD + d0;
  *(u16x8*)(dst)     = w0;
  *(u16x8*)(dst + 8) = w1;
}

// ---------------- launch ----------------
extern "C" void kernel_launch(void* const* d_in, const int* in_sizes, int n_in,
                              void* d_out, int out_size, void* d_ws, size_t ws_size,
                              hipStream_t stream) {
  (void)in_sizes; (void)n_in; (void)out_size; (void)ws_size;
  const float* x   = (const float*)d_in[0];
  const float* qw  = (const float*)d_in[1];
  const float* qb  = (const float*)d_in[2];
  const float* kw  = (const float*)d_in[3];
  const float* kbi = (const float*)d_in[4];
  const float* vw  = (const float*)d_in[5];
  const float* vb  = (const float*)d_in[6];
  const float* ow  = (const float*)d_in[7];
  const float* ob  = (const float*)d_in[8];
  const float* w0  = (const float*)d_in[9];
  const float* b0  = (const float*)d_in[10];
  const float* w1  = (const float*)d_in[11];
  const float* b1  = (const float*)d_in[12];
  const float* w2  = (const float*)d_in[13];
  const float* b2  = (const float*)d_in[14];
  const float* anw = (const float*)d_in[15];
  const float* fnw = (const float*)d_in[16];

  char* ws = (char*)d_ws;
  float*          h    = (float*)ws;                              // 0-8MB fp32 residual
  unsigned short* xn   = (unsigned short*)(ws + (8u  << 20));     // 8-12
  unsigned short* q    = (unsigned short*)(ws + (12u << 20));     // 12-16
  unsigned short* k    = (unsigned short*)(ws + (16u << 20));     // 16-20
  unsigned short* v    = (unsigned short*)(ws + (20u << 20));     // 20-24
  unsigned short* vt   = (unsigned short*)(ws + (24u << 20));     // 24-28
  unsigned short* ao   = (unsigned short*)(ws + (28u << 20));     // 28-32
  unsigned short* y    = (unsigned short*)(ws + (32u << 20));     // 32-36
  unsigned short* hbuf = (unsigned short*)(ws + (12u << 20));     // 12-28 (aliases q,k,v,vt)
  unsigned short* Wq   = (unsigned short*)(ws + (36u << 20));     // 36-42
  unsigned short* Wo   = (unsigned short*)(ws + (42u << 20));     // 42-44
  unsigned short* W01  = (unsigned short*)(ws + (44u << 20));     // 44-60
  unsigned short* W2   = (unsigned short*)(ws + (60u << 20));     // 60-68
  float*          Opar = (float*)(ws + (68u << 20));              // 68-86 (18MB)
  float*          Spar = (float*)(ws + (86u << 20));              // 86-86.3

  prep_t<<<4096, 64, 0, stream>>>(qw, kw, vw, ow, w0, w1, w2, Wq, Wo, W01, W2);
  initrms_k<<<BTOK / 4, 256, 0, stream>>>(x, anw, h, xn);

  for (int l = 0; l < 4; ++l) {
    size_t bo  = (size_t)l * D_MODEL;
    size_t bho = (size_t)l * HIDE;

    gemm5_k<EPI_QKV, 128, 64><<<768, 256, 0, stream>>>(
        xn, Wq + (size_t)l * 786432, qb + bo, kbi + bo, vb + bo,
        q, k, v, BTOK, 3 * D_MODEL, D_MODEL);
    vtrans_k<<<dim3(32, 16), 64, 0, stream>>>(v, vt);
    attn5_k<<<dim3(80, 16), 256, 0, stream>>>(q, k, vt, ao, Opar, Spar);
    attn_comb_k<<<384, 256, 0, stream>>>(Opar, Spar, ao);
    gemm5_k<EPI_PLAIN, 64, 64><<<512, 256, 0, stream>>>(
        ao, Wo + (size_t)l * 262144, ob + bo, nullptr, nullptr,
        y, nullptr, nullptr, BTOK, D_MODEL, D_MODEL);
    addrms_k<<<BTOK / 4, 256, 0, stream>>>(h, y, fnw + bo, xn);

    gemm5_k<EPI_PLAIN, 128, 128><<<512, 256, 0, stream>>>(
        xn, W01 + (size_t)l * 2097152, b0 + bho, nullptr, nullptr,
        hbuf, nullptr, nullptr, BTOK, HIDE, D_MODEL);
    gemm5_k<EPI_GATE, 128, 128><<<512, 256, 0, stream>>>(
        xn, W01 + (size_t)l * 2097152 + 1048576, b1 + bho, nullptr, nullptr,
        hbuf, nullptr, nullptr, BTOK, HIDE, D_MODEL);
    gemm5_k<EPI_PLAIN, 64, 64><<<512, 256, 0, stream>>>(
        hbuf, W2 + (size_t)l * 1048576, b2 + bo, nullptr, nullptr,
        y, nullptr, nullptr, BTOK, D_MODEL, HIDE);
    addrms_k<<<BTOK / 4, 256, 0, stream>>>(
        h, y, (l < 3 ? anw + bo + D_MODEL : anw), xn);
  }
  hipMemcpyAsync(d_out, h, (size_t)BTOK * D_MODEL * sizeof(float),
                 hipMemcpyDeviceToDevice, stream);
}

// Round 10
// 477.168 us; speedup vs baseline: 3.4199x; 1.1245x over previous
//
#include <hip/hip_runtime.h>
#include <math.h>

// ---------------- types ----------------
typedef unsigned int   uint4v __attribute__((ext_vector_type(4)));
typedef float          f32x4  __attribute__((ext_vector_type(4)));
typedef __bf16         bf16x8 __attribute__((ext_vector_type(8)));
typedef unsigned short u16x8  __attribute__((ext_vector_type(8)));
typedef unsigned short u16x4  __attribute__((ext_vector_type(4)));

#define D_MODEL 512
#define SEQ     2048
#define BTOK    4096   // B * SEQ
#define HIDE    2048
#define NHEAD   8
#define HD      64

static __device__ __forceinline__ unsigned short f2bf(float f) {
  __bf16 b = (__bf16)f;
  return __builtin_bit_cast(unsigned short, b);
}
static __device__ __forceinline__ float bf2f(unsigned short b) {
  union { unsigned u; float f; } v; v.u = ((unsigned)b) << 16;
  return v.f;
}
static __device__ __forceinline__ bf16x8 ldb8(const unsigned short* p) {
  return __builtin_bit_cast(bf16x8, *(const uint4v*)p);
}
static __device__ __forceinline__ f32x4 mfma16(bf16x8 a, bf16x8 b, f32x4 c) {
  return __builtin_amdgcn_mfma_f32_16x16x32_bf16(a, b, c, 0, 0, 0);
}

typedef unsigned int u32_g __attribute__((address_space(1)));
typedef unsigned int u32_l __attribute__((address_space(3)));
static __device__ __forceinline__ void gload16(const unsigned short* g, unsigned short* l) {
  __builtin_amdgcn_global_load_lds((const u32_g*)(const void*)g,
                                   (u32_l*)(void*)l, 16, 0, 0);
}

#define SWZ(r, off) ((off) ^ (((r) & 7) << 4))
#define QSCALE 0.180336880f   // 0.125 * log2(e)

// ---------------- weight prep: LDS-tiled transpose f32 [K][N] -> bf16 [N][K] ----
__global__ __launch_bounds__(64) void prep_t(
    const float* __restrict__ qw, const float* __restrict__ kw,
    const float* __restrict__ vw, const float* __restrict__ ow,
    const float* __restrict__ w0, const float* __restrict__ w1,
    const float* __restrict__ w2,
    unsigned short* __restrict__ Wq, unsigned short* __restrict__ Wo,
    unsigned short* __restrict__ W01, unsigned short* __restrict__ W2)
{
  int bid = blockIdx.x;
  int l = bid >> 10;
  int r = bid & 1023;
  const float* src; unsigned short* dst;
  int tr, tc, srcN, dstK;
  if (r < 192) {
    int sel = r >> 6, tt = r & 63;
    tr = tt >> 3; tc = tt & 7;
    src = (sel == 0 ? qw : sel == 1 ? kw : vw) + (size_t)l * 262144;
    srcN = 512; dstK = 512;
    dst = Wq + (size_t)l * 786432 + (size_t)(sel * 512 + tc * 64) * 512 + tr * 64;
  } else if (r < 256) {
    int tt = r - 192; tr = tt >> 3; tc = tt & 7;
    src = ow + (size_t)l * 262144; srcN = 512; dstK = 512;
    dst = Wo + (size_t)l * 262144 + (size_t)(tc * 64) * 512 + tr * 64;
  } else if (r < 768) {
    int idx = r - 256; int sel = idx >> 8; int tt = idx & 255;
    tr = tt >> 5; tc = tt & 31;
    src = (sel ? w1 : w0) + (size_t)l * 1048576; srcN = 2048; dstK = 512;
    dst = W01 + (size_t)l * 2097152 + (size_t)sel * 1048576 + (size_t)(tc * 64) * 512 + tr * 64;
  } else {
    int tt = r - 768; tr = tt >> 3; tc = tt & 7;
    src = w2 + (size_t)l * 1048576; srcN = 512; dstK = 2048;
    dst = W2 + (size_t)l * 1048576 + (size_t)(tc * 64) * 2048 + tr * 64;
  }
  src += (size_t)(tr * 64) * srcN + tc * 64;
  __shared__ unsigned short T[64][68];
  int t = threadIdx.x;
  #pragma unroll
  for (int it = 0; it < 16; ++it) {
    int row = it * 4 + (t >> 4);
    int col = (t & 15) * 4;
    f32x4 v4 = *(const f32x4*)(src + (size_t)row * srcN + col);
    u16x4 o; o[0] = f2bf(v4.x); o[1] = f2bf(v4.y); o[2] = f2bf(v4.z); o[3] = f2bf(v4.w);
    *(u16x4*)&T[row][col] = o;
  }
  __syncthreads();
  unsigned short* orow = dst + (size_t)t * dstK;
  #pragma unroll
  for (int j0 = 0; j0 < 8; ++j0) {
    u16x8 o;
    #pragma unroll
    for (int j = 0; j < 8; ++j) o[j] = T[j0 * 8 + j][t];
    *(u16x8*)(orow + j0 * 8) = o;
  }
}

// ---------------- initrms: h = x; xn = rms(x)*w ----------------
__global__ __launch_bounds__(256) void initrms_k(const float* __restrict__ x,
                                                 const float* __restrict__ w,
                                                 float* __restrict__ h,
                                                 unsigned short* __restrict__ xn) {
  int row  = blockIdx.x * 4 + (threadIdx.x >> 6);
  int lane = threadIdx.x & 63;
  const float* xr = x + (size_t)row * D_MODEL + lane * 8;
  f32x4 v0 = *(const f32x4*)(xr);
  f32x4 v1 = *(const f32x4*)(xr + 4);
  *(f32x4*)(h + (size_t)row * D_MODEL + lane * 8)     = v0;
  *(f32x4*)(h + (size_t)row * D_MODEL + lane * 8 + 4) = v1;
  float ss = v0.x*v0.x + v0.y*v0.y + v0.z*v0.z + v0.w*v0.w
           + v1.x*v1.x + v1.y*v1.y + v1.z*v1.z + v1.w*v1.w;
  #pragma unroll
  for (int m = 1; m < 64; m <<= 1) ss += __shfl_xor(ss, m, 64);
  float inv = 1.0f / (sqrtf(ss * (1.0f / D_MODEL)) + 1e-6f);
  f32x4 w0 = *(const f32x4*)(w + lane * 8);
  f32x4 w1 = *(const f32x4*)(w + lane * 8 + 4);
  u16x8 o;
  o[0] = f2bf(v0.x * w0.x * inv); o[1] = f2bf(v0.y * w0.y * inv);
  o[2] = f2bf(v0.z * w0.z * inv); o[3] = f2bf(v0.w * w0.w * inv);
  o[4] = f2bf(v1.x * w1.x * inv); o[5] = f2bf(v1.y * w1.y * inv);
  o[6] = f2bf(v1.z * w1.z * inv); o[7] = f2bf(v1.w * w1.w * inv);
  *(u16x8*)(xn + (size_t)row * D_MODEL + lane * 8) = o;
}

// ---------------- addrms: h += y(bf16); xn = rms(h)*w ----------------
__global__ __launch_bounds__(256) void addrms_k(float* __restrict__ h,
                                                const unsigned short* __restrict__ y,
                                                const float* __restrict__ w,
                                                unsigned short* __restrict__ xn) {
  int row  = blockIdx.x * 4 + (threadIdx.x >> 6);
  int lane = threadIdx.x & 63;
  float* hr = h + (size_t)row * D_MODEL + lane * 8;
  f32x4 v0 = *(const f32x4*)(hr);
  f32x4 v1 = *(const f32x4*)(hr + 4);
  u16x8 yy = *(const u16x8*)(y + (size_t)row * D_MODEL + lane * 8);
  v0.x += bf2f(yy[0]); v0.y += bf2f(yy[1]); v0.z += bf2f(yy[2]); v0.w += bf2f(yy[3]);
  v1.x += bf2f(yy[4]); v1.y += bf2f(yy[5]); v1.z += bf2f(yy[6]); v1.w += bf2f(yy[7]);
  *(f32x4*)(hr)     = v0;
  *(f32x4*)(hr + 4) = v1;
  float ss = v0.x*v0.x + v0.y*v0.y + v0.z*v0.z + v0.w*v0.w
           + v1.x*v1.x + v1.y*v1.y + v1.z*v1.z + v1.w*v1.w;
  #pragma unroll
  for (int m = 1; m < 64; m <<= 1) ss += __shfl_xor(ss, m, 64);
  float inv = 1.0f / (sqrtf(ss * (1.0f / D_MODEL)) + 1e-6f);
  f32x4 w0 = *(const f32x4*)(w + lane * 8);
  f32x4 w1 = *(const f32x4*)(w + lane * 8 + 4);
  u16x8 o;
  o[0] = f2bf(v0.x * w0.x * inv); o[1] = f2bf(v0.y * w0.y * inv);
  o[2] = f2bf(v0.z * w0.z * inv); o[3] = f2bf(v0.w * w0.w * inv);
  o[4] = f2bf(v1.x * w1.x * inv); o[5] = f2bf(v1.y * w1.y * inv);
  o[6] = f2bf(v1.z * w1.z * inv); o[7] = f2bf(v1.w * w1.w * inv);
  *(u16x8*)(xn + (size_t)row * D_MODEL + lane * 8) = o;
}

// ---------------- GEMM v5: single-buffer 2-barrier + T2 swizzle ----------
#define EPI_QKV   0
#define EPI_PLAIN 1

template<int EPI, int BM, int BN>
__global__ __launch_bounds__(256) void gemm5_k(
    const unsigned short* __restrict__ A,
    const unsigned short* __restrict__ Bt,    // [N][K]
    const float* __restrict__ bias0,
    const float* __restrict__ bias1,
    const float* __restrict__ bias2,
    void* __restrict__ out0,
    void* __restrict__ out1,
    void* __restrict__ out2,
    int M, int N, int K)
{
  constexpr int MF = BM / 32;
  constexpr int NF = BN / 32;
  constexpr int ALOADS = BM / 32;
  constexpr int BLOADS = BN / 32;

  __shared__ __attribute__((aligned(16))) unsigned short Al[BM * 64];
  __shared__ __attribute__((aligned(16))) unsigned short Bl[BN * 64];

  int nblk = gridDim.x;
  int orig = blockIdx.x;
  int qq = nblk >> 3, rr = nblk & 7, xcd = orig & 7, pos = orig >> 3;
  int lid = (xcd < rr ? xcd * (qq + 1) : rr * (qq + 1) + (xcd - rr) * qq) + pos;
  int numN = N / BN;
  int mt = lid / numN, nt = lid % numN;
  int m0 = mt * BM, n0 = nt * BN;

  int tid = threadIdx.x, lane = tid & 63, w = tid >> 6;
  int wm = w >> 1, wn = w & 1;
  int g = lane >> 4, c = lane & 15;
  int srow = lane >> 3, sslot = lane & 7;
  int sgc = (sslot ^ srow) * 8;            // pre-swizzled global col

  const unsigned short* aG = A  + (size_t)(m0 + w * (BM / 4) + srow) * K + sgc;
  const unsigned short* bG = Bt + (size_t)(n0 + w * (BN / 4) + srow) * K + sgc;
  unsigned short* aL = &Al[(w * (BM / 4) + srow) * 64 + sslot * 8];
  unsigned short* bL = &Bl[(w * (BN / 4) + srow) * 64 + sslot * 8];

  f32x4 acc[MF][NF] = {};
  int KT = K >> 6;
  int rk = c & 7;

  for (int kt = 0; kt < KT; ++kt) {
    if (kt) __syncthreads();
    #pragma unroll
    for (int t = 0; t < ALOADS; ++t)
      gload16(aG + (size_t)(t * 8) * K + kt * 64, aL + t * 8 * 64);
    #pragma unroll
    for (int t = 0; t < BLOADS; ++t)
      gload16(bG + (size_t)(t * 8) * K + kt * 64, bL + t * 8 * 64);
    __syncthreads();
    #pragma unroll
    for (int ks = 0; ks < 2; ++ks) {
      int slot = (ks * 4 + g) ^ rk;
      bf16x8 af[MF], bfr[NF];
      #pragma unroll
      for (int i = 0; i < MF; ++i)
        af[i] = ldb8(&Al[(wm * (MF * 16) + i * 16 + c) * 64 + slot * 8]);
      #pragma unroll
      for (int j = 0; j < NF; ++j)
        bfr[j] = ldb8(&Bl[(wn * (NF * 16) + j * 16 + c) * 64 + slot * 8]);
      #pragma unroll
      for (int i = 0; i < MF; ++i)
        #pragma unroll
        for (int j = 0; j < NF; ++j)
          acc[i][j] = mfma16(af[i], bfr[j], acc[i][j]);
    }
  }

  #pragma unroll
  for (int i = 0; i < MF; ++i) {
    int mrow = m0 + wm * (MF * 16) + i * 16 + g * 4;
    #pragma unroll
    for (int j = 0; j < NF; ++j) {
      int n = n0 + wn * (NF * 16) + j * 16 + c;
      if (EPI == EPI_QKV) {
        int sel  = n >> 9;
        int nloc = n & 511;
        const float* bp = sel == 0 ? bias0 : sel == 1 ? bias1 : bias2;
        unsigned short* o = (unsigned short*)(sel == 0 ? out0 : sel == 1 ? out1 : out2);
        float sc = (sel == 0) ? QSCALE : 1.0f;
        float bn = bp[nloc];
        #pragma unroll
        for (int ii = 0; ii < 4; ++ii)
          o[(size_t)(mrow + ii) * D_MODEL + nloc] = f2bf((acc[i][j][ii] + bn) * sc);
      } else {  // EPI_PLAIN
        float bn = bias0[n];
        unsigned short* o = (unsigned short*)out0;
        #pragma unroll
        for (int ii = 0; ii < 4; ++ii)
          o[(size_t)(mrow + ii) * N + n] = f2bf(acc[i][j][ii] + bn);
      }
    }
  }
}

// ---------------- GEMM v5d: fused dual-B gated FFN-up --------------------
// out = (A@W0t + b0) * silu(A@W1t + b1); n-major XCD chunking (B is 8MB).
template<int BM, int BN>
__global__ __launch_bounds__(256) void gemm5d_k(
    const unsigned short* __restrict__ A,
    const unsigned short* __restrict__ B0t,   // [N][K]
    const unsigned short* __restrict__ B1t,   // [N][K]
    const float* __restrict__ bias0,
    const float* __restrict__ bias1,
    unsigned short* __restrict__ out,
    int M, int N, int K)
{
  constexpr int MF = BM / 32;
  constexpr int NF = BN / 32;
  constexpr int ALOADS = BM / 32;
  constexpr int BLOADS = BN / 32;

  __shared__ __attribute__((aligned(16))) unsigned short Al[BM * 64];
  __shared__ __attribute__((aligned(16))) unsigned short B0l[BN * 64];
  __shared__ __attribute__((aligned(16))) unsigned short B1l[BN * 64];

  int nblk = gridDim.x;
  int orig = blockIdx.x;
  int qq = nblk >> 3, rr = nblk & 7, xcd = orig & 7, pos = orig >> 3;
  int lid = (xcd < rr ? xcd * (qq + 1) : rr * (qq + 1) + (xcd - rr) * qq) + pos;
  int numM = M / BM;
  int nt = lid / numM, mt = lid % numM;   // n-major: XCD chunk shares B panel
  int m0 = mt * BM, n0 = nt * BN;

  int tid = threadIdx.x, lane = tid & 63, w = tid >> 6;
  int wm = w >> 1, wn = w & 1;
  int g = lane >> 4, c = lane & 15;
  int srow = lane >> 3, sslot = lane & 7;
  int sgc = (sslot ^ srow) * 8;

  const unsigned short* aG  = A   + (size_t)(m0 + w * (BM / 4) + srow) * K + sgc;
  const unsigned short* b0G = B0t + (size_t)(n0 + w * (BN / 4) + srow) * K + sgc;
  const unsigned short* b1G = B1t + (size_t)(n0 + w * (BN / 4) + srow) * K + sgc;
  unsigned short* aL  = &Al [(w * (BM / 4) + srow) * 64 + sslot * 8];
  unsigned short* b0L = &B0l[(w * (BN / 4) + srow) * 64 + sslot * 8];
  unsigned short* b1L = &B1l[(w * (BN / 4) + srow) * 64 + sslot * 8];

  f32x4 acc0[MF][NF] = {};
  f32x4 acc1[MF][NF] = {};
  int KT = K >> 6;
  int rk = c & 7;

  for (int kt = 0; kt < KT; ++kt) {
    if (kt) __syncthreads();
    #pragma unroll
    for (int t = 0; t < ALOADS; ++t)
      gload16(aG + (size_t)(t * 8) * K + kt * 64, aL + t * 8 * 64);
    #pragma unroll
    for (int t = 0; t < BLOADS; ++t) {
      gload16(b0G + (size_t)(t * 8) * K + kt * 64, b0L + t * 8 * 64);
      gload16(b1G + (size_t)(t * 8) * K + kt * 64, b1L + t * 8 * 64);
    }
    __syncthreads();
    #pragma unroll
    for (int ks = 0; ks < 2; ++ks) {
      int slot = (ks * 4 + g) ^ rk;
      bf16x8 af[MF], b0f[NF], b1f[NF];
      #pragma unroll
      for (int i = 0; i < MF; ++i)
        af[i] = ldb8(&Al[(wm * (MF * 16) + i * 16 + c) * 64 + slot * 8]);
      #pragma unroll
      for (int j = 0; j < NF; ++j) {
        b0f[j] = ldb8(&B0l[(wn * (NF * 16) + j * 16 + c) * 64 + slot * 8]);
        b1f[j] = ldb8(&B1l[(wn * (NF * 16) + j * 16 + c) * 64 + slot * 8]);
      }
      #pragma unroll
      for (int i = 0; i < MF; ++i)
        #pragma unroll
        for (int j = 0; j < NF; ++j) {
          acc0[i][j] = mfma16(af[i], b0f[j], acc0[i][j]);
          acc1[i][j] = mfma16(af[i], b1f[j], acc1[i][j]);
        }
    }
  }

  #pragma unroll
  for (int i = 0; i < MF; ++i) {
    int mrow = m0 + wm * (MF * 16) + i * 16 + g * 4;
    #pragma unroll
    for (int j = 0; j < NF; ++j) {
      int n = n0 + wn * (NF * 16) + j * 16 + c;
      float b0n = bias0[n], b1n = bias1[n];
      #pragma unroll
      for (int ii = 0; ii < 4; ++ii) {
        float a  = acc0[i][j][ii] + b0n;
        float gv = acc1[i][j][ii] + b1n;
        float s  = gv / (1.0f + __expf(-gv));
        out[(size_t)(mrow + ii) * N + n] = f2bf(a * s);
      }
    }
  }
}

// ---------------- V transpose: v [B*S][512] -> vt [bh][d][s] ----------------
__global__ __launch_bounds__(64) void vtrans_k(const unsigned short* __restrict__ V,
                                               unsigned short* __restrict__ VT) {
  __shared__ unsigned short T[64][76];
  int t = threadIdx.x;
  int s0 = blockIdx.x * 64;
  int bh = blockIdx.y, b = bh >> 3, h = bh & 7;
  const unsigned short* src = V + (size_t)(b * SEQ + s0) * D_MODEL + h * HD;
  #pragma unroll
  for (int j0 = 0; j0 < 8; ++j0) {
    u16x8 vv = *(const u16x8*)(src + (size_t)t * D_MODEL + j0 * 8);
    *(u16x8*)&T[t][j0 * 8] = vv;
  }
  __syncthreads();
  unsigned short* dst = VT + ((size_t)bh * HD + t) * SEQ + s0;
  #pragma unroll
  for (int j0 = 0; j0 < 8; ++j0) {
    u16x8 o;
    #pragma unroll
    for (int j = 0; j < 8; ++j) o[j] = T[j0 * 8 + j][t];
    *(u16x8*)(dst + j0 * 8) = o;
  }
}

// ---------------- attention v5: split-K flash, no-max softmax ------------
struct Stg { uint4v k0, k1, v0, v1; };

static __device__ __forceinline__ Stg stage_load(const unsigned short* Kp,
                                                 const unsigned short* Vp,
                                                 int kbase, int srow, int sslot) {
  Stg s;
  const unsigned short* kr = Kp + (size_t)(kbase + srow) * D_MODEL + sslot * 8;
  s.k0 = *(const uint4v*)kr;
  s.k1 = *(const uint4v*)(kr + 32);
  const unsigned short* vr = Vp + (size_t)srow * SEQ + kbase + sslot * 8;
  s.v0 = *(const uint4v*)vr;
  s.v1 = *(const uint4v*)(vr + 32);
  return s;
}
static __device__ __forceinline__ void stage_write(unsigned short* Klb, unsigned short* Vlb,
                                                   const Stg& s, int srow, int sslot) {
  char* kb = (char*)Klb;
  *(uint4v*)(kb + SWZ(srow, srow * 128 + sslot * 16))       = s.k0;
  *(uint4v*)(kb + SWZ(srow, srow * 128 + (sslot + 4) * 16)) = s.k1;
  char* vb = (char*)Vlb;
  *(uint4v*)(vb + SWZ(srow, srow * 128 + sslot * 16))       = s.v0;
  *(uint4v*)(vb + SWZ(srow, srow * 128 + (sslot + 4) * 16)) = s.v1;
}

template<bool MASKED>
static __device__ __forceinline__ void attn_tile(
    const unsigned short* Klb, const unsigned short* Vlb,
    bf16x8 qf0, bf16x8 qf1, f32x4* oacc, float& ps,
    int g, int c, int kbase, int qrow)
{
  f32x4 z[4];
  #pragma unroll
  for (int hh = 0; hh < 4; ++hh) {
    int r = hh * 16 + c;
    const char* base = (const char*)Klb;
    bf16x8 k0 = ldb8((const unsigned short*)(base + SWZ(r, r * 128 + g * 16)));
    bf16x8 k1 = ldb8((const unsigned short*)(base + SWZ(r, r * 128 + 64 + g * 16)));
    f32x4 t = {};
    t = mfma16(k0, qf0, t);
    t = mfma16(k1, qf1, t);
    z[hh] = t;
  }
  u16x8 pa0, pa1;
  #pragma unroll
  for (int hh = 0; hh < 4; ++hh) {
    #pragma unroll
    for (int i = 0; i < 4; ++i) {
      float p = exp2f(z[hh][i]);
      if (MASKED && (kbase + hh * 16 + g * 4 + i > qrow)) p = 0.0f;
      ps += p;
      unsigned short pb = f2bf(p);
      if (hh < 2) pa0[hh * 4 + i] = pb;
      else        pa1[(hh - 2) * 4 + i] = pb;
    }
  }
  bf16x8 af0 = __builtin_bit_cast(bf16x8, pa0);
  bf16x8 af1 = __builtin_bit_cast(bf16x8, pa1);
  #pragma unroll
  for (int db = 0; db < 4; ++db) {
    int r = db * 16 + c;
    const char* base = (const char*)Vlb;
    u16x4 v00 = *(const u16x4*)(base + SWZ(r, r * 128 + g * 8));
    u16x4 v01 = *(const u16x4*)(base + SWZ(r, r * 128 + 32 + g * 8));
    u16x4 v10 = *(const u16x4*)(base + SWZ(r, r * 128 + 64 + g * 8));
    u16x4 v11 = *(const u16x4*)(base + SWZ(r, r * 128 + 96 + g * 8));
    u16x8 vb0, vb1;
    #pragma unroll
    for (int j = 0; j < 4; ++j) {
      vb0[j] = v00[j]; vb0[4 + j] = v01[j];
      vb1[j] = v10[j]; vb1[4 + j] = v11[j];
    }
    oacc[db] = mfma16(af0, __builtin_bit_cast(bf16x8, vb0), oacc[db]);
    oacc[db] = mfma16(af1, __builtin_bit_cast(bf16x8, vb1), oacc[db]);
  }
}

static __device__ __forceinline__ int slot_base(int c) {
  if (c < 16) return (c - 8) * 2;
  if (c < 24) return 16 + (c - 16) * 3;
  return 40 + (c - 24) * 4;
}

__global__ __launch_bounds__(256) void attn5_k(const unsigned short* __restrict__ Q,
                                               const unsigned short* __restrict__ K,
                                               const unsigned short* __restrict__ VT,
                                               unsigned short* __restrict__ O,
                                               float* __restrict__ Oparts,
                                               float* __restrict__ Sparts)
{
  __shared__ __attribute__((aligned(16))) unsigned short Kl[2][64 * 64];
  __shared__ __attribute__((aligned(16))) unsigned short Vl[2][64 * 64];
  int tid = threadIdx.x, lane = tid & 63, w = tid >> 6;
  int g = lane >> 4, cl = lane & 15;

  int z = 79 - (int)blockIdx.x;
  int c, sp;
  if (z < 8)        { c = z;                    sp = 0; }
  else if (z < 24)  { int t2 = z - 8;  c = 8  + (t2 >> 1); sp = t2 & 1; }
  else if (z < 48)  { int t2 = z - 24; c = 16 + t2 / 3;    sp = t2 % 3; }
  else              { int t2 = z - 48; c = 24 + (t2 >> 2); sp = t2 & 3; }
  int kt0 = sp * 8;
  int kt1 = min(c + 1, kt0 + 8);
  bool lastsplit = (kt1 == c + 1);

  int bh = blockIdx.y, b = bh >> 3, h = bh & 7;
  int q0 = c * 64;
  const unsigned short* Qp = Q + (size_t)(b * SEQ) * D_MODEL + h * HD;
  const unsigned short* Kp = K + (size_t)(b * SEQ) * D_MODEL + h * HD;
  const unsigned short* Vp = VT + (size_t)bh * HD * SEQ;

  int qrow = q0 + w * 16 + cl;
  bf16x8 qf0 = ldb8(Qp + (size_t)qrow * D_MODEL + g * 8);
  bf16x8 qf1 = ldb8(Qp + (size_t)qrow * D_MODEL + 32 + g * 8);

  f32x4 oacc[4] = {};
  float ps = 0.0f;
  int srow = tid >> 2, sslot = tid & 3;

  Stg s0 = stage_load(Kp, Vp, kt0 * 64, srow, sslot);
  stage_write(&Kl[0][0], &Vl[0][0], s0, srow, sslot);
  __syncthreads();

  int buf = 0;
  for (int kt = kt0; kt < kt1 - 1; ++kt) {
    Stg sn = stage_load(Kp, Vp, (kt + 1) * 64, srow, sslot);
    attn_tile<false>(&Kl[buf][0], &Vl[buf][0], qf0, qf1, oacc, ps, g, cl, 0, 0);
    stage_write(&Kl[buf ^ 1][0], &Vl[buf ^ 1][0], sn, srow, sslot);
    __syncthreads();
    buf ^= 1;
  }
  if (lastsplit)
    attn_tile<true>(&Kl[buf][0], &Vl[buf][0], qf0, qf1, oacc, ps, g, cl,
                    (kt1 - 1) * 64, qrow);
  else
    attn_tile<false>(&Kl[buf][0], &Vl[buf][0], qf0, qf1, oacc, ps, g, cl, 0, 0);

  ps += __shfl_xor(ps, 16, 64);
  ps += __shfl_xor(ps, 32, 64);

  if (c < 8) {
    f32x4 inv;
    #pragma unroll
    for (int i = 0; i < 4; ++i) inv[i] = 1.0f / __shfl(ps, g * 4 + i, 64);
    #pragma unroll
    for (int db = 0; db < 4; ++db)
      #pragma unroll
      for (int i = 0; i < 4; ++i)
        O[(size_t)(b * SEQ + q0 + w * 16 + g * 4 + i) * D_MODEL + h * HD + db * 16 + cl] =
            f2bf(oacc[db][i] * inv[i]);
  } else {
    size_t slot = (size_t)bh * 72 + slot_base(c) + sp;
    float* Op = Oparts + slot * 4096;
    float* Sp = Sparts + slot * 64;
    #pragma unroll
    for (int db = 0; db < 4; ++db)
      #pragma unroll
      for (int i = 0; i < 4; ++i)
        Op[(w * 16 + g * 4 + i) * 64 + db * 16 + cl] = oacc[db][i];
    if (g == 0) Sp[w * 16 + cl] = ps;
  }
}

__global__ __launch_bounds__(256) void attn_comb_k(const float* __restrict__ Oparts,
                                                   const float* __restrict__ Sparts,
                                                   unsigned short* __restrict__ O) {
  int t  = threadIdx.x;
  int c  = 8 + (int)(blockIdx.x % 24);
  int bh = (int)(blockIdx.x / 24);
  int b = bh >> 3, h = bh & 7;
  int ns = (c + 8) >> 3;
  size_t slot = (size_t)bh * 72 + slot_base(c);
  const float* O0 = Oparts + slot * 4096;
  const float* S0 = Sparts + slot * 64;
  int r = t >> 2, d0 = (t & 3) * 16;
  f32x4 a0 = {}, a1 = {}, a2 = {}, a3 = {};
  float s = 0.0f;
  for (int si = 0; si < ns; ++si) {
    const float* o = O0 + si * 4096 + r * 64 + d0;
    a0 += *(const f32x4*)(o);
    a1 += *(const f32x4*)(o + 4);
    a2 += *(const f32x4*)(o + 8);
    a3 += *(const f32x4*)(o + 12);
    s  += S0[si * 64 + r];
  }
  float inv = 1.0f / s;
  u16x8 w0, w1;
  #pragma unroll
  for (int j = 0; j < 4; ++j) {
    w0[j]     = f2bf(a0[j] * inv); w0[4 + j] = f2bf(a1[j] * inv);
    w1[j]     = f2bf(a2[j] * inv); w1[4 + j] = f2bf(a3[j] * inv);
  }
  unsigned short* dst = O + (size_t)(b * SEQ + c * 64 + r) * D_MODEL + h * HD + d0;
  *(u16x8*)(dst)     = w0;
  *(u16x8*)(dst + 8) = w1;
}

// ---------------- launch ----------------
extern "C" void kernel_launch(void* const* d_in, const int* in_sizes, int n_in,
                              void* d_out, int out_size, void* d_ws, size_t ws_size,
                              hipStream_t stream) {
  (void)in_sizes; (void)n_in; (void)out_size; (void)ws_size;
  const float* x   = (const float*)d_in[0];
  const float* qw  = (const float*)d_in[1];
  const float* qb  = (const float*)d_in[2];
  const float* kw  = (const float*)d_in[3];
  const float* kbi = (const float*)d_in[4];
  const float* vw  = (const float*)d_in[5];
  const float* vb  = (const float*)d_in[6];
  const float* ow  = (const float*)d_in[7];
  const float* ob  = (const float*)d_in[8];
  const float* w0  = (const float*)d_in[9];
  const float* b0  = (const float*)d_in[10];
  const float* w1  = (const float*)d_in[11];
  const float* b1  = (const float*)d_in[12];
  const float* w2  = (const float*)d_in[13];
  const float* b2  = (const float*)d_in[14];
  const float* anw = (const float*)d_in[15];
  const float* fnw = (const float*)d_in[16];

  char* ws = (char*)d_ws;
  float*          h    = (float*)ws;                              // 0-8MB fp32 residual
  unsigned short* xn   = (unsigned short*)(ws + (8u  << 20));     // 8-12
  unsigned short* q    = (unsigned short*)(ws + (12u << 20));     // 12-16
  unsigned short* k    = (unsigned short*)(ws + (16u << 20));     // 16-20
  unsigned short* v    = (unsigned short*)(ws + (20u << 20));     // 20-24
  unsigned short* vt   = (unsigned short*)(ws + (24u << 20));     // 24-28
  unsigned short* ao   = (unsigned short*)(ws + (28u << 20));     // 28-32
  unsigned short* y    = (unsigned short*)(ws + (32u << 20));     // 32-36
  unsigned short* hbuf = (unsigned short*)(ws + (12u << 20));     // 12-28 (aliases q,k,v,vt)
  unsigned short* Wq   = (unsigned short*)(ws + (36u << 20));     // 36-42
  unsigned short* Wo   = (unsigned short*)(ws + (42u << 20));     // 42-44
  unsigned short* W01  = (unsigned short*)(ws + (44u << 20));     // 44-60
  unsigned short* W2   = (unsigned short*)(ws + (60u << 20));     // 60-68
  float*          Opar = (float*)(ws + (68u << 20));              // 68-86 (18MB)
  float*          Spar = (float*)(ws + (86u << 20));              // 86-86.3

  prep_t<<<4096, 64, 0, stream>>>(qw, kw, vw, ow, w0, w1, w2, Wq, Wo, W01, W2);
  initrms_k<<<BTOK / 4, 256, 0, stream>>>(x, anw, h, xn);

  for (int l = 0; l < 4; ++l) {
    size_t bo  = (size_t)l * D_MODEL;
    size_t bho = (size_t)l * HIDE;

    gemm5_k<EPI_QKV, 128, 64><<<768, 256, 0, stream>>>(
        xn, Wq + (size_t)l * 786432, qb + bo, kbi + bo, vb + bo,
        q, k, v, BTOK, 3 * D_MODEL, D_MODEL);
    vtrans_k<<<dim3(32, 16), 64, 0, stream>>>(v, vt);
    attn5_k<<<dim3(80, 16), 256, 0, stream>>>(q, k, vt, ao, Opar, Spar);
    attn_comb_k<<<384, 256, 0, stream>>>(Opar, Spar, ao);
    gemm5_k<EPI_PLAIN, 64, 64><<<512, 256, 0, stream>>>(
        ao, Wo + (size_t)l * 262144, ob + bo, nullptr, nullptr,
        y, nullptr, nullptr, BTOK, D_MODEL, D_MODEL);
    addrms_k<<<BTOK / 4, 256, 0, stream>>>(h, y, fnw + bo, xn);

    gemm5d_k<128, 64><<<1024, 256, 0, stream>>>(
        xn, W01 + (size_t)l * 2097152, W01 + (size_t)l * 2097152 + 1048576,
        b0 + bho, b1 + bho, hbuf, BTOK, HIDE, D_MODEL);
    gemm5_k<EPI_PLAIN, 64, 64><<<512, 256, 0, stream>>>(
        hbuf, W2 + (size_t)l * 1048576, b2 + bo, nullptr, nullptr,
        y, nullptr, nullptr, BTOK, D_MODEL, HIDE);
    addrms_k<<<BTOK / 4, 256, 0, stream>>>(
        h, y, (l < 3 ? anw + bo + D_MODEL : anw), xn);
  }
  hipMemcpyAsync(d_out, h, (size_t)BTOK * D_MODEL * sizeof(float),
                 hipMemcpyDeviceToDevice, stream);
}

// Round 11
// 471.416 us; speedup vs baseline: 3.4616x; 1.0122x over previous
//
#include <hip/hip_runtime.h>
#include <math.h>

// ---------------- types ----------------
typedef unsigned int   uint4v __attribute__((ext_vector_type(4)));
typedef float          f32x4  __attribute__((ext_vector_type(4)));
typedef __bf16         bf16x8 __attribute__((ext_vector_type(8)));
typedef unsigned short u16x8  __attribute__((ext_vector_type(8)));
typedef unsigned short u16x4  __attribute__((ext_vector_type(4)));

#define D_MODEL 512
#define SEQ     2048
#define BTOK    4096   // B * SEQ
#define HIDE    2048
#define NHEAD   8
#define HD      64

static __device__ __forceinline__ unsigned short f2bf(float f) {
  __bf16 b = (__bf16)f;
  return __builtin_bit_cast(unsigned short, b);
}
static __device__ __forceinline__ float bf2f(unsigned short b) {
  union { unsigned u; float f; } v; v.u = ((unsigned)b) << 16;
  return v.f;
}
static __device__ __forceinline__ bf16x8 ldb8(const unsigned short* p) {
  return __builtin_bit_cast(bf16x8, *(const uint4v*)p);
}
static __device__ __forceinline__ f32x4 mfma16(bf16x8 a, bf16x8 b, f32x4 c) {
  return __builtin_amdgcn_mfma_f32_16x16x32_bf16(a, b, c, 0, 0, 0);
}

typedef unsigned int u32_g __attribute__((address_space(1)));
typedef unsigned int u32_l __attribute__((address_space(3)));
static __device__ __forceinline__ void gload16(const unsigned short* g, unsigned short* l) {
  __builtin_amdgcn_global_load_lds((const u32_g*)(const void*)g,
                                   (u32_l*)(void*)l, 16, 0, 0);
}

#define SWZ(r, off) ((off) ^ (((r) & 7) << 4))
#define QSCALE 0.180336880f   // 0.125 * log2(e)

// ---------------- weight prep: LDS-tiled transpose f32 [K][N] -> bf16 [N][K] ----
__global__ __launch_bounds__(64) void prep_t(
    const float* __restrict__ qw, const float* __restrict__ kw,
    const float* __restrict__ vw, const float* __restrict__ ow,
    const float* __restrict__ w0, const float* __restrict__ w1,
    const float* __restrict__ w2,
    unsigned short* __restrict__ Wq, unsigned short* __restrict__ Wo,
    unsigned short* __restrict__ W01, unsigned short* __restrict__ W2)
{
  int bid = blockIdx.x;
  int l = bid >> 10;
  int r = bid & 1023;
  const float* src; unsigned short* dst;
  int tr, tc, srcN, dstK;
  if (r < 192) {
    int sel = r >> 6, tt = r & 63;
    tr = tt >> 3; tc = tt & 7;
    src = (sel == 0 ? qw : sel == 1 ? kw : vw) + (size_t)l * 262144;
    srcN = 512; dstK = 512;
    dst = Wq + (size_t)l * 786432 + (size_t)(sel * 512 + tc * 64) * 512 + tr * 64;
  } else if (r < 256) {
    int tt = r - 192; tr = tt >> 3; tc = tt & 7;
    src = ow + (size_t)l * 262144; srcN = 512; dstK = 512;
    dst = Wo + (size_t)l * 262144 + (size_t)(tc * 64) * 512 + tr * 64;
  } else if (r < 768) {
    int idx = r - 256; int sel = idx >> 8; int tt = idx & 255;
    tr = tt >> 5; tc = tt & 31;
    src = (sel ? w1 : w0) + (size_t)l * 1048576; srcN = 2048; dstK = 512;
    dst = W01 + (size_t)l * 2097152 + (size_t)sel * 1048576 + (size_t)(tc * 64) * 512 + tr * 64;
  } else {
    int tt = r - 768; tr = tt >> 3; tc = tt & 7;
    src = w2 + (size_t)l * 1048576; srcN = 512; dstK = 2048;
    dst = W2 + (size_t)l * 1048576 + (size_t)(tc * 64) * 2048 + tr * 64;
  }
  src += (size_t)(tr * 64) * srcN + tc * 64;
  __shared__ unsigned short T[64][68];
  int t = threadIdx.x;
  #pragma unroll
  for (int it = 0; it < 16; ++it) {
    int row = it * 4 + (t >> 4);
    int col = (t & 15) * 4;
    f32x4 v4 = *(const f32x4*)(src + (size_t)row * srcN + col);
    u16x4 o; o[0] = f2bf(v4.x); o[1] = f2bf(v4.y); o[2] = f2bf(v4.z); o[3] = f2bf(v4.w);
    *(u16x4*)&T[row][col] = o;
  }
  __syncthreads();
  unsigned short* orow = dst + (size_t)t * dstK;
  #pragma unroll
  for (int j0 = 0; j0 < 8; ++j0) {
    u16x8 o;
    #pragma unroll
    for (int j = 0; j < 8; ++j) o[j] = T[j0 * 8 + j][t];
    *(u16x8*)(orow + j0 * 8) = o;
  }
}

// ---------------- initrms: h = x; xn = rms(x)*w ----------------
__global__ __launch_bounds__(256) void initrms_k(const float* __restrict__ x,
                                                 const float* __restrict__ w,
                                                 float* __restrict__ h,
                                                 unsigned short* __restrict__ xn) {
  int row  = blockIdx.x * 4 + (threadIdx.x >> 6);
  int lane = threadIdx.x & 63;
  const float* xr = x + (size_t)row * D_MODEL + lane * 8;
  f32x4 v0 = *(const f32x4*)(xr);
  f32x4 v1 = *(const f32x4*)(xr + 4);
  *(f32x4*)(h + (size_t)row * D_MODEL + lane * 8)     = v0;
  *(f32x4*)(h + (size_t)row * D_MODEL + lane * 8 + 4) = v1;
  float ss = v0.x*v0.x + v0.y*v0.y + v0.z*v0.z + v0.w*v0.w
           + v1.x*v1.x + v1.y*v1.y + v1.z*v1.z + v1.w*v1.w;
  #pragma unroll
  for (int m = 1; m < 64; m <<= 1) ss += __shfl_xor(ss, m, 64);
  float inv = 1.0f / (sqrtf(ss * (1.0f / D_MODEL)) + 1e-6f);
  f32x4 w0 = *(const f32x4*)(w + lane * 8);
  f32x4 w1 = *(const f32x4*)(w + lane * 8 + 4);
  u16x8 o;
  o[0] = f2bf(v0.x * w0.x * inv); o[1] = f2bf(v0.y * w0.y * inv);
  o[2] = f2bf(v0.z * w0.z * inv); o[3] = f2bf(v0.w * w0.w * inv);
  o[4] = f2bf(v1.x * w1.x * inv); o[5] = f2bf(v1.y * w1.y * inv);
  o[6] = f2bf(v1.z * w1.z * inv); o[7] = f2bf(v1.w * w1.w * inv);
  *(u16x8*)(xn + (size_t)row * D_MODEL + lane * 8) = o;
}

// ---------------- addrms: h += y(bf16); xn = rms(h)*w ----------------
__global__ __launch_bounds__(256) void addrms_k(float* __restrict__ h,
                                                const unsigned short* __restrict__ y,
                                                const float* __restrict__ w,
                                                unsigned short* __restrict__ xn) {
  int row  = blockIdx.x * 4 + (threadIdx.x >> 6);
  int lane = threadIdx.x & 63;
  float* hr = h + (size_t)row * D_MODEL + lane * 8;
  f32x4 v0 = *(const f32x4*)(hr);
  f32x4 v1 = *(const f32x4*)(hr + 4);
  u16x8 yy = *(const u16x8*)(y + (size_t)row * D_MODEL + lane * 8);
  v0.x += bf2f(yy[0]); v0.y += bf2f(yy[1]); v0.z += bf2f(yy[2]); v0.w += bf2f(yy[3]);
  v1.x += bf2f(yy[4]); v1.y += bf2f(yy[5]); v1.z += bf2f(yy[6]); v1.w += bf2f(yy[7]);
  *(f32x4*)(hr)     = v0;
  *(f32x4*)(hr + 4) = v1;
  float ss = v0.x*v0.x + v0.y*v0.y + v0.z*v0.z + v0.w*v0.w
           + v1.x*v1.x + v1.y*v1.y + v1.z*v1.z + v1.w*v1.w;
  #pragma unroll
  for (int m = 1; m < 64; m <<= 1) ss += __shfl_xor(ss, m, 64);
  float inv = 1.0f / (sqrtf(ss * (1.0f / D_MODEL)) + 1e-6f);
  f32x4 w0 = *(const f32x4*)(w + lane * 8);
  f32x4 w1 = *(const f32x4*)(w + lane * 8 + 4);
  u16x8 o;
  o[0] = f2bf(v0.x * w0.x * inv); o[1] = f2bf(v0.y * w0.y * inv);
  o[2] = f2bf(v0.z * w0.z * inv); o[3] = f2bf(v0.w * w0.w * inv);
  o[4] = f2bf(v1.x * w1.x * inv); o[5] = f2bf(v1.y * w1.y * inv);
  o[6] = f2bf(v1.z * w1.z * inv); o[7] = f2bf(v1.w * w1.w * inv);
  *(u16x8*)(xn + (size_t)row * D_MODEL + lane * 8) = o;
}

// ---------------- GEMM v6: 2-phase dbuf pipeline + T2 swizzle -------------
// Per K-step: issue next tile's global_load_lds FIRST, then compute current
// from the other LDS buffer; one barrier per K-step (drain lands post-MFMA).
#define EPI_QKV   0
#define EPI_PLAIN 1

template<int EPI, int BM, int BN>
__global__ __launch_bounds__(256) void gemm6_k(
    const unsigned short* __restrict__ A,
    const unsigned short* __restrict__ Bt,    // [N][K]
    const float* __restrict__ bias0,
    const float* __restrict__ bias1,
    const float* __restrict__ bias2,
    void* __restrict__ out0,
    void* __restrict__ out1,
    void* __restrict__ out2,                  // QKV: vt [bh][d][s]
    int M, int N, int K)
{
  constexpr int MF = BM / 32;
  constexpr int NF = BN / 32;
  constexpr int ALOADS = BM / 32;
  constexpr int BLOADS = BN / 32;

  __shared__ __attribute__((aligned(16))) unsigned short Al[2][BM * 64];
  __shared__ __attribute__((aligned(16))) unsigned short Bl[2][BN * 64];

  int nblk = gridDim.x;
  int orig = blockIdx.x;
  int qq = nblk >> 3, rr = nblk & 7, xcd = orig & 7, pos = orig >> 3;
  int lid = (xcd < rr ? xcd * (qq + 1) : rr * (qq + 1) + (xcd - rr) * qq) + pos;
  int numN = N / BN;
  int mt = lid / numN, nt = lid % numN;
  int m0 = mt * BM, n0 = nt * BN;

  int tid = threadIdx.x, lane = tid & 63, w = tid >> 6;
  int wm = w >> 1, wn = w & 1;
  int g = lane >> 4, c = lane & 15;
  int srow = lane >> 3, sslot = lane & 7;
  int sgc = (sslot ^ srow) * 8;            // pre-swizzled global col

  const unsigned short* aG = A  + (size_t)(m0 + w * (BM / 4) + srow) * K + sgc;
  const unsigned short* bG = Bt + (size_t)(n0 + w * (BN / 4) + srow) * K + sgc;
  int aOff = (w * (BM / 4) + srow) * 64 + sslot * 8;
  int bOff = (w * (BN / 4) + srow) * 64 + sslot * 8;

  f32x4 acc[MF][NF] = {};
  int KT = K >> 6;
  int rk = c & 7;

  // prologue: stage kt=0 into buf0
  #pragma unroll
  for (int t = 0; t < ALOADS; ++t)
    gload16(aG + (size_t)(t * 8) * K, &Al[0][aOff + t * 8 * 64]);
  #pragma unroll
  for (int t = 0; t < BLOADS; ++t)
    gload16(bG + (size_t)(t * 8) * K, &Bl[0][bOff + t * 8 * 64]);
  __syncthreads();

  for (int kt = 0; kt < KT; ++kt) {
    int cur = kt & 1;
    if (kt + 1 < KT) {
      int nb = cur ^ 1;
      const unsigned short* aGk = aG + (kt + 1) * 64;
      const unsigned short* bGk = bG + (kt + 1) * 64;
      #pragma unroll
      for (int t = 0; t < ALOADS; ++t)
        gload16(aGk + (size_t)(t * 8) * K, &Al[nb][aOff + t * 8 * 64]);
      #pragma unroll
      for (int t = 0; t < BLOADS; ++t)
        gload16(bGk + (size_t)(t * 8) * K, &Bl[nb][bOff + t * 8 * 64]);
    }
    #pragma unroll
    for (int ks = 0; ks < 2; ++ks) {
      int slot = (ks * 4 + g) ^ rk;
      bf16x8 af[MF], bfr[NF];
      #pragma unroll
      for (int i = 0; i < MF; ++i)
        af[i] = ldb8(&Al[cur][(wm * (MF * 16) + i * 16 + c) * 64 + slot * 8]);
      #pragma unroll
      for (int j = 0; j < NF; ++j)
        bfr[j] = ldb8(&Bl[cur][(wn * (NF * 16) + j * 16 + c) * 64 + slot * 8]);
      #pragma unroll
      for (int i = 0; i < MF; ++i)
        #pragma unroll
        for (int j = 0; j < NF; ++j)
          acc[i][j] = mfma16(af[i], bfr[j], acc[i][j]);
    }
    __syncthreads();   // drains prefetch vmcnt + guards buf reuse
  }

  if (EPI == EPI_QKV) {
    int sel  = n0 >> 9;            // block-uniform
    if (sel < 2) {
      #pragma unroll
      for (int i = 0; i < MF; ++i) {
        int mrow = m0 + wm * (MF * 16) + i * 16 + g * 4;
        #pragma unroll
        for (int j = 0; j < NF; ++j) {
          int nloc = (n0 & 511) + wn * (NF * 16) + j * 16 + c;
          const float* bp = sel == 0 ? bias0 : bias1;
          unsigned short* o = (unsigned short*)(sel == 0 ? out0 : out1);
          float sc = (sel == 0) ? QSCALE : 1.0f;
          float bn = bp[nloc];
          #pragma unroll
          for (int ii = 0; ii < 4; ++ii)
            o[(size_t)(mrow + ii) * D_MODEL + nloc] = f2bf((acc[i][j][ii] + bn) * sc);
        }
      }
    } else {
      // V: transpose 128x64 tile in LDS, write vt[bh][d][s] coalesced
      unsigned short* T = &Al[0][0];            // 64 x 136 (<32KB)
      #pragma unroll
      for (int i = 0; i < MF; ++i) {
        int ml0 = wm * (MF * 16) + i * 16 + g * 4;
        #pragma unroll
        for (int j = 0; j < NF; ++j) {
          int nl = wn * (NF * 16) + j * 16 + c;
          float bn = bias2[(n0 & 511) + nl];
          u16x4 pk;
          #pragma unroll
          for (int ii = 0; ii < 4; ++ii) pk[ii] = f2bf(acc[i][j][ii] + bn);
          *(u16x4*)&T[nl * 136 + ml0] = pk;
        }
      }
      __syncthreads();
      int b  = m0 >> 11, s0 = m0 & 2047;
      int hh = (n0 & 511) >> 6;
      int r  = tid >> 2, c0 = (tid & 3) * 32;
      unsigned short* dst = (unsigned short*)out2 +
          ((size_t)(b * NHEAD + hh) * HD + r) * SEQ + s0 + c0;
      #pragma unroll
      for (int u = 0; u < 4; ++u)
        *(u16x8*)(dst + u * 8) = *(u16x8*)&T[r * 136 + c0 + u * 8];
    }
  } else {  // EPI_PLAIN
    #pragma unroll
    for (int i = 0; i < MF; ++i) {
      int mrow = m0 + wm * (MF * 16) + i * 16 + g * 4;
      #pragma unroll
      for (int j = 0; j < NF; ++j) {
        int n = n0 + wn * (NF * 16) + j * 16 + c;
        float bn = bias0[n];
        unsigned short* o = (unsigned short*)out0;
        #pragma unroll
        for (int ii = 0; ii < 4; ++ii)
          o[(size_t)(mrow + ii) * N + n] = f2bf(acc[i][j][ii] + bn);
      }
    }
  }
}

// ---------------- GEMM v6d: fused dual-B gated FFN-up, 2-phase dbuf -------
template<int BM, int BN>
__global__ __launch_bounds__(256) void gemm6d_k(
    const unsigned short* __restrict__ A,
    const unsigned short* __restrict__ B0t,   // [N][K]
    const unsigned short* __restrict__ B1t,   // [N][K]
    const float* __restrict__ bias0,
    const float* __restrict__ bias1,
    unsigned short* __restrict__ out,
    int M, int N, int K)
{
  constexpr int MF = BM / 32;
  constexpr int NF = BN / 32;
  constexpr int ALOADS = BM / 32;
  constexpr int BLOADS = BN / 32;

  __shared__ __attribute__((aligned(16))) unsigned short Al[2][BM * 64];
  __shared__ __attribute__((aligned(16))) unsigned short B0l[2][BN * 64];
  __shared__ __attribute__((aligned(16))) unsigned short B1l[2][BN * 64];

  int nblk = gridDim.x;
  int orig = blockIdx.x;
  int qq = nblk >> 3, rr = nblk & 7, xcd = orig & 7, pos = orig >> 3;
  int lid = (xcd < rr ? xcd * (qq + 1) : rr * (qq + 1) + (xcd - rr) * qq) + pos;
  int numM = M / BM;
  int nt = lid / numM, mt = lid % numM;   // n-major: XCD chunk shares B panel
  int m0 = mt * BM, n0 = nt * BN;

  int tid = threadIdx.x, lane = tid & 63, w = tid >> 6;
  int wm = w >> 1, wn = w & 1;
  int g = lane >> 4, c = lane & 15;
  int srow = lane >> 3, sslot = lane & 7;
  int sgc = (sslot ^ srow) * 8;

  const unsigned short* aG  = A   + (size_t)(m0 + w * (BM / 4) + srow) * K + sgc;
  const unsigned short* b0G = B0t + (size_t)(n0 + w * (BN / 4) + srow) * K + sgc;
  const unsigned short* b1G = B1t + (size_t)(n0 + w * (BN / 4) + srow) * K + sgc;
  int aOff = (w * (BM / 4) + srow) * 64 + sslot * 8;
  int bOff = (w * (BN / 4) + srow) * 64 + sslot * 8;

  f32x4 acc0[MF][NF] = {};
  f32x4 acc1[MF][NF] = {};
  int KT = K >> 6;
  int rk = c & 7;

  #pragma unroll
  for (int t = 0; t < ALOADS; ++t)
    gload16(aG + (size_t)(t * 8) * K, &Al[0][aOff + t * 8 * 64]);
  #pragma unroll
  for (int t = 0; t < BLOADS; ++t) {
    gload16(b0G + (size_t)(t * 8) * K, &B0l[0][bOff + t * 8 * 64]);
    gload16(b1G + (size_t)(t * 8) * K, &B1l[0][bOff + t * 8 * 64]);
  }
  __syncthreads();

  for (int kt = 0; kt < KT; ++kt) {
    int cur = kt & 1;
    if (kt + 1 < KT) {
      int nb = cur ^ 1;
      const unsigned short* aGk  = aG  + (kt + 1) * 64;
      const unsigned short* b0Gk = b0G + (kt + 1) * 64;
      const unsigned short* b1Gk = b1G + (kt + 1) * 64;
      #pragma unroll
      for (int t = 0; t < ALOADS; ++t)
        gload16(aGk + (size_t)(t * 8) * K, &Al[nb][aOff + t * 8 * 64]);
      #pragma unroll
      for (int t = 0; t < BLOADS; ++t) {
        gload16(b0Gk + (size_t)(t * 8) * K, &B0l[nb][bOff + t * 8 * 64]);
        gload16(b1Gk + (size_t)(t * 8) * K, &B1l[nb][bOff + t * 8 * 64]);
      }
    }
    #pragma unroll
    for (int ks = 0; ks < 2; ++ks) {
      int slot = (ks * 4 + g) ^ rk;
      bf16x8 af[MF], b0f[NF], b1f[NF];
      #pragma unroll
      for (int i = 0; i < MF; ++i)
        af[i] = ldb8(&Al[cur][(wm * (MF * 16) + i * 16 + c) * 64 + slot * 8]);
      #pragma unroll
      for (int j = 0; j < NF; ++j) {
        b0f[j] = ldb8(&B0l[cur][(wn * (NF * 16) + j * 16 + c) * 64 + slot * 8]);
        b1f[j] = ldb8(&B1l[cur][(wn * (NF * 16) + j * 16 + c) * 64 + slot * 8]);
      }
      #pragma unroll
      for (int i = 0; i < MF; ++i)
        #pragma unroll
        for (int j = 0; j < NF; ++j) {
          acc0[i][j] = mfma16(af[i], b0f[j], acc0[i][j]);
          acc1[i][j] = mfma16(af[i], b1f[j], acc1[i][j]);
        }
    }
    __syncthreads();
  }

  #pragma unroll
  for (int i = 0; i < MF; ++i) {
    int mrow = m0 + wm * (MF * 16) + i * 16 + g * 4;
    #pragma unroll
    for (int j = 0; j < NF; ++j) {
      int n = n0 + wn * (NF * 16) + j * 16 + c;
      float b0n = bias0[n], b1n = bias1[n];
      #pragma unroll
      for (int ii = 0; ii < 4; ++ii) {
        float a  = acc0[i][j][ii] + b0n;
        float gv = acc1[i][j][ii] + b1n;
        float s  = gv / (1.0f + __expf(-gv));
        out[(size_t)(mrow + ii) * N + n] = f2bf(a * s);
      }
    }
  }
}

// ---------------- attention v5: split-K flash, no-max softmax ------------
struct Stg { uint4v k0, k1, v0, v1; };

static __device__ __forceinline__ Stg stage_load(const unsigned short* Kp,
                                                 const unsigned short* Vp,
                                                 int kbase, int srow, int sslot) {
  Stg s;
  const unsigned short* kr = Kp + (size_t)(kbase + srow) * D_MODEL + sslot * 8;
  s.k0 = *(const uint4v*)kr;
  s.k1 = *(const uint4v*)(kr + 32);
  const unsigned short* vr = Vp + (size_t)srow * SEQ + kbase + sslot * 8;
  s.v0 = *(const uint4v*)vr;
  s.v1 = *(const uint4v*)(vr + 32);
  return s;
}
static __device__ __forceinline__ void stage_write(unsigned short* Klb, unsigned short* Vlb,
                                                   const Stg& s, int srow, int sslot) {
  char* kb = (char*)Klb;
  *(uint4v*)(kb + SWZ(srow, srow * 128 + sslot * 16))       = s.k0;
  *(uint4v*)(kb + SWZ(srow, srow * 128 + (sslot + 4) * 16)) = s.k1;
  char* vb = (char*)Vlb;
  *(uint4v*)(vb + SWZ(srow, srow * 128 + sslot * 16))       = s.v0;
  *(uint4v*)(vb + SWZ(srow, srow * 128 + (sslot + 4) * 16)) = s.v1;
}

template<bool MASKED>
static __device__ __forceinline__ void attn_tile(
    const unsigned short* Klb, const unsigned short* Vlb,
    bf16x8 qf0, bf16x8 qf1, f32x4* oacc, float& ps,
    int g, int c, int kbase, int qrow)
{
  f32x4 z[4];
  #pragma unroll
  for (int hh = 0; hh < 4; ++hh) {
    int r = hh * 16 + c;
    const char* base = (const char*)Klb;
    bf16x8 k0 = ldb8((const unsigned short*)(base + SWZ(r, r * 128 + g * 16)));
    bf16x8 k1 = ldb8((const unsigned short*)(base + SWZ(r, r * 128 + 64 + g * 16)));
    f32x4 t = {};
    t = mfma16(k0, qf0, t);
    t = mfma16(k1, qf1, t);
    z[hh] = t;
  }
  u16x8 pa0, pa1;
  #pragma unroll
  for (int hh = 0; hh < 4; ++hh) {
    #pragma unroll
    for (int i = 0; i < 4; ++i) {
      float p = exp2f(z[hh][i]);
      if (MASKED && (kbase + hh * 16 + g * 4 + i > qrow)) p = 0.0f;
      ps += p;
      unsigned short pb = f2bf(p);
      if (hh < 2) pa0[hh * 4 + i] = pb;
      else        pa1[(hh - 2) * 4 + i] = pb;
    }
  }
  bf16x8 af0 = __builtin_bit_cast(bf16x8, pa0);
  bf16x8 af1 = __builtin_bit_cast(bf16x8, pa1);
  #pragma unroll
  for (int db = 0; db < 4; ++db) {
    int r = db * 16 + c;
    const char* base = (const char*)Vlb;
    u16x4 v00 = *(const u16x4*)(base + SWZ(r, r * 128 + g * 8));
    u16x4 v01 = *(const u16x4*)(base + SWZ(r, r * 128 + 32 + g * 8));
    u16x4 v10 = *(const u16x4*)(base + SWZ(r, r * 128 + 64 + g * 8));
    u16x4 v11 = *(const u16x4*)(base + SWZ(r, r * 128 + 96 + g * 8));
    u16x8 vb0, vb1;
    #pragma unroll
    for (int j = 0; j < 4; ++j) {
      vb0[j] = v00[j]; vb0[4 + j] = v01[j];
      vb1[j] = v10[j]; vb1[4 + j] = v11[j];
    }
    oacc[db] = mfma16(af0, __builtin_bit_cast(bf16x8, vb0), oacc[db]);
    oacc[db] = mfma16(af1, __builtin_bit_cast(bf16x8, vb1), oacc[db]);
  }
}

static __device__ __forceinline__ int slot_base(int c) {
  if (c < 16) return (c - 8) * 2;
  if (c < 24) return 16 + (c - 16) * 3;
  return 40 + (c - 24) * 4;
}

__global__ __launch_bounds__(256) void attn5_k(const unsigned short* __restrict__ Q,
                                               const unsigned short* __restrict__ K,
                                               const unsigned short* __restrict__ VT,
                                               unsigned short* __restrict__ O,
                                               float* __restrict__ Oparts,
                                               float* __restrict__ Sparts)
{
  __shared__ __attribute__((aligned(16))) unsigned short Kl[2][64 * 64];
  __shared__ __attribute__((aligned(16))) unsigned short Vl[2][64 * 64];
  int tid = threadIdx.x, lane = tid & 63, w = tid >> 6;
  int g = lane >> 4, cl = lane & 15;

  int z = 79 - (int)blockIdx.x;
  int c, sp;
  if (z < 8)        { c = z;                    sp = 0; }
  else if (z < 24)  { int t2 = z - 8;  c = 8  + (t2 >> 1); sp = t2 & 1; }
  else if (z < 48)  { int t2 = z - 24; c = 16 + t2 / 3;    sp = t2 % 3; }
  else              { int t2 = z - 48; c = 24 + (t2 >> 2); sp = t2 & 3; }
  int kt0 = sp * 8;
  int kt1 = min(c + 1, kt0 + 8);
  bool lastsplit = (kt1 == c + 1);

  int bh = blockIdx.y, b = bh >> 3, h = bh & 7;
  int q0 = c * 64;
  const unsigned short* Qp = Q + (size_t)(b * SEQ) * D_MODEL + h * HD;
  const unsigned short* Kp = K + (size_t)(b * SEQ) * D_MODEL + h * HD;
  const unsigned short* Vp = VT + (size_t)bh * HD * SEQ;

  int qrow = q0 + w * 16 + cl;
  bf16x8 qf0 = ldb8(Qp + (size_t)qrow * D_MODEL + g * 8);
  bf16x8 qf1 = ldb8(Qp + (size_t)qrow * D_MODEL + 32 + g * 8);

  f32x4 oacc[4] = {};
  float ps = 0.0f;
  int srow = tid >> 2, sslot = tid & 3;

  Stg s0 = stage_load(Kp, Vp, kt0 * 64, srow, sslot);
  stage_write(&Kl[0][0], &Vl[0][0], s0, srow, sslot);
  __syncthreads();

  int buf = 0;
  for (int kt = kt0; kt < kt1 - 1; ++kt) {
    Stg sn = stage_load(Kp, Vp, (kt + 1) * 64, srow, sslot);
    attn_tile<false>(&Kl[buf][0], &Vl[buf][0], qf0, qf1, oacc, ps, g, cl, 0, 0);
    stage_write(&Kl[buf ^ 1][0], &Vl[buf ^ 1][0], sn, srow, sslot);
    __syncthreads();
    buf ^= 1;
  }
  if (lastsplit)
    attn_tile<true>(&Kl[buf][0], &Vl[buf][0], qf0, qf1, oacc, ps, g, cl,
                    (kt1 - 1) * 64, qrow);
  else
    attn_tile<false>(&Kl[buf][0], &Vl[buf][0], qf0, qf1, oacc, ps, g, cl, 0, 0);

  ps += __shfl_xor(ps, 16, 64);
  ps += __shfl_xor(ps, 32, 64);

  if (c < 8) {
    f32x4 inv;
    #pragma unroll
    for (int i = 0; i < 4; ++i) inv[i] = 1.0f / __shfl(ps, g * 4 + i, 64);
    #pragma unroll
    for (int db = 0; db < 4; ++db)
      #pragma unroll
      for (int i = 0; i < 4; ++i)
        O[(size_t)(b * SEQ + q0 + w * 16 + g * 4 + i) * D_MODEL + h * HD + db * 16 + cl] =
            f2bf(oacc[db][i] * inv[i]);
  } else {
    size_t slot = (size_t)bh * 72 + slot_base(c) + sp;
    float* Op = Oparts + slot * 4096;
    float* Sp = Sparts + slot * 64;
    #pragma unroll
    for (int db = 0; db < 4; ++db)
      #pragma unroll
      for (int i = 0; i < 4; ++i)
        Op[(w * 16 + g * 4 + i) * 64 + db * 16 + cl] = oacc[db][i];
    if (g == 0) Sp[w * 16 + cl] = ps;
  }
}

__global__ __launch_bounds__(256) void attn_comb_k(const float* __restrict__ Oparts,
                                                   const float* __restrict__ Sparts,
                                                   unsigned short* __restrict__ O) {
  int t  = threadIdx.x;
  int c  = 8 + (int)(blockIdx.x % 24);
  int bh = (int)(blockIdx.x / 24);
  int b = bh >> 3, h = bh & 7;
  int ns = (c + 8) >> 3;
  size_t slot = (size_t)bh * 72 + slot_base(c);
  const float* O0 = Oparts + slot * 4096;
  const float* S0 = Sparts + slot * 64;
  int r = t >> 2, d0 = (t & 3) * 16;
  f32x4 a0 = {}, a1 = {}, a2 = {}, a3 = {};
  float s = 0.0f;
  for (int si = 0; si < ns; ++si) {
    const float* o = O0 + si * 4096 + r * 64 + d0;
    a0 += *(const f32x4*)(o);
    a1 += *(const f32x4*)(o + 4);
    a2 += *(const f32x4*)(o + 8);
    a3 += *(const f32x4*)(o + 12);
    s  += S0[si * 64 + r];
  }
  float inv = 1.0f / s;
  u16x8 w0, w1;
  #pragma unroll
  for (int j = 0; j < 4; ++j) {
    w0[j]     = f2bf(a0[j] * inv); w0[4 + j] = f2bf(a1[j] * inv);
    w1[j]     = f2bf(a2[j] * inv); w1[4 + j] = f2bf(a3[j] * inv);
  }
  unsigned short* dst = O + (size_t)(b * SEQ + c * 64 + r) * D_MODEL + h * HD + d0;
  *(u16x8*)(dst)     = w0;
  *(u16x8*)(dst + 8) = w1;
}

// ---------------- launch ----------------
extern "C" void kernel_launch(void* const* d_in, const int* in_sizes, int n_in,
                              void* d_out, int out_size, void* d_ws, size_t ws_size,
                              hipStream_t stream) {
  (void)in_sizes; (void)n_in; (void)out_size; (void)ws_size;
  const float* x   = (const float*)d_in[0];
  const float* qw  = (const float*)d_in[1];
  const float* qb  = (const float*)d_in[2];
  const float* kw  = (const float*)d_in[3];
  const float* kbi = (const float*)d_in[4];
  const float* vw  = (const float*)d_in[5];
  const float* vb  = (const float*)d_in[6];
  const float* ow  = (const float*)d_in[7];
  const float* ob  = (const float*)d_in[8];
  const float* w0  = (const float*)d_in[9];
  const float* b0  = (const float*)d_in[10];
  const float* w1  = (const float*)d_in[11];
  const float* b1  = (const float*)d_in[12];
  const float* w2  = (const float*)d_in[13];
  const float* b2  = (const float*)d_in[14];
  const float* anw = (const float*)d_in[15];
  const float* fnw = (const float*)d_in[16];

  char* ws = (char*)d_ws;
  float*          h    = (float*)ws;                              // 0-8MB fp32 residual
  unsigned short* xn   = (unsigned short*)(ws + (8u  << 20));     // 8-12
  unsigned short* q    = (unsigned short*)(ws + (12u << 20));     // 12-16
  unsigned short* k    = (unsigned short*)(ws + (16u << 20));     // 16-20
  unsigned short* vt   = (unsigned short*)(ws + (24u << 20));     // 24-28
  unsigned short* ao   = (unsigned short*)(ws + (28u << 20));     // 28-32
  unsigned short* y    = (unsigned short*)(ws + (32u << 20));     // 32-36
  unsigned short* hbuf = (unsigned short*)(ws + (12u << 20));     // 12-28 (aliases q,k,vt)
  unsigned short* Wq   = (unsigned short*)(ws + (36u << 20));     // 36-42
  unsigned short* Wo   = (unsigned short*)(ws + (42u << 20));     // 42-44
  unsigned short* W01  = (unsigned short*)(ws + (44u << 20));     // 44-60
  unsigned short* W2   = (unsigned short*)(ws + (60u << 20));     // 60-68
  float*          Opar = (float*)(ws + (68u << 20));              // 68-86 (18MB)
  float*          Spar = (float*)(ws + (86u << 20));              // 86-86.3

  prep_t<<<4096, 64, 0, stream>>>(qw, kw, vw, ow, w0, w1, w2, Wq, Wo, W01, W2);
  initrms_k<<<BTOK / 4, 256, 0, stream>>>(x, anw, h, xn);

  for (int l = 0; l < 4; ++l) {
    size_t bo  = (size_t)l * D_MODEL;
    size_t bho = (size_t)l * HIDE;

    gemm6_k<EPI_QKV, 128, 64><<<768, 256, 0, stream>>>(
        xn, Wq + (size_t)l * 786432, qb + bo, kbi + bo, vb + bo,
        q, k, vt, BTOK, 3 * D_MODEL, D_MODEL);
    attn5_k<<<dim3(80, 16), 256, 0, stream>>>(q, k, vt, ao, Opar, Spar);
    attn_comb_k<<<384, 256, 0, stream>>>(Opar, Spar, ao);
    gemm6_k<EPI_PLAIN, 64, 64><<<512, 256, 0, stream>>>(
        ao, Wo + (size_t)l * 262144, ob + bo, nullptr, nullptr,
        y, nullptr, nullptr, BTOK, D_MODEL, D_MODEL);
    addrms_k<<<BTOK / 4, 256, 0, stream>>>(h, y, fnw + bo, xn);

    gemm6d_k<128, 64><<<1024, 256, 0, stream>>>(
        xn, W01 + (size_t)l * 2097152, W01 + (size_t)l * 2097152 + 1048576,
        b0 + bho, b1 + bho, hbuf, BTOK, HIDE, D_MODEL);
    gemm6_k<EPI_PLAIN, 64, 64><<<512, 256, 0, stream>>>(
        hbuf, W2 + (size_t)l * 1048576, b2 + bo, nullptr, nullptr,
        y, nullptr, nullptr, BTOK, D_MODEL, HIDE);
    addrms_k<<<BTOK / 4, 256, 0, stream>>>(
        h, y, (l < 3 ? anw + bo + D_MODEL : anw), xn);
  }
  hipMemcpyAsync(d_out, h, (size_t)BTOK * D_MODEL * sizeof(float),
                 hipMemcpyDeviceToDevice, stream);
}

// Round 12
// 467.409 us; speedup vs baseline: 3.4913x; 1.0086x over previous
//
#include <hip/hip_runtime.h>
#include <math.h>

// ---------------- types ----------------
typedef unsigned int   uint4v __attribute__((ext_vector_type(4)));
typedef float          f32x4  __attribute__((ext_vector_type(4)));
typedef __bf16         bf16x8 __attribute__((ext_vector_type(8)));
typedef unsigned short u16x8  __attribute__((ext_vector_type(8)));
typedef unsigned short u16x4  __attribute__((ext_vector_type(4)));

#define D_MODEL 512
#define SEQ     2048
#define BTOK    4096   // B * SEQ
#define HIDE    2048
#define NHEAD   8
#define HD      64

static __device__ __forceinline__ unsigned short f2bf(float f) {
  __bf16 b = (__bf16)f;
  return __builtin_bit_cast(unsigned short, b);
}
static __device__ __forceinline__ float bf2f(unsigned short b) {
  union { unsigned u; float f; } v; v.u = ((unsigned)b) << 16;
  return v.f;
}
static __device__ __forceinline__ bf16x8 ldb8(const unsigned short* p) {
  return __builtin_bit_cast(bf16x8, *(const uint4v*)p);
}
static __device__ __forceinline__ f32x4 mfma16(bf16x8 a, bf16x8 b, f32x4 c) {
  return __builtin_amdgcn_mfma_f32_16x16x32_bf16(a, b, c, 0, 0, 0);
}

typedef unsigned int u32_g __attribute__((address_space(1)));
typedef unsigned int u32_l __attribute__((address_space(3)));
static __device__ __forceinline__ void gload16(const unsigned short* g, unsigned short* l) {
  __builtin_amdgcn_global_load_lds((const u32_g*)(const void*)g,
                                   (u32_l*)(void*)l, 16, 0, 0);
}

#define SWZ(r, off) ((off) ^ (((r) & 7) << 4))
#define QSCALE 0.180336880f   // 0.125 * log2(e)

// counted-vmcnt wait: keep newest loads in flight, wait for older ones
template<int N>
static __device__ __forceinline__ void waitcnt_vm() {
  asm volatile("s_waitcnt vmcnt(%0)" :: "i"(N) : "memory");
}

// ---------------- weight prep: LDS-tiled transpose f32 [K][N] -> bf16 [N][K] ----
__global__ __launch_bounds__(64) void prep_t(
    const float* __restrict__ qw, const float* __restrict__ kw,
    const float* __restrict__ vw, const float* __restrict__ ow,
    const float* __restrict__ w0, const float* __restrict__ w1,
    const float* __restrict__ w2,
    unsigned short* __restrict__ Wq, unsigned short* __restrict__ Wo,
    unsigned short* __restrict__ W01, unsigned short* __restrict__ W2)
{
  int bid = blockIdx.x;
  int l = bid >> 10;
  int r = bid & 1023;
  const float* src; unsigned short* dst;
  int tr, tc, srcN, dstK;
  if (r < 192) {
    int sel = r >> 6, tt = r & 63;
    tr = tt >> 3; tc = tt & 7;
    src = (sel == 0 ? qw : sel == 1 ? kw : vw) + (size_t)l * 262144;
    srcN = 512; dstK = 512;
    dst = Wq + (size_t)l * 786432 + (size_t)(sel * 512 + tc * 64) * 512 + tr * 64;
  } else if (r < 256) {
    int tt = r - 192; tr = tt >> 3; tc = tt & 7;
    src = ow + (size_t)l * 262144; srcN = 512; dstK = 512;
    dst = Wo + (size_t)l * 262144 + (size_t)(tc * 64) * 512 + tr * 64;
  } else if (r < 768) {
    int idx = r - 256; int sel = idx >> 8; int tt = idx & 255;
    tr = tt >> 5; tc = tt & 31;
    src = (sel ? w1 : w0) + (size_t)l * 1048576; srcN = 2048; dstK = 512;
    dst = W01 + (size_t)l * 2097152 + (size_t)sel * 1048576 + (size_t)(tc * 64) * 512 + tr * 64;
  } else {
    int tt = r - 768; tr = tt >> 3; tc = tt & 7;
    src = w2 + (size_t)l * 1048576; srcN = 512; dstK = 2048;
    dst = W2 + (size_t)l * 1048576 + (size_t)(tc * 64) * 2048 + tr * 64;
  }
  src += (size_t)(tr * 64) * srcN + tc * 64;
  __shared__ unsigned short T[64][68];
  int t = threadIdx.x;
  #pragma unroll
  for (int it = 0; it < 16; ++it) {
    int row = it * 4 + (t >> 4);
    int col = (t & 15) * 4;
    f32x4 v4 = *(const f32x4*)(src + (size_t)row * srcN + col);
    u16x4 o; o[0] = f2bf(v4.x); o[1] = f2bf(v4.y); o[2] = f2bf(v4.z); o[3] = f2bf(v4.w);
    *(u16x4*)&T[row][col] = o;
  }
  __syncthreads();
  unsigned short* orow = dst + (size_t)t * dstK;
  #pragma unroll
  for (int j0 = 0; j0 < 8; ++j0) {
    u16x8 o;
    #pragma unroll
    for (int j = 0; j < 8; ++j) o[j] = T[j0 * 8 + j][t];
    *(u16x8*)(orow + j0 * 8) = o;
  }
}

// ---------------- initrms: h = x; xn = rms(x)*w ----------------
__global__ __launch_bounds__(256) void initrms_k(const float* __restrict__ x,
                                                 const float* __restrict__ w,
                                                 float* __restrict__ h,
                                                 unsigned short* __restrict__ xn) {
  int row  = blockIdx.x * 4 + (threadIdx.x >> 6);
  int lane = threadIdx.x & 63;
  const float* xr = x + (size_t)row * D_MODEL + lane * 8;
  f32x4 v0 = *(const f32x4*)(xr);
  f32x4 v1 = *(const f32x4*)(xr + 4);
  *(f32x4*)(h + (size_t)row * D_MODEL + lane * 8)     = v0;
  *(f32x4*)(h + (size_t)row * D_MODEL + lane * 8 + 4) = v1;
  float ss = v0.x*v0.x + v0.y*v0.y + v0.z*v0.z + v0.w*v0.w
           + v1.x*v1.x + v1.y*v1.y + v1.z*v1.z + v1.w*v1.w;
  #pragma unroll
  for (int m = 1; m < 64; m <<= 1) ss += __shfl_xor(ss, m, 64);
  float inv = 1.0f / (sqrtf(ss * (1.0f / D_MODEL)) + 1e-6f);
  f32x4 w0 = *(const f32x4*)(w + lane * 8);
  f32x4 w1 = *(const f32x4*)(w + lane * 8 + 4);
  u16x8 o;
  o[0] = f2bf(v0.x * w0.x * inv); o[1] = f2bf(v0.y * w0.y * inv);
  o[2] = f2bf(v0.z * w0.z * inv); o[3] = f2bf(v0.w * w0.w * inv);
  o[4] = f2bf(v1.x * w1.x * inv); o[5] = f2bf(v1.y * w1.y * inv);
  o[6] = f2bf(v1.z * w1.z * inv); o[7] = f2bf(v1.w * w1.w * inv);
  *(u16x8*)(xn + (size_t)row * D_MODEL + lane * 8) = o;
}

// ---------------- addrms: h += y(bf16); xn = rms(h)*w ----------------
__global__ __launch_bounds__(256) void addrms_k(float* __restrict__ h,
                                                const unsigned short* __restrict__ y,
                                                const float* __restrict__ w,
                                                unsigned short* __restrict__ xn) {
  int row  = blockIdx.x * 4 + (threadIdx.x >> 6);
  int lane = threadIdx.x & 63;
  float* hr = h + (size_t)row * D_MODEL + lane * 8;
  f32x4 v0 = *(const f32x4*)(hr);
  f32x4 v1 = *(const f32x4*)(hr + 4);
  u16x8 yy = *(const u16x8*)(y + (size_t)row * D_MODEL + lane * 8);
  v0.x += bf2f(yy[0]); v0.y += bf2f(yy[1]); v0.z += bf2f(yy[2]); v0.w += bf2f(yy[3]);
  v1.x += bf2f(yy[4]); v1.y += bf2f(yy[5]); v1.z += bf2f(yy[6]); v1.w += bf2f(yy[7]);
  *(f32x4*)(hr)     = v0;
  *(f32x4*)(hr + 4) = v1;
  float ss = v0.x*v0.x + v0.y*v0.y + v0.z*v0.z + v0.w*v0.w
           + v1.x*v1.x + v1.y*v1.y + v1.z*v1.z + v1.w*v1.w;
  #pragma unroll
  for (int m = 1; m < 64; m <<= 1) ss += __shfl_xor(ss, m, 64);
  float inv = 1.0f / (sqrtf(ss * (1.0f / D_MODEL)) + 1e-6f);
  f32x4 w0 = *(const f32x4*)(w + lane * 8);
  f32x4 w1 = *(const f32x4*)(w + lane * 8 + 4);
  u16x8 o;
  o[0] = f2bf(v0.x * w0.x * inv); o[1] = f2bf(v0.y * w0.y * inv);
  o[2] = f2bf(v0.z * w0.z * inv); o[3] = f2bf(v0.w * w0.w * inv);
  o[4] = f2bf(v1.x * w1.x * inv); o[5] = f2bf(v1.y * w1.y * inv);
  o[6] = f2bf(v1.z * w1.z * inv); o[7] = f2bf(v1.w * w1.w * inv);
  *(u16x8*)(xn + (size_t)row * D_MODEL + lane * 8) = o;
}

// ---------------- GEMM v7: counted-vmcnt pipeline (T4) + T2 swizzle -------
// Loads for tile kt+1 stay IN FLIGHT across both barriers of step kt:
//   issue(kt+1) -> vmcnt(NL) waits only kt's loads -> raw barrier -> compute
//   -> raw barrier (no vmcnt drain).
#define EPI_QKV   0
#define EPI_PLAIN 1

template<int EPI, int BM, int BN>
__global__ __launch_bounds__(256) void gemm7_k(
    const unsigned short* __restrict__ A,
    const unsigned short* __restrict__ Bt,    // [N][K]
    const float* __restrict__ bias0,
    const float* __restrict__ bias1,
    const float* __restrict__ bias2,
    void* __restrict__ out0,
    void* __restrict__ out1,
    void* __restrict__ out2,                  // QKV: vt [bh][d][s]
    int M, int N, int K)
{
  constexpr int MF = BM / 32;
  constexpr int NF = BN / 32;
  constexpr int ALOADS = BM / 32;
  constexpr int BLOADS = BN / 32;
  constexpr int NL = ALOADS + BLOADS;        // loads/thread/tile

  __shared__ __attribute__((aligned(16))) unsigned short Al[2][BM * 64];
  __shared__ __attribute__((aligned(16))) unsigned short Bl[2][BN * 64];

  int nblk = gridDim.x;
  int orig = blockIdx.x;
  int qq = nblk >> 3, rr = nblk & 7, xcd = orig & 7, pos = orig >> 3;
  int lid = (xcd < rr ? xcd * (qq + 1) : rr * (qq + 1) + (xcd - rr) * qq) + pos;
  int numN = N / BN;
  int mt = lid / numN, nt = lid % numN;
  int m0 = mt * BM, n0 = nt * BN;

  int tid = threadIdx.x, lane = tid & 63, w = tid >> 6;
  int wm = w >> 1, wn = w & 1;
  int g = lane >> 4, c = lane & 15;
  int srow = lane >> 3, sslot = lane & 7;
  int sgc = (sslot ^ srow) * 8;            // pre-swizzled global col

  const unsigned short* aG = A  + (size_t)(m0 + w * (BM / 4) + srow) * K + sgc;
  const unsigned short* bG = Bt + (size_t)(n0 + w * (BN / 4) + srow) * K + sgc;
  int aOff = (w * (BM / 4) + srow) * 64 + sslot * 8;
  int bOff = (w * (BN / 4) + srow) * 64 + sslot * 8;

  f32x4 acc[MF][NF] = {};
  int KT = K >> 6;
  int rk = c & 7;

  // prologue: stage kt=0 into buf0
  #pragma unroll
  for (int t = 0; t < ALOADS; ++t)
    gload16(aG + (size_t)(t * 8) * K, &Al[0][aOff + t * 8 * 64]);
  #pragma unroll
  for (int t = 0; t < BLOADS; ++t)
    gload16(bG + (size_t)(t * 8) * K, &Bl[0][bOff + t * 8 * 64]);

  for (int kt = 0; kt < KT; ++kt) {
    int cur = kt & 1;
    if (kt + 1 < KT) {
      int nb = cur ^ 1;
      const unsigned short* aGk = aG + (kt + 1) * 64;
      const unsigned short* bGk = bG + (kt + 1) * 64;
      #pragma unroll
      for (int t = 0; t < ALOADS; ++t)
        gload16(aGk + (size_t)(t * 8) * K, &Al[nb][aOff + t * 8 * 64]);
      #pragma unroll
      for (int t = 0; t < BLOADS; ++t)
        gload16(bGk + (size_t)(t * 8) * K, &Bl[nb][bOff + t * 8 * 64]);
      waitcnt_vm<NL>();                    // kt's loads done; kt+1's in flight
    } else {
      waitcnt_vm<0>();
    }
    __builtin_amdgcn_s_barrier();          // all waves' kt loads landed
    __builtin_amdgcn_sched_barrier(0);     // pin ds_reads below barrier
    #pragma unroll
    for (int ks = 0; ks < 2; ++ks) {
      int slot = (ks * 4 + g) ^ rk;
      bf16x8 af[MF], bfr[NF];
      #pragma unroll
      for (int i = 0; i < MF; ++i)
        af[i] = ldb8(&Al[cur][(wm * (MF * 16) + i * 16 + c) * 64 + slot * 8]);
      #pragma unroll
      for (int j = 0; j < NF; ++j)
        bfr[j] = ldb8(&Bl[cur][(wn * (NF * 16) + j * 16 + c) * 64 + slot * 8]);
      #pragma unroll
      for (int i = 0; i < MF; ++i)
        #pragma unroll
        for (int j = 0; j < NF; ++j)
          acc[i][j] = mfma16(af[i], bfr[j], acc[i][j]);
    }
    __builtin_amdgcn_sched_barrier(0);
    __builtin_amdgcn_s_barrier();          // release cur for overwrite (no drain)
  }

  if (EPI == EPI_QKV) {
    int sel  = n0 >> 9;            // block-uniform
    if (sel < 2) {
      #pragma unroll
      for (int i = 0; i < MF; ++i) {
        int mrow = m0 + wm * (MF * 16) + i * 16 + g * 4;
        #pragma unroll
        for (int j = 0; j < NF; ++j) {
          int nloc = (n0 & 511) + wn * (NF * 16) + j * 16 + c;
          const float* bp = sel == 0 ? bias0 : bias1;
          unsigned short* o = (unsigned short*)(sel == 0 ? out0 : out1);
          float sc = (sel == 0) ? QSCALE : 1.0f;
          float bn = bp[nloc];
          #pragma unroll
          for (int ii = 0; ii < 4; ++ii)
            o[(size_t)(mrow + ii) * D_MODEL + nloc] = f2bf((acc[i][j][ii] + bn) * sc);
        }
      }
    } else {
      // V: transpose 128x64 tile in LDS, write vt[bh][d][s] coalesced
      unsigned short* T = &Al[0][0];            // 64 x 136
      #pragma unroll
      for (int i = 0; i < MF; ++i) {
        int ml0 = wm * (MF * 16) + i * 16 + g * 4;
        #pragma unroll
        for (int j = 0; j < NF; ++j) {
          int nl = wn * (NF * 16) + j * 16 + c;
          float bn = bias2[(n0 & 511) + nl];
          u16x4 pk;
          #pragma unroll
          for (int ii = 0; ii < 4; ++ii) pk[ii] = f2bf(acc[i][j][ii] + bn);
          *(u16x4*)&T[nl * 136 + ml0] = pk;
        }
      }
      __syncthreads();
      int b  = m0 >> 11, s0 = m0 & 2047;
      int hh = (n0 & 511) >> 6;
      int r  = tid >> 2, c0 = (tid & 3) * 32;
      unsigned short* dst = (unsigned short*)out2 +
          ((size_t)(b * NHEAD + hh) * HD + r) * SEQ + s0 + c0;
      #pragma unroll
      for (int u = 0; u < 4; ++u)
        *(u16x8*)(dst + u * 8) = *(u16x8*)&T[r * 136 + c0 + u * 8];
    }
  } else {  // EPI_PLAIN
    #pragma unroll
    for (int i = 0; i < MF; ++i) {
      int mrow = m0 + wm * (MF * 16) + i * 16 + g * 4;
      #pragma unroll
      for (int j = 0; j < NF; ++j) {
        int n = n0 + wn * (NF * 16) + j * 16 + c;
        float bn = bias0[n];
        unsigned short* o = (unsigned short*)out0;
        #pragma unroll
        for (int ii = 0; ii < 4; ++ii)
          o[(size_t)(mrow + ii) * N + n] = f2bf(acc[i][j][ii] + bn);
      }
    }
  }
}

// ---------------- GEMM v7d: fused dual-B gated FFN-up, counted pipeline ---
template<int BM, int BN>
__global__ __launch_bounds__(256) void gemm7d_k(
    const unsigned short* __restrict__ A,
    const unsigned short* __restrict__ B0t,   // [N][K]
    const unsigned short* __restrict__ B1t,   // [N][K]
    const float* __restrict__ bias0,
    const float* __restrict__ bias1,
    unsigned short* __restrict__ out,
    int M, int N, int K)
{
  constexpr int MF = BM / 32;
  constexpr int NF = BN / 32;
  constexpr int ALOADS = BM / 32;
  constexpr int BLOADS = BN / 32;
  constexpr int NL = ALOADS + 2 * BLOADS;

  __shared__ __attribute__((aligned(16))) unsigned short Al[2][BM * 64];
  __shared__ __attribute__((aligned(16))) unsigned short B0l[2][BN * 64];
  __shared__ __attribute__((aligned(16))) unsigned short B1l[2][BN * 64];

  int nblk = gridDim.x;
  int orig = blockIdx.x;
  int qq = nblk >> 3, rr = nblk & 7, xcd = orig & 7, pos = orig >> 3;
  int lid = (xcd < rr ? xcd * (qq + 1) : rr * (qq + 1) + (xcd - rr) * qq) + pos;
  int numM = M / BM;
  int nt = lid / numM, mt = lid % numM;   // n-major: XCD chunk shares B panel
  int m0 = mt * BM, n0 = nt * BN;

  int tid = threadIdx.x, lane = tid & 63, w = tid >> 6;
  int wm = w >> 1, wn = w & 1;
  int g = lane >> 4, c = lane & 15;
  int srow = lane >> 3, sslot = lane & 7;
  int sgc = (sslot ^ srow) * 8;

  const unsigned short* aG  = A   + (size_t)(m0 + w * (BM / 4) + srow) * K + sgc;
  const unsigned short* b0G = B0t + (size_t)(n0 + w * (BN / 4) + srow) * K + sgc;
  const unsigned short* b1G = B1t + (size_t)(n0 + w * (BN / 4) + srow) * K + sgc;
  int aOff = (w * (BM / 4) + srow) * 64 + sslot * 8;
  int bOff = (w * (BN / 4) + srow) * 64 + sslot * 8;

  f32x4 acc0[MF][NF] = {};
  f32x4 acc1[MF][NF] = {};
  int KT = K >> 6;
  int rk = c & 7;

  #pragma unroll
  for (int t = 0; t < ALOADS; ++t)
    gload16(aG + (size_t)(t * 8) * K, &Al[0][aOff + t * 8 * 64]);
  #pragma unroll
  for (int t = 0; t < BLOADS; ++t) {
    gload16(b0G + (size_t)(t * 8) * K, &B0l[0][bOff + t * 8 * 64]);
    gload16(b1G + (size_t)(t * 8) * K, &B1l[0][bOff + t * 8 * 64]);
  }

  for (int kt = 0; kt < KT; ++kt) {
    int cur = kt & 1;
    if (kt + 1 < KT) {
      int nb = cur ^ 1;
      const unsigned short* aGk  = aG  + (kt + 1) * 64;
      const unsigned short* b0Gk = b0G + (kt + 1) * 64;
      const unsigned short* b1Gk = b1G + (kt + 1) * 64;
      #pragma unroll
      for (int t = 0; t < ALOADS; ++t)
        gload16(aGk + (size_t)(t * 8) * K, &Al[nb][aOff + t * 8 * 64]);
      #pragma unroll
      for (int t = 0; t < BLOADS; ++t) {
        gload16(b0Gk + (size_t)(t * 8) * K, &B0l[nb][bOff + t * 8 * 64]);
        gload16(b1Gk + (size_t)(t * 8) * K, &B1l[nb][bOff + t * 8 * 64]);
      }
      waitcnt_vm<NL>();
    } else {
      waitcnt_vm<0>();
    }
    __builtin_amdgcn_s_barrier();
    __builtin_amdgcn_sched_barrier(0);
    #pragma unroll
    for (int ks = 0; ks < 2; ++ks) {
      int slot = (ks * 4 + g) ^ rk;
      bf16x8 af[MF], b0f[NF], b1f[NF];
      #pragma unroll
      for (int i = 0; i < MF; ++i)
        af[i] = ldb8(&Al[cur][(wm * (MF * 16) + i * 16 + c) * 64 + slot * 8]);
      #pragma unroll
      for (int j = 0; j < NF; ++j) {
        b0f[j] = ldb8(&B0l[cur][(wn * (NF * 16) + j * 16 + c) * 64 + slot * 8]);
        b1f[j] = ldb8(&B1l[cur][(wn * (NF * 16) + j * 16 + c) * 64 + slot * 8]);
      }
      #pragma unroll
      for (int i = 0; i < MF; ++i)
        #pragma unroll
        for (int j = 0; j < NF; ++j) {
          acc0[i][j] = mfma16(af[i], b0f[j], acc0[i][j]);
          acc1[i][j] = mfma16(af[i], b1f[j], acc1[i][j]);
        }
    }
    __builtin_amdgcn_sched_barrier(0);
    __builtin_amdgcn_s_barrier();
  }

  #pragma unroll
  for (int i = 0; i < MF; ++i) {
    int mrow = m0 + wm * (MF * 16) + i * 16 + g * 4;
    #pragma unroll
    for (int j = 0; j < NF; ++j) {
      int n = n0 + wn * (NF * 16) + j * 16 + c;
      float b0n = bias0[n], b1n = bias1[n];
      #pragma unroll
      for (int ii = 0; ii < 4; ++ii) {
        float a  = acc0[i][j][ii] + b0n;
        float gv = acc1[i][j][ii] + b1n;
        float s  = gv / (1.0f + __expf(-gv));
        out[(size_t)(mrow + ii) * N + n] = f2bf(a * s);
      }
    }
  }
}

// ---------------- attention v5: split-K flash, no-max softmax ------------
struct Stg { uint4v k0, k1, v0, v1; };

static __device__ __forceinline__ Stg stage_load(const unsigned short* Kp,
                                                 const unsigned short* Vp,
                                                 int kbase, int srow, int sslot) {
  Stg s;
  const unsigned short* kr = Kp + (size_t)(kbase + srow) * D_MODEL + sslot * 8;
  s.k0 = *(const uint4v*)kr;
  s.k1 = *(const uint4v*)(kr + 32);
  const unsigned short* vr = Vp + (size_t)srow * SEQ + kbase + sslot * 8;
  s.v0 = *(const uint4v*)vr;
  s.v1 = *(const uint4v*)(vr + 32);
  return s;
}
static __device__ __forceinline__ void stage_write(unsigned short* Klb, unsigned short* Vlb,
                                                   const Stg& s, int srow, int sslot) {
  char* kb = (char*)Klb;
  *(uint4v*)(kb + SWZ(srow, srow * 128 + sslot * 16))       = s.k0;
  *(uint4v*)(kb + SWZ(srow, srow * 128 + (sslot + 4) * 16)) = s.k1;
  char* vb = (char*)Vlb;
  *(uint4v*)(vb + SWZ(srow, srow * 128 + sslot * 16))       = s.v0;
  *(uint4v*)(vb + SWZ(srow, srow * 128 + (sslot + 4) * 16)) = s.v1;
}

template<bool MASKED>
static __device__ __forceinline__ void attn_tile(
    const unsigned short* Klb, const unsigned short* Vlb,
    bf16x8 qf0, bf16x8 qf1, f32x4* oacc, float& ps,
    int g, int c, int kbase, int qrow)
{
  f32x4 z[4];
  #pragma unroll
  for (int hh = 0; hh < 4; ++hh) {
    int r = hh * 16 + c;
    const char* base = (const char*)Klb;
    bf16x8 k0 = ldb8((const unsigned short*)(base + SWZ(r, r * 128 + g * 16)));
    bf16x8 k1 = ldb8((const unsigned short*)(base + SWZ(r, r * 128 + 64 + g * 16)));
    f32x4 t = {};
    t = mfma16(k0, qf0, t);
    t = mfma16(k1, qf1, t);
    z[hh] = t;
  }
  u16x8 pa0, pa1;
  #pragma unroll
  for (int hh = 0; hh < 4; ++hh) {
    #pragma unroll
    for (int i = 0; i < 4; ++i) {
      float p = exp2f(z[hh][i]);
      if (MASKED && (kbase + hh * 16 + g * 4 + i > qrow)) p = 0.0f;
      ps += p;
      unsigned short pb = f2bf(p);
      if (hh < 2) pa0[hh * 4 + i] = pb;
      else        pa1[(hh - 2) * 4 + i] = pb;
    }
  }
  bf16x8 af0 = __builtin_bit_cast(bf16x8, pa0);
  bf16x8 af1 = __builtin_bit_cast(bf16x8, pa1);
  #pragma unroll
  for (int db = 0; db < 4; ++db) {
    int r = db * 16 + c;
    const char* base = (const char*)Vlb;
    u16x4 v00 = *(const u16x4*)(base + SWZ(r, r * 128 + g * 8));
    u16x4 v01 = *(const u16x4*)(base + SWZ(r, r * 128 + 32 + g * 8));
    u16x4 v10 = *(const u16x4*)(base + SWZ(r, r * 128 + 64 + g * 8));
    u16x4 v11 = *(const u16x4*)(base + SWZ(r, r * 128 + 96 + g * 8));
    u16x8 vb0, vb1;
    #pragma unroll
    for (int j = 0; j < 4; ++j) {
      vb0[j] = v00[j]; vb0[4 + j] = v01[j];
      vb1[j] = v10[j]; vb1[4 + j] = v11[j];
    }
    oacc[db] = mfma16(af0, __builtin_bit_cast(bf16x8, vb0), oacc[db]);
    oacc[db] = mfma16(af1, __builtin_bit_cast(bf16x8, vb1), oacc[db]);
  }
}

static __device__ __forceinline__ int slot_base(int c) {
  if (c < 16) return (c - 8) * 2;
  if (c < 24) return 16 + (c - 16) * 3;
  return 40 + (c - 24) * 4;
}

__global__ __launch_bounds__(256) void attn5_k(const unsigned short* __restrict__ Q,
                                               const unsigned short* __restrict__ K,
                                               const unsigned short* __restrict__ VT,
                                               unsigned short* __restrict__ O,
                                               float* __restrict__ Oparts,
                                               float* __restrict__ Sparts)
{
  __shared__ __attribute__((aligned(16))) unsigned short Kl[2][64 * 64];
  __shared__ __attribute__((aligned(16))) unsigned short Vl[2][64 * 64];
  int tid = threadIdx.x, lane = tid & 63, w = tid >> 6;
  int g = lane >> 4, cl = lane & 15;

  int z = 79 - (int)blockIdx.x;
  int c, sp;
  if (z < 8)        { c = z;                    sp = 0; }
  else if (z < 24)  { int t2 = z - 8;  c = 8  + (t2 >> 1); sp = t2 & 1; }
  else if (z < 48)  { int t2 = z - 24; c = 16 + t2 / 3;    sp = t2 % 3; }
  else              { int t2 = z - 48; c = 24 + (t2 >> 2); sp = t2 & 3; }
  int kt0 = sp * 8;
  int kt1 = min(c + 1, kt0 + 8);
  bool lastsplit = (kt1 == c + 1);

  int bh = blockIdx.y, b = bh >> 3, h = bh & 7;
  int q0 = c * 64;
  const unsigned short* Qp = Q + (size_t)(b * SEQ) * D_MODEL + h * HD;
  const unsigned short* Kp = K + (size_t)(b * SEQ) * D_MODEL + h * HD;
  const unsigned short* Vp = VT + (size_t)bh * HD * SEQ;

  int qrow = q0 + w * 16 + cl;
  bf16x8 qf0 = ldb8(Qp + (size_t)qrow * D_MODEL + g * 8);
  bf16x8 qf1 = ldb8(Qp + (size_t)qrow * D_MODEL + 32 + g * 8);

  f32x4 oacc[4] = {};
  float ps = 0.0f;
  int srow = tid >> 2, sslot = tid & 3;

  Stg s0 = stage_load(Kp, Vp, kt0 * 64, srow, sslot);
  stage_write(&Kl[0][0], &Vl[0][0], s0, srow, sslot);
  __syncthreads();

  int buf = 0;
  for (int kt = kt0; kt < kt1 - 1; ++kt) {
    Stg sn = stage_load(Kp, Vp, (kt + 1) * 64, srow, sslot);
    attn_tile<false>(&Kl[buf][0], &Vl[buf][0], qf0, qf1, oacc, ps, g, cl, 0, 0);
    stage_write(&Kl[buf ^ 1][0], &Vl[buf ^ 1][0], sn, srow, sslot);
    __syncthreads();
    buf ^= 1;
  }
  if (lastsplit)
    attn_tile<true>(&Kl[buf][0], &Vl[buf][0], qf0, qf1, oacc, ps, g, cl,
                    (kt1 - 1) * 64, qrow);
  else
    attn_tile<false>(&Kl[buf][0], &Vl[buf][0], qf0, qf1, oacc, ps, g, cl, 0, 0);

  ps += __shfl_xor(ps, 16, 64);
  ps += __shfl_xor(ps, 32, 64);

  if (c < 8) {
    f32x4 inv;
    #pragma unroll
    for (int i = 0; i < 4; ++i) inv[i] = 1.0f / __shfl(ps, g * 4 + i, 64);
    #pragma unroll
    for (int db = 0; db < 4; ++db)
      #pragma unroll
      for (int i = 0; i < 4; ++i)
        O[(size_t)(b * SEQ + q0 + w * 16 + g * 4 + i) * D_MODEL + h * HD + db * 16 + cl] =
            f2bf(oacc[db][i] * inv[i]);
  } else {
    size_t slot = (size_t)bh * 72 + slot_base(c) + sp;
    float* Op = Oparts + slot * 4096;
    float* Sp = Sparts + slot * 64;
    #pragma unroll
    for (int db = 0; db < 4; ++db)
      #pragma unroll
      for (int i = 0; i < 4; ++i)
        Op[(w * 16 + g * 4 + i) * 64 + db * 16 + cl] = oacc[db][i];
    if (g == 0) Sp[w * 16 + cl] = ps;
  }
}

__global__ __launch_bounds__(256) void attn_comb_k(const float* __restrict__ Oparts,
                                                   const float* __restrict__ Sparts,
                                                   unsigned short* __restrict__ O) {
  int t  = threadIdx.x;
  int c  = 8 + (int)(blockIdx.x % 24);
  int bh = (int)(blockIdx.x / 24);
  int b = bh >> 3, h = bh & 7;
  int ns = (c + 8) >> 3;
  size_t slot = (size_t)bh * 72 + slot_base(c);
  const float* O0 = Oparts + slot * 4096;
  const float* S0 = Sparts + slot * 64;
  int r = t >> 2, d0 = (t & 3) * 16;
  f32x4 a0 = {}, a1 = {}, a2 = {}, a3 = {};
  float s = 0.0f;
  for (int si = 0; si < ns; ++si) {
    const float* o = O0 + si * 4096 + r * 64 + d0;
    a0 += *(const f32x4*)(o);
    a1 += *(const f32x4*)(o + 4);
    a2 += *(const f32x4*)(o + 8);
    a3 += *(const f32x4*)(o + 12);
    s  += S0[si * 64 + r];
  }
  float inv = 1.0f / s;
  u16x8 w0, w1;
  #pragma unroll
  for (int j = 0; j < 4; ++j) {
    w0[j]     = f2bf(a0[j] * inv); w0[4 + j] = f2bf(a1[j] * inv);
    w1[j]     = f2bf(a2[j] * inv); w1[4 + j] = f2bf(a3[j] * inv);
  }
  unsigned short* dst = O + (size_t)(b * SEQ + c * 64 + r) * D_MODEL + h * HD + d0;
  *(u16x8*)(dst)     = w0;
  *(u16x8*)(dst + 8) = w1;
}

// ---------------- launch ----------------
extern "C" void kernel_launch(void* const* d_in, const int* in_sizes, int n_in,
                              void* d_out, int out_size, void* d_ws, size_t ws_size,
                              hipStream_t stream) {
  (void)in_sizes; (void)n_in; (void)out_size; (void)ws_size;
  const float* x   = (const float*)d_in[0];
  const float* qw  = (const float*)d_in[1];
  const float* qb  = (const float*)d_in[2];
  const float* kw  = (const float*)d_in[3];
  const float* kbi = (const float*)d_in[4];
  const float* vw  = (const float*)d_in[5];
  const float* vb  = (const float*)d_in[6];
  const float* ow  = (const float*)d_in[7];
  const float* ob  = (const float*)d_in[8];
  const float* w0  = (const float*)d_in[9];
  const float* b0  = (const float*)d_in[10];
  const float* w1  = (const float*)d_in[11];
  const float* b1  = (const float*)d_in[12];
  const float* w2  = (const float*)d_in[13];
  const float* b2  = (const float*)d_in[14];
  const float* anw = (const float*)d_in[15];
  const float* fnw = (const float*)d_in[16];

  char* ws = (char*)d_ws;
  float*          h    = (float*)ws;                              // 0-8MB fp32 residual
  unsigned short* xn   = (unsigned short*)(ws + (8u  << 20));     // 8-12
  unsigned short* q    = (unsigned short*)(ws + (12u << 20));     // 12-16
  unsigned short* k    = (unsigned short*)(ws + (16u << 20));     // 16-20
  unsigned short* vt   = (unsigned short*)(ws + (24u << 20));     // 24-28
  unsigned short* ao   = (unsigned short*)(ws + (28u << 20));     // 28-32
  unsigned short* y    = (unsigned short*)(ws + (32u << 20));     // 32-36
  unsigned short* hbuf = (unsigned short*)(ws + (12u << 20));     // 12-28 (aliases q,k,vt)
  unsigned short* Wq   = (unsigned short*)(ws + (36u << 20));     // 36-42
  unsigned short* Wo   = (unsigned short*)(ws + (42u << 20));     // 42-44
  unsigned short* W01  = (unsigned short*)(ws + (44u << 20));     // 44-60
  unsigned short* W2   = (unsigned short*)(ws + (60u << 20));     // 60-68
  float*          Opar = (float*)(ws + (68u << 20));              // 68-86 (18MB)
  float*          Spar = (float*)(ws + (86u << 20));              // 86-86.3

  prep_t<<<4096, 64, 0, stream>>>(qw, kw, vw, ow, w0, w1, w2, Wq, Wo, W01, W2);
  initrms_k<<<BTOK / 4, 256, 0, stream>>>(x, anw, h, xn);

  for (int l = 0; l < 4; ++l) {
    size_t bo  = (size_t)l * D_MODEL;
    size_t bho = (size_t)l * HIDE;

    gemm7_k<EPI_QKV, 128, 64><<<768, 256, 0, stream>>>(
        xn, Wq + (size_t)l * 786432, qb + bo, kbi + bo, vb + bo,
        q, k, vt, BTOK, 3 * D_MODEL, D_MODEL);
    attn5_k<<<dim3(80, 16), 256, 0, stream>>>(q, k, vt, ao, Opar, Spar);
    attn_comb_k<<<384, 256, 0, stream>>>(Opar, Spar, ao);
    gemm7_k<EPI_PLAIN, 64, 64><<<512, 256, 0, stream>>>(
        ao, Wo + (size_t)l * 262144, ob + bo, nullptr, nullptr,
        y, nullptr, nullptr, BTOK, D_MODEL, D_MODEL);
    addrms_k<<<BTOK / 4, 256, 0, stream>>>(h, y, fnw + bo, xn);

    gemm7d_k<128, 64><<<1024, 256, 0, stream>>>(
        xn, W01 + (size_t)l * 2097152, W01 + (size_t)l * 2097152 + 1048576,
        b0 + bho, b1 + bho, hbuf, BTOK, HIDE, D_MODEL);
    gemm7_k<EPI_PLAIN, 64, 64><<<512, 256, 0, stream>>>(
        hbuf, W2 + (size_t)l * 1048576, b2 + bo, nullptr, nullptr,
        y, nullptr, nullptr, BTOK, D_MODEL, HIDE);
    addrms_k<<<BTOK / 4, 256, 0, stream>>>(
        h, y, (l < 3 ? anw + bo + D_MODEL : anw), xn);
  }
  hipMemcpyAsync(d_out, h, (size_t)BTOK * D_MODEL * sizeof(float),
                 hipMemcpyDeviceToDevice, stream);
}

// Round 13
// 454.052 us; speedup vs baseline: 3.5940x; 1.0294x over previous
//
#include <hip/hip_runtime.h>
#include <math.h>

// ---------------- types ----------------
typedef unsigned int   uint4v __attribute__((ext_vector_type(4)));
typedef float          f32x4  __attribute__((ext_vector_type(4)));
typedef __bf16         bf16x8 __attribute__((ext_vector_type(8)));
typedef unsigned short u16x8  __attribute__((ext_vector_type(8)));
typedef unsigned short u16x4  __attribute__((ext_vector_type(4)));

#define D_MODEL 512
#define SEQ     2048
#define BTOK    4096   // B * SEQ
#define HIDE    2048
#define NHEAD   8
#define HD      64

static __device__ __forceinline__ unsigned short f2bf(float f) {
  __bf16 b = (__bf16)f;
  return __builtin_bit_cast(unsigned short, b);
}
static __device__ __forceinline__ float bf2f(unsigned short b) {
  union { unsigned u; float f; } v; v.u = ((unsigned)b) << 16;
  return v.f;
}
static __device__ __forceinline__ bf16x8 ldb8(const unsigned short* p) {
  return __builtin_bit_cast(bf16x8, *(const uint4v*)p);
}
static __device__ __forceinline__ f32x4 mfma16(bf16x8 a, bf16x8 b, f32x4 c) {
  return __builtin_amdgcn_mfma_f32_16x16x32_bf16(a, b, c, 0, 0, 0);
}

typedef unsigned int u32_g __attribute__((address_space(1)));
typedef unsigned int u32_l __attribute__((address_space(3)));
static __device__ __forceinline__ void gload16(const unsigned short* g, unsigned short* l) {
  __builtin_amdgcn_global_load_lds((const u32_g*)(const void*)g,
                                   (u32_l*)(void*)l, 16, 0, 0);
}

#define SWZ(r, off) ((off) ^ (((r) & 7) << 4))
#define QSCALE 0.180336880f   // 0.125 * log2(e)

template<int N>
static __device__ __forceinline__ void waitcnt_vm() {
  asm volatile("s_waitcnt vmcnt(%0)" :: "i"(N) : "memory");
}

// ---------------- weight prep: LDS-tiled transpose f32 [K][N] -> bf16 [N][K] ----
// W01 is written INTERLEAVED in 16-col groups: rows g*32..+15 = W0 cols
// g*16..+15, rows g*32+16..+31 = W1 cols g*16..+15  (N=4096 total).
__global__ __launch_bounds__(64) void prep_t(
    const float* __restrict__ qw, const float* __restrict__ kw,
    const float* __restrict__ vw, const float* __restrict__ ow,
    const float* __restrict__ w0, const float* __restrict__ w1,
    const float* __restrict__ w2,
    unsigned short* __restrict__ Wq, unsigned short* __restrict__ Wo,
    unsigned short* __restrict__ W01, unsigned short* __restrict__ W2)
{
  int bid = blockIdx.x;
  int l = bid >> 10;
  int r = bid & 1023;
  const float* src; unsigned short* dst = nullptr;
  int tr, tc, srcN, dstK = 512;
  int w01sel = -1;
  if (r < 192) {
    int sel = r >> 6, tt = r & 63;
    tr = tt >> 3; tc = tt & 7;
    src = (sel == 0 ? qw : sel == 1 ? kw : vw) + (size_t)l * 262144;
    srcN = 512;
    dst = Wq + (size_t)l * 786432 + (size_t)(sel * 512 + tc * 64) * 512 + tr * 64;
  } else if (r < 256) {
    int tt = r - 192; tr = tt >> 3; tc = tt & 7;
    src = ow + (size_t)l * 262144; srcN = 512;
    dst = Wo + (size_t)l * 262144 + (size_t)(tc * 64) * 512 + tr * 64;
  } else if (r < 768) {
    int idx = r - 256; w01sel = idx >> 8; int tt = idx & 255;
    tr = tt >> 5; tc = tt & 31;
    src = (w01sel ? w1 : w0) + (size_t)l * 1048576; srcN = 2048;
    dst = W01 + (size_t)l * 2097152;   // base; row computed per-thread below
  } else {
    int tt = r - 768; tr = tt >> 3; tc = tt & 7;
    src = w2 + (size_t)l * 1048576; srcN = 512; dstK = 2048;
    dst = W2 + (size_t)l * 1048576 + (size_t)(tc * 64) * 2048 + tr * 64;
  }
  src += (size_t)(tr * 64) * srcN + tc * 64;
  __shared__ unsigned short T[64][68];
  int t = threadIdx.x;
  #pragma unroll
  for (int it = 0; it < 16; ++it) {
    int row = it * 4 + (t >> 4);
    int col = (t & 15) * 4;
    f32x4 v4 = *(const f32x4*)(src + (size_t)row * srcN + col);
    u16x4 o; o[0] = f2bf(v4.x); o[1] = f2bf(v4.y); o[2] = f2bf(v4.z); o[3] = f2bf(v4.w);
    *(u16x4*)&T[row][col] = o;
  }
  __syncthreads();
  unsigned short* orow;
  if (w01sel >= 0) {
    int row = (tc * 4 + (t >> 4)) * 32 + w01sel * 16 + (t & 15);
    orow = dst + (size_t)row * 512 + tr * 64;
  } else {
    orow = dst + (size_t)t * dstK;
  }
  #pragma unroll
  for (int j0 = 0; j0 < 8; ++j0) {
    u16x8 o;
    #pragma unroll
    for (int j = 0; j < 8; ++j) o[j] = T[j0 * 8 + j][t];
    *(u16x8*)(orow + j0 * 8) = o;
  }
}

// ---------------- initrms: h = x; xn = rms(x)*w ----------------
__global__ __launch_bounds__(256) void initrms_k(const float* __restrict__ x,
                                                 const float* __restrict__ w,
                                                 float* __restrict__ h,
                                                 unsigned short* __restrict__ xn) {
  int row  = blockIdx.x * 4 + (threadIdx.x >> 6);
  int lane = threadIdx.x & 63;
  const float* xr = x + (size_t)row * D_MODEL + lane * 8;
  f32x4 v0 = *(const f32x4*)(xr);
  f32x4 v1 = *(const f32x4*)(xr + 4);
  *(f32x4*)(h + (size_t)row * D_MODEL + lane * 8)     = v0;
  *(f32x4*)(h + (size_t)row * D_MODEL + lane * 8 + 4) = v1;
  float ss = v0.x*v0.x + v0.y*v0.y + v0.z*v0.z + v0.w*v0.w
           + v1.x*v1.x + v1.y*v1.y + v1.z*v1.z + v1.w*v1.w;
  #pragma unroll
  for (int m = 1; m < 64; m <<= 1) ss += __shfl_xor(ss, m, 64);
  float inv = 1.0f / (sqrtf(ss * (1.0f / D_MODEL)) + 1e-6f);
  f32x4 w0 = *(const f32x4*)(w + lane * 8);
  f32x4 w1 = *(const f32x4*)(w + lane * 8 + 4);
  u16x8 o;
  o[0] = f2bf(v0.x * w0.x * inv); o[1] = f2bf(v0.y * w0.y * inv);
  o[2] = f2bf(v0.z * w0.z * inv); o[3] = f2bf(v0.w * w0.w * inv);
  o[4] = f2bf(v1.x * w1.x * inv); o[5] = f2bf(v1.y * w1.y * inv);
  o[6] = f2bf(v1.z * w1.z * inv); o[7] = f2bf(v1.w * w1.w * inv);
  *(u16x8*)(xn + (size_t)row * D_MODEL + lane * 8) = o;
}

// ---------------- addrms: h += y(bf16); xn = rms(h)*w ----------------
__global__ __launch_bounds__(256) void addrms_k(float* __restrict__ h,
                                                const unsigned short* __restrict__ y,
                                                const float* __restrict__ w,
                                                unsigned short* __restrict__ xn) {
  int row  = blockIdx.x * 4 + (threadIdx.x >> 6);
  int lane = threadIdx.x & 63;
  float* hr = h + (size_t)row * D_MODEL + lane * 8;
  f32x4 v0 = *(const f32x4*)(hr);
  f32x4 v1 = *(const f32x4*)(hr + 4);
  u16x8 yy = *(const u16x8*)(y + (size_t)row * D_MODEL + lane * 8);
  v0.x += bf2f(yy[0]); v0.y += bf2f(yy[1]); v0.z += bf2f(yy[2]); v0.w += bf2f(yy[3]);
  v1.x += bf2f(yy[4]); v1.y += bf2f(yy[5]); v1.z += bf2f(yy[6]); v1.w += bf2f(yy[7]);
  *(f32x4*)(hr)     = v0;
  *(f32x4*)(hr + 4) = v1;
  float ss = v0.x*v0.x + v0.y*v0.y + v0.z*v0.z + v0.w*v0.w
           + v1.x*v1.x + v1.y*v1.y + v1.z*v1.z + v1.w*v1.w;
  #pragma unroll
  for (int m = 1; m < 64; m <<= 1) ss += __shfl_xor(ss, m, 64);
  float inv = 1.0f / (sqrtf(ss * (1.0f / D_MODEL)) + 1e-6f);
  f32x4 w0 = *(const f32x4*)(w + lane * 8);
  f32x4 w1 = *(const f32x4*)(w + lane * 8 + 4);
  u16x8 o;
  o[0] = f2bf(v0.x * w0.x * inv); o[1] = f2bf(v0.y * w0.y * inv);
  o[2] = f2bf(v0.z * w0.z * inv); o[3] = f2bf(v0.w * w0.w * inv);
  o[4] = f2bf(v1.x * w1.x * inv); o[5] = f2bf(v1.y * w1.y * inv);
  o[6] = f2bf(v1.z * w1.z * inv); o[7] = f2bf(v1.w * w1.w * inv);
  *(u16x8*)(xn + (size_t)row * D_MODEL + lane * 8) = o;
}

// ---------------- GEMM v7: counted-vmcnt pipeline + T2 swizzle ------------
#define EPI_QKV   0
#define EPI_PLAIN 1

template<int EPI, int BM, int BN>
__global__ __launch_bounds__(256) void gemm7_k(
    const unsigned short* __restrict__ A,
    const unsigned short* __restrict__ Bt,    // [N][K]
    const float* __restrict__ bias0,
    const float* __restrict__ bias1,
    const float* __restrict__ bias2,
    void* __restrict__ out0,
    void* __restrict__ out1,
    void* __restrict__ out2,                  // QKV: vt [bh][d][s]
    int M, int N, int K)
{
  constexpr int MF = BM / 32;
  constexpr int NF = BN / 32;
  constexpr int ALOADS = BM / 32;
  constexpr int BLOADS = BN / 32;
  constexpr int NL = ALOADS + BLOADS;

  __shared__ __attribute__((aligned(16))) unsigned short Al[2][BM * 64];
  __shared__ __attribute__((aligned(16))) unsigned short Bl[2][BN * 64];

  int nblk = gridDim.x;
  int orig = blockIdx.x;
  int qq = nblk >> 3, rr = nblk & 7, xcd = orig & 7, pos = orig >> 3;
  int lid = (xcd < rr ? xcd * (qq + 1) : rr * (qq + 1) + (xcd - rr) * qq) + pos;
  int numN = N / BN;
  int mt = lid / numN, nt = lid % numN;
  int m0 = mt * BM, n0 = nt * BN;

  int tid = threadIdx.x, lane = tid & 63, w = tid >> 6;
  int wm = w >> 1, wn = w & 1;
  int g = lane >> 4, c = lane & 15;
  int srow = lane >> 3, sslot = lane & 7;
  int sgc = (sslot ^ srow) * 8;

  const unsigned short* aG = A  + (size_t)(m0 + w * (BM / 4) + srow) * K + sgc;
  const unsigned short* bG = Bt + (size_t)(n0 + w * (BN / 4) + srow) * K + sgc;
  int aOff = (w * (BM / 4) + srow) * 64 + sslot * 8;
  int bOff = (w * (BN / 4) + srow) * 64 + sslot * 8;

  f32x4 acc[MF][NF] = {};
  int KT = K >> 6;
  int rk = c & 7;

  #pragma unroll
  for (int t = 0; t < ALOADS; ++t)
    gload16(aG + (size_t)(t * 8) * K, &Al[0][aOff + t * 8 * 64]);
  #pragma unroll
  for (int t = 0; t < BLOADS; ++t)
    gload16(bG + (size_t)(t * 8) * K, &Bl[0][bOff + t * 8 * 64]);

  for (int kt = 0; kt < KT; ++kt) {
    int cur = kt & 1;
    if (kt + 1 < KT) {
      int nb = cur ^ 1;
      const unsigned short* aGk = aG + (kt + 1) * 64;
      const unsigned short* bGk = bG + (kt + 1) * 64;
      #pragma unroll
      for (int t = 0; t < ALOADS; ++t)
        gload16(aGk + (size_t)(t * 8) * K, &Al[nb][aOff + t * 8 * 64]);
      #pragma unroll
      for (int t = 0; t < BLOADS; ++t)
        gload16(bGk + (size_t)(t * 8) * K, &Bl[nb][bOff + t * 8 * 64]);
      waitcnt_vm<NL>();
    } else {
      waitcnt_vm<0>();
    }
    __builtin_amdgcn_s_barrier();
    __builtin_amdgcn_sched_barrier(0);
    #pragma unroll
    for (int ks = 0; ks < 2; ++ks) {
      int slot = (ks * 4 + g) ^ rk;
      bf16x8 af[MF], bfr[NF];
      #pragma unroll
      for (int i = 0; i < MF; ++i)
        af[i] = ldb8(&Al[cur][(wm * (MF * 16) + i * 16 + c) * 64 + slot * 8]);
      #pragma unroll
      for (int j = 0; j < NF; ++j)
        bfr[j] = ldb8(&Bl[cur][(wn * (NF * 16) + j * 16 + c) * 64 + slot * 8]);
      #pragma unroll
      for (int i = 0; i < MF; ++i)
        #pragma unroll
        for (int j = 0; j < NF; ++j)
          acc[i][j] = mfma16(af[i], bfr[j], acc[i][j]);
    }
    __builtin_amdgcn_sched_barrier(0);
    __builtin_amdgcn_s_barrier();
  }

  if (EPI == EPI_QKV) {
    int sel  = n0 >> 9;
    if (sel < 2) {
      #pragma unroll
      for (int i = 0; i < MF; ++i) {
        int mrow = m0 + wm * (MF * 16) + i * 16 + g * 4;
        #pragma unroll
        for (int j = 0; j < NF; ++j) {
          int nloc = (n0 & 511) + wn * (NF * 16) + j * 16 + c;
          const float* bp = sel == 0 ? bias0 : bias1;
          unsigned short* o = (unsigned short*)(sel == 0 ? out0 : out1);
          float sc = (sel == 0) ? QSCALE : 1.0f;
          float bn = bp[nloc];
          #pragma unroll
          for (int ii = 0; ii < 4; ++ii)
            o[(size_t)(mrow + ii) * D_MODEL + nloc] = f2bf((acc[i][j][ii] + bn) * sc);
        }
      }
    } else {
      unsigned short* T = &Al[0][0];            // 64 x 136
      #pragma unroll
      for (int i = 0; i < MF; ++i) {
        int ml0 = wm * (MF * 16) + i * 16 + g * 4;
        #pragma unroll
        for (int j = 0; j < NF; ++j) {
          int nl = wn * (NF * 16) + j * 16 + c;
          float bn = bias2[(n0 & 511) + nl];
          u16x4 pk;
          #pragma unroll
          for (int ii = 0; ii < 4; ++ii) pk[ii] = f2bf(acc[i][j][ii] + bn);
          *(u16x4*)&T[nl * 136 + ml0] = pk;
        }
      }
      __syncthreads();
      int b  = m0 >> 11, s0 = m0 & 2047;
      int hh = (n0 & 511) >> 6;
      int r  = tid >> 2, c0 = (tid & 3) * 32;
      unsigned short* dst = (unsigned short*)out2 +
          ((size_t)(b * NHEAD + hh) * HD + r) * SEQ + s0 + c0;
      #pragma unroll
      for (int u = 0; u < 4; ++u)
        *(u16x8*)(dst + u * 8) = *(u16x8*)&T[r * 136 + c0 + u * 8];
    }
  } else {  // EPI_PLAIN
    #pragma unroll
    for (int i = 0; i < MF; ++i) {
      int mrow = m0 + wm * (MF * 16) + i * 16 + g * 4;
      #pragma unroll
      for (int j = 0; j < NF; ++j) {
        int n = n0 + wn * (NF * 16) + j * 16 + c;
        float bn = bias0[n];
        unsigned short* o = (unsigned short*)out0;
        #pragma unroll
        for (int ii = 0; ii < 4; ++ii)
          o[(size_t)(mrow + ii) * N + n] = f2bf(acc[i][j][ii] + bn);
      }
    }
  }
}

// ---------------- GEMM v8g: 256x256 gated FFN-up on interleaved W01 -------
// 8 waves (2m x 4n), wave tile 128x64, counted-vmcnt 2-phase, T2 swizzle.
// B rows interleaved: frag pair (2t, 2t+1) = (W0, W1) cols of SAME 16-group,
// same lane -> gate epilogue is lane-local: out = a * silu(g).
__global__ __launch_bounds__(512, 2) void gemm8g_k(
    const unsigned short* __restrict__ A,
    const unsigned short* __restrict__ Bi,    // [4096][512] interleaved
    const float* __restrict__ bias0,          // [2048]
    const float* __restrict__ bias1,          // [2048]
    unsigned short* __restrict__ out)         // [M][2048]
{
  constexpr int BM = 256, BN = 256, K = 512, NOUT = 2048;
  constexpr int MF = 8, NF = 4;               // wave tile 128 x 64
  constexpr int ALOADS = 4, BLOADS = 4, NL = 8;

  __shared__ __attribute__((aligned(16))) unsigned short Al[2][BM * 64];
  __shared__ __attribute__((aligned(16))) unsigned short Bl[2][BN * 64];

  int nblk = gridDim.x;                       // 256 (divisible by 8)
  int orig = blockIdx.x;
  int qq = nblk >> 3, xcd = orig & 7, pos = orig >> 3;
  int lid = xcd * qq + pos;
  int mt = lid >> 4, nt = lid & 15;           // 16 x 16
  int m0 = mt * BM, n0 = nt * BN;

  int tid = threadIdx.x, lane = tid & 63, w = tid >> 6;  // 8 waves
  int wm = w >> 2, wn = w & 3;                // 2m x 4n
  int g = lane >> 4, c = lane & 15;
  int srow = lane >> 3, sslot = lane & 7;
  int sgc = (sslot ^ srow) * 8;

  const unsigned short* aG = A  + (size_t)(m0 + w * 32 + srow) * K + sgc;
  const unsigned short* bG = Bi + (size_t)(n0 + w * 32 + srow) * K + sgc;
  int aOff = (w * 32 + srow) * 64 + sslot * 8;
  int bOff = aOff;

  f32x4 acc[MF][NF] = {};
  int rk = c & 7;
  constexpr int KT = K >> 6;                  // 8

  #pragma unroll
  for (int t = 0; t < ALOADS; ++t)
    gload16(aG + (size_t)(t * 8) * K, &Al[0][aOff + t * 8 * 64]);
  #pragma unroll
  for (int t = 0; t < BLOADS; ++t)
    gload16(bG + (size_t)(t * 8) * K, &Bl[0][bOff + t * 8 * 64]);

  for (int kt = 0; kt < KT; ++kt) {
    int cur = kt & 1;
    if (kt + 1 < KT) {
      int nb = cur ^ 1;
      const unsigned short* aGk = aG + (kt + 1) * 64;
      const unsigned short* bGk = bG + (kt + 1) * 64;
      #pragma unroll
      for (int t = 0; t < ALOADS; ++t)
        gload16(aGk + (size_t)(t * 8) * K, &Al[nb][aOff + t * 8 * 64]);
      #pragma unroll
      for (int t = 0; t < BLOADS; ++t)
        gload16(bGk + (size_t)(t * 8) * K, &Bl[nb][bOff + t * 8 * 64]);
      waitcnt_vm<NL>();
    } else {
      waitcnt_vm<0>();
    }
    __builtin_amdgcn_s_barrier();
    __builtin_amdgcn_sched_barrier(0);
    #pragma unroll
    for (int ks = 0; ks < 2; ++ks) {
      int slot = (ks * 4 + g) ^ rk;
      bf16x8 af[MF], bfr[NF];
      #pragma unroll
      for (int i = 0; i < MF; ++i)
        af[i] = ldb8(&Al[cur][(wm * 128 + i * 16 + c) * 64 + slot * 8]);
      #pragma unroll
      for (int j = 0; j < NF; ++j)
        bfr[j] = ldb8(&Bl[cur][(wn * 64 + j * 16 + c) * 64 + slot * 8]);
      #pragma unroll
      for (int i = 0; i < MF; ++i)
        #pragma unroll
        for (int j = 0; j < NF; ++j)
          acc[i][j] = mfma16(af[i], bfr[j], acc[i][j]);
    }
    __builtin_amdgcn_sched_barrier(0);
    __builtin_amdgcn_s_barrier();
  }

  // epilogue: frag pair (2t, 2t+1) -> out col (n0 + wn*64)/2 + t*16 + c
  #pragma unroll
  for (int i = 0; i < MF; ++i) {
    int mrow = m0 + wm * 128 + i * 16 + g * 4;
    #pragma unroll
    for (int t = 0; t < 2; ++t) {
      int n_out = ((n0 + wn * 64) >> 1) + t * 16 + c;
      float b0n = bias0[n_out], b1n = bias1[n_out];
      #pragma unroll
      for (int ii = 0; ii < 4; ++ii) {
        float a  = acc[i][2 * t][ii] + b0n;
        float gv = acc[i][2 * t + 1][ii] + b1n;
        float s  = gv / (1.0f + __expf(-gv));
        out[(size_t)(mrow + ii) * NOUT + n_out] = f2bf(a * s);
      }
    }
  }
}

// ---------------- attention v5: split-K flash, no-max softmax ------------
struct Stg { uint4v k0, k1, v0, v1; };

static __device__ __forceinline__ Stg stage_load(const unsigned short* Kp,
                                                 const unsigned short* Vp,
                                                 int kbase, int srow, int sslot) {
  Stg s;
  const unsigned short* kr = Kp + (size_t)(kbase + srow) * D_MODEL + sslot * 8;
  s.k0 = *(const uint4v*)kr;
  s.k1 = *(const uint4v*)(kr + 32);
  const unsigned short* vr = Vp + (size_t)srow * SEQ + kbase + sslot * 8;
  s.v0 = *(const uint4v*)vr;
  s.v1 = *(const uint4v*)(vr + 32);
  return s;
}
static __device__ __forceinline__ void stage_write(unsigned short* Klb, unsigned short* Vlb,
                                                   const Stg& s, int srow, int sslot) {
  char* kb = (char*)Klb;
  *(uint4v*)(kb + SWZ(srow, srow * 128 + sslot * 16))       = s.k0;
  *(uint4v*)(kb + SWZ(srow, srow * 128 + (sslot + 4) * 16)) = s.k1;
  char* vb = (char*)Vlb;
  *(uint4v*)(vb + SWZ(srow, srow * 128 + sslot * 16))       = s.v0;
  *(uint4v*)(vb + SWZ(srow, srow * 128 + (sslot + 4) * 16)) = s.v1;
}

template<bool MASKED>
static __device__ __forceinline__ void attn_tile(
    const unsigned short* Klb, const unsigned short* Vlb,
    bf16x8 qf0, bf16x8 qf1, f32x4* oacc, float& ps,
    int g, int c, int kbase, int qrow)
{
  f32x4 z[4];
  #pragma unroll
  for (int hh = 0; hh < 4; ++hh) {
    int r = hh * 16 + c;
    const char* base = (const char*)Klb;
    bf16x8 k0 = ldb8((const unsigned short*)(base + SWZ(r, r * 128 + g * 16)));
    bf16x8 k1 = ldb8((const unsigned short*)(base + SWZ(r, r * 128 + 64 + g * 16)));
    f32x4 t = {};
    t = mfma16(k0, qf0, t);
    t = mfma16(k1, qf1, t);
    z[hh] = t;
  }
  u16x8 pa0, pa1;
  #pragma unroll
  for (int hh = 0; hh < 4; ++hh) {
    #pragma unroll
    for (int i = 0; i < 4; ++i) {
      float p = exp2f(z[hh][i]);
      if (MASKED && (kbase + hh * 16 + g * 4 + i > qrow)) p = 0.0f;
      ps += p;
      unsigned short pb = f2bf(p);
      if (hh < 2) pa0[hh * 4 + i] = pb;
      else        pa1[(hh - 2) * 4 + i] = pb;
    }
  }
  bf16x8 af0 = __builtin_bit_cast(bf16x8, pa0);
  bf16x8 af1 = __builtin_bit_cast(bf16x8, pa1);
  #pragma unroll
  for (int db = 0; db < 4; ++db) {
    int r = db * 16 + c;
    const char* base = (const char*)Vlb;
    u16x4 v00 = *(const u16x4*)(base + SWZ(r, r * 128 + g * 8));
    u16x4 v01 = *(const u16x4*)(base + SWZ(r, r * 128 + 32 + g * 8));
    u16x4 v10 = *(const u16x4*)(base + SWZ(r, r * 128 + 64 + g * 8));
    u16x4 v11 = *(const u16x4*)(base + SWZ(r, r * 128 + 96 + g * 8));
    u16x8 vb0, vb1;
    #pragma unroll
    for (int j = 0; j < 4; ++j) {
      vb0[j] = v00[j]; vb0[4 + j] = v01[j];
      vb1[j] = v10[j]; vb1[4 + j] = v11[j];
    }
    oacc[db] = mfma16(af0, __builtin_bit_cast(bf16x8, vb0), oacc[db]);
    oacc[db] = mfma16(af1, __builtin_bit_cast(bf16x8, vb1), oacc[db]);
  }
}

static __device__ __forceinline__ int slot_base(int c) {
  if (c < 16) return (c - 8) * 2;
  if (c < 24) return 16 + (c - 16) * 3;
  return 40 + (c - 24) * 4;
}

__global__ __launch_bounds__(256) void attn5_k(const unsigned short* __restrict__ Q,
                                               const unsigned short* __restrict__ K,
                                               const unsigned short* __restrict__ VT,
                                               unsigned short* __restrict__ O,
                                               float* __restrict__ Oparts,
                                               float* __restrict__ Sparts)
{
  __shared__ __attribute__((aligned(16))) unsigned short Kl[2][64 * 64];
  __shared__ __attribute__((aligned(16))) unsigned short Vl[2][64 * 64];
  int tid = threadIdx.x, lane = tid & 63, w = tid >> 6;
  int g = lane >> 4, cl = lane & 15;

  int z = 79 - (int)blockIdx.x;
  int c, sp;
  if (z < 8)        { c = z;                    sp = 0; }
  else if (z < 24)  { int t2 = z - 8;  c = 8  + (t2 >> 1); sp = t2 & 1; }
  else if (z < 48)  { int t2 = z - 24; c = 16 + t2 / 3;    sp = t2 % 3; }
  else              { int t2 = z - 48; c = 24 + (t2 >> 2); sp = t2 & 3; }
  int kt0 = sp * 8;
  int kt1 = min(c + 1, kt0 + 8);
  bool lastsplit = (kt1 == c + 1);

  int bh = blockIdx.y, b = bh >> 3, h = bh & 7;
  int q0 = c * 64;
  const unsigned short* Qp = Q + (size_t)(b * SEQ) * D_MODEL + h * HD;
  const unsigned short* Kp = K + (size_t)(b * SEQ) * D_MODEL + h * HD;
  const unsigned short* Vp = VT + (size_t)bh * HD * SEQ;

  int qrow = q0 + w * 16 + cl;
  bf16x8 qf0 = ldb8(Qp + (size_t)qrow * D_MODEL + g * 8);
  bf16x8 qf1 = ldb8(Qp + (size_t)qrow * D_MODEL + 32 + g * 8);

  f32x4 oacc[4] = {};
  float ps = 0.0f;
  int srow = tid >> 2, sslot = tid & 3;

  Stg s0 = stage_load(Kp, Vp, kt0 * 64, srow, sslot);
  stage_write(&Kl[0][0], &Vl[0][0], s0, srow, sslot);
  __syncthreads();

  int buf = 0;
  for (int kt = kt0; kt < kt1 - 1; ++kt) {
    Stg sn = stage_load(Kp, Vp, (kt + 1) * 64, srow, sslot);
    attn_tile<false>(&Kl[buf][0], &Vl[buf][0], qf0, qf1, oacc, ps, g, cl, 0, 0);
    stage_write(&Kl[buf ^ 1][0], &Vl[buf ^ 1][0], sn, srow, sslot);
    __syncthreads();
    buf ^= 1;
  }
  if (lastsplit)
    attn_tile<true>(&Kl[buf][0], &Vl[buf][0], qf0, qf1, oacc, ps, g, cl,
                    (kt1 - 1) * 64, qrow);
  else
    attn_tile<false>(&Kl[buf][0], &Vl[buf][0], qf0, qf1, oacc, ps, g, cl, 0, 0);

  ps += __shfl_xor(ps, 16, 64);
  ps += __shfl_xor(ps, 32, 64);

  if (c < 8) {
    f32x4 inv;
    #pragma unroll
    for (int i = 0; i < 4; ++i) inv[i] = 1.0f / __shfl(ps, g * 4 + i, 64);
    #pragma unroll
    for (int db = 0; db < 4; ++db)
      #pragma unroll
      for (int i = 0; i < 4; ++i)
        O[(size_t)(b * SEQ + q0 + w * 16 + g * 4 + i) * D_MODEL + h * HD + db * 16 + cl] =
            f2bf(oacc[db][i] * inv[i]);
  } else {
    size_t slot = (size_t)bh * 72 + slot_base(c) + sp;
    float* Op = Oparts + slot * 4096;
    float* Sp = Sparts + slot * 64;
    #pragma unroll
    for (int db = 0; db < 4; ++db)
      #pragma unroll
      for (int i = 0; i < 4; ++i)
        Op[(w * 16 + g * 4 + i) * 64 + db * 16 + cl] = oacc[db][i];
    if (g == 0) Sp[w * 16 + cl] = ps;
  }
}

__global__ __launch_bounds__(256) void attn_comb_k(const float* __restrict__ Oparts,
                                                   const float* __restrict__ Sparts,
                                                   unsigned short* __restrict__ O) {
  int t  = threadIdx.x;
  int c  = 8 + (int)(blockIdx.x % 24);
  int bh = (int)(blockIdx.x / 24);
  int b = bh >> 3, h = bh & 7;
  int ns = (c + 8) >> 3;
  size_t slot = (size_t)bh * 72 + slot_base(c);
  const float* O0 = Oparts + slot * 4096;
  const float* S0 = Sparts + slot * 64;
  int r = t >> 2, d0 = (t & 3) * 16;
  f32x4 a0 = {}, a1 = {}, a2 = {}, a3 = {};
  float s = 0.0f;
  for (int si = 0; si < ns; ++si) {
    const float* o = O0 + si * 4096 + r * 64 + d0;
    a0 += *(const f32x4*)(o);
    a1 += *(const f32x4*)(o + 4);
    a2 += *(const f32x4*)(o + 8);
    a3 += *(const f32x4*)(o + 12);
    s  += S0[si * 64 + r];
  }
  float inv = 1.0f / s;
  u16x8 w0, w1;
  #pragma unroll
  for (int j = 0; j < 4; ++j) {
    w0[j]     = f2bf(a0[j] * inv); w0[4 + j] = f2bf(a1[j] * inv);
    w1[j]     = f2bf(a2[j] * inv); w1[4 + j] = f2bf(a3[j] * inv);
  }
  unsigned short* dst = O + (size_t)(b * SEQ + c * 64 + r) * D_MODEL + h * HD + d0;
  *(u16x8*)(dst)     = w0;
  *(u16x8*)(dst + 8) = w1;
}

// ---------------- launch ----------------
extern "C" void kernel_launch(void* const* d_in, const int* in_sizes, int n_in,
                              void* d_out, int out_size, void* d_ws, size_t ws_size,
                              hipStream_t stream) {
  (void)in_sizes; (void)n_in; (void)out_size; (void)ws_size;
  const float* x   = (const float*)d_in[0];
  const float* qw  = (const float*)d_in[1];
  const float* qb  = (const float*)d_in[2];
  const float* kw  = (const float*)d_in[3];
  const float* kbi = (const float*)d_in[4];
  const float* vw  = (const float*)d_in[5];
  const float* vb  = (const float*)d_in[6];
  const float* ow  = (const float*)d_in[7];
  const float* ob  = (const float*)d_in[8];
  const float* w0  = (const float*)d_in[9];
  const float* b0  = (const float*)d_in[10];
  const float* w1  = (const float*)d_in[11];
  const float* b1  = (const float*)d_in[12];
  const float* w2  = (const float*)d_in[13];
  const float* b2  = (const float*)d_in[14];
  const float* anw = (const float*)d_in[15];
  const float* fnw = (const float*)d_in[16];

  char* ws = (char*)d_ws;
  float*          h    = (float*)ws;                              // 0-8MB fp32 residual
  unsigned short* xn   = (unsigned short*)(ws + (8u  << 20));     // 8-12
  unsigned short* q    = (unsigned short*)(ws + (12u << 20));     // 12-16
  unsigned short* k    = (unsigned short*)(ws + (16u << 20));     // 16-20
  unsigned short* vt   = (unsigned short*)(ws + (24u << 20));     // 24-28
  unsigned short* ao   = (unsigned short*)(ws + (28u << 20));     // 28-32
  unsigned short* y    = (unsigned short*)(ws + (32u << 20));     // 32-36
  unsigned short* hbuf = (unsigned short*)(ws + (12u << 20));     // 12-28 (aliases q,k,vt)
  unsigned short* Wq   = (unsigned short*)(ws + (36u << 20));     // 36-42
  unsigned short* Wo   = (unsigned short*)(ws + (42u << 20));     // 42-44
  unsigned short* W01  = (unsigned short*)(ws + (44u << 20));     // 44-60 (interleaved)
  unsigned short* W2   = (unsigned short*)(ws + (60u << 20));     // 60-68
  float*          Opar = (float*)(ws + (68u << 20));              // 68-86 (18MB)
  float*          Spar = (float*)(ws + (86u << 20));              // 86-86.3

  prep_t<<<4096, 64, 0, stream>>>(qw, kw, vw, ow, w0, w1, w2, Wq, Wo, W01, W2);
  initrms_k<<<BTOK / 4, 256, 0, stream>>>(x, anw, h, xn);

  for (int l = 0; l < 4; ++l) {
    size_t bo  = (size_t)l * D_MODEL;
    size_t bho = (size_t)l * HIDE;

    gemm7_k<EPI_QKV, 128, 64><<<768, 256, 0, stream>>>(
        xn, Wq + (size_t)l * 786432, qb + bo, kbi + bo, vb + bo,
        q, k, vt, BTOK, 3 * D_MODEL, D_MODEL);
    attn5_k<<<dim3(80, 16), 256, 0, stream>>>(q, k, vt, ao, Opar, Spar);
    attn_comb_k<<<384, 256, 0, stream>>>(Opar, Spar, ao);
    gemm7_k<EPI_PLAIN, 64, 64><<<512, 256, 0, stream>>>(
        ao, Wo + (size_t)l * 262144, ob + bo, nullptr, nullptr,
        y, nullptr, nullptr, BTOK, D_MODEL, D_MODEL);
    addrms_k<<<BTOK / 4, 256, 0, stream>>>(h, y, fnw + bo, xn);

    gemm8g_k<<<256, 512, 0, stream>>>(
        xn, W01 + (size_t)l * 2097152, b0 + bho, b1 + bho, hbuf);
    gemm7_k<EPI_PLAIN, 64, 64><<<512, 256, 0, stream>>>(
        hbuf, W2 + (size_t)l * 1048576, b2 + bo, nullptr, nullptr,
        y, nullptr, nullptr, BTOK, D_MODEL, HIDE);
    addrms_k<<<BTOK / 4, 256, 0, stream>>>(
        h, y, (l < 3 ? anw + bo + D_MODEL : anw), xn);
  }
  hipMemcpyAsync(d_out, h, (size_t)BTOK * D_MODEL * sizeof(float),
                 hipMemcpyDeviceToDevice, stream);
}